// Round 6
// baseline (572.378 us; speedup 1.0000x reference)
//
#include <hip/hip_runtime.h>

typedef __attribute__((ext_vector_type(8))) short short8;
typedef __attribute__((ext_vector_type(4))) float f32x4;
typedef unsigned short u16;
typedef unsigned int u32;

__device__ __forceinline__ u16 f2bf(float f) {
  u32 u = __float_as_uint(f);
  u = (u + 0x7fffu + ((u >> 16) & 1u)) >> 16;
  return (u16)u;
}
__device__ __forceinline__ void atomAddF(float* p, float v) { unsafeAtomicAdd(p, v); }
__device__ __forceinline__ u32 fflip(float f) {
  u32 u = __float_as_uint(f);
  return (u & 0x80000000u) ? ~u : (u | 0x80000000u);
}
__device__ __forceinline__ float funflip(u32 u) {
  return __uint_as_float((u & 0x80000000u) ? (u ^ 0x80000000u) : ~u);
}
__device__ __forceinline__ void add4(float4& a, const float4 b) {
  a.x += b.x; a.y += b.y; a.z += b.z; a.w += b.w;
}

// stage `groups` B row-groups (8 k-rows each, C cols) into LDS with +8 u16 pad/group
__device__ __forceinline__ void stageB(const u16* __restrict__ Bp, u16* __restrict__ Bs,
                                       int groups, int g0, int C, int tid) {
  int per = C * 4;  // u32 per group
  for (int g = 0; g < groups; ++g) {
    const u32* src = (const u32*)(Bp + (size_t)(g0 + g) * C * 8);
    u32* dst = (u32*)(Bs + (size_t)g * (C * 8 + 8));
    for (int i = tid; i < per; i += 256) dst[i] = src[i];
  }
}

// ---- setup: pack bf16 weights (MFMA B-frag layout) + find graph boundaries ----
__global__ void setup_k(const float* __restrict__ Wm1, const float* __restrict__ We1,
                        const float* __restrict__ Ws1, const float* __restrict__ Wm2,
                        const int* __restrict__ batch, u16* __restrict__ Wp1,
                        u16* __restrict__ Wp2, int* __restrict__ gstart,
                        int* __restrict__ gend, int N) {
  int tid = blockIdx.x * 256 + threadIdx.x;
  if (tid < 64 * 192) {  // Wcat1 = [Wm1(16); We1(4); Ws1(16)] rows, pad K to 64
    int k = tid / 192, n = tid % 192;
    float v = 0.f;
    if (k < 16) v = Wm1[k * 192 + n];
    else if (k < 20) v = We1[(k - 16) * 192 + n];
    else if (k < 36) v = Ws1[(k - 20) * 192 + n];
    Wp1[((k >> 3) * 192 + n) * 8 + (k & 7)] = f2bf(v);
  }
  if (tid < 224 * 208) {  // W_msg2, pad K 208->224
    int k = tid / 208, n = tid % 208;
    float v = (k < 208) ? Wm2[k * 208 + n] : 0.f;
    Wp2[((k >> 3) * 208 + n) * 8 + (k & 7)] = f2bf(v);
  }
  if (tid < N) {  // batch sorted -> unique writers
    int b = batch[tid];
    if (tid == 0 || batch[tid - 1] != b) gstart[b] = tid;
    if (tid == N - 1 || batch[tid + 1] != b) gend[b] = tid;
  }
}

// ---- pack W_l1 (1248x624) to bf16 B-frag layout ----
__global__ void pack1_k(const float* __restrict__ W1, u16* __restrict__ Wp3) {
  int tid = blockIdx.x * 256 + threadIdx.x;
  if (tid >= 1248 * 624) return;
  int k = tid / 624, n = tid % 624;
  Wp3[((size_t)(k >> 3) * 624 + n) * 8 + (k & 7)] = f2bf(W1[(size_t)k * 624 + n]);
}

// ---- CSR build: count -> scan -> scatter ----
__global__ void count_k(const int* __restrict__ ei, int* __restrict__ deg, int E) {
  int e = blockIdx.x * 256 + threadIdx.x;
  if (e >= E) return;
  atomicAdd(&deg[ei[E + e]], 1);
}

__global__ void scanA_k(const int* __restrict__ deg, int* __restrict__ bsum, int N) {
  __shared__ int sh[256];
  int t = threadIdx.x;
  int i = blockIdx.x * 256 + t;
  sh[t] = (i < N) ? deg[i] : 0;
  __syncthreads();
  for (int off = 128; off > 0; off >>= 1) {
    if (t < off) sh[t] += sh[t + off];
    __syncthreads();
  }
  if (t == 0) bsum[blockIdx.x] = sh[0];
}

__global__ void scanB_k(int* __restrict__ bsum, int nb) {  // nb <= 256, 1 block
  __shared__ int sh[256];
  int t = threadIdx.x;
  int v = (t < nb) ? bsum[t] : 0;
  sh[t] = v;
  __syncthreads();
  for (int off = 1; off < 256; off <<= 1) {
    int u = (t >= off) ? sh[t - off] : 0;
    __syncthreads();
    sh[t] += u;
    __syncthreads();
  }
  if (t < nb) bsum[t] = sh[t] - v;  // exclusive
}

__global__ void scanC_k(const int* __restrict__ deg, const int* __restrict__ bsum,
                        int* __restrict__ rowptr, int* __restrict__ cur, int N) {
  __shared__ int sh[256];
  int t = threadIdx.x;
  int i = blockIdx.x * 256 + t;
  int d = (i < N) ? deg[i] : 0;
  sh[t] = d;
  __syncthreads();
  for (int off = 1; off < 256; off <<= 1) {
    int u = (t >= off) ? sh[t - off] : 0;
    __syncthreads();
    sh[t] += u;
    __syncthreads();
  }
  int excl = sh[t] - d + bsum[blockIdx.x];
  if (i < N) {
    rowptr[i] = excl;
    cur[i] = excl;
    if (i == N - 1) rowptr[N] = excl + d;
  }
}

__global__ void scatter_k(const int* __restrict__ ei, int* __restrict__ cur,
                          int2* __restrict__ se, int E) {
  int e = blockIdx.x * 256 + threadIdx.x;
  if (e >= E) return;
  int s = ei[e], d = ei[E + e];
  int slot = atomicAdd(&cur[d], 1);
  se[slot] = make_int2(s, e);
}

// ---- gather pass 1: 4 lanes per node, quad shuffle-reduce ---- block=256
__global__ void gather1_k(const int2* __restrict__ se, const int* __restrict__ rowptr,
                          const float* __restrict__ x, const float* __restrict__ ea,
                          float* __restrict__ acc1, int N) {
  int tid = blockIdx.x * 256 + threadIdx.x;
  int n = tid >> 2, q = tid & 3;
  if (n >= N) return;
  int j0 = rowptr[n], j1 = rowptr[n + 1];
  float4 a0 = {0, 0, 0, 0}, a1 = a0, a2 = a0, a3 = a0, a4 = a0;
  for (int j = j0 + q; j < j1; j += 4) {
    int2 p = se[j];
    const float4* xs = (const float4*)(x + (size_t)p.x * 16);
    float4 w = *(const float4*)(ea + (size_t)p.y * 4);
    add4(a0, xs[0]); add4(a1, xs[1]); add4(a2, xs[2]); add4(a3, xs[3]); add4(a4, w);
  }
  float v[24] = {a0.x, a0.y, a0.z, a0.w, a1.x, a1.y, a1.z, a1.w,
                 a2.x, a2.y, a2.z, a2.w, a3.x, a3.y, a3.z, a3.w,
                 a4.x, a4.y, a4.z, a4.w, (float)(j1 - j0), 0.f, 0.f, 0.f};
#pragma unroll
  for (int i = 0; i < 20; ++i) {
    v[i] += __shfl_xor(v[i], 1);
    v[i] += __shfl_xor(v[i], 2);
  }
  float4* out = (float4*)(acc1 + (size_t)n * 24);
  out[q] = make_float4(v[q * 4], v[q * 4 + 1], v[q * 4 + 2], v[q * 4 + 3]);
  if (q < 2) out[4 + q] = make_float4(v[16 + q * 4], v[17 + q * 4], v[18 + q * 4], v[19 + q * 4]);
}

// ---- gather pass 2: acc2[n] = sum over in-edges of acc1[src][0..21) ---- block=256
__global__ void gather2_k(const int2* __restrict__ se, const int* __restrict__ rowptr,
                          const float* __restrict__ acc1, float* __restrict__ acc2, int N) {
  int tid = blockIdx.x * 256 + threadIdx.x;
  int n = tid >> 2, q = tid & 3;
  if (n >= N) return;
  int j0 = rowptr[n], j1 = rowptr[n + 1];
  float4 a0 = {0, 0, 0, 0}, a1 = a0, a2 = a0, a3 = a0, a4 = a0;
  float dg = 0.f;
  for (int j = j0 + q; j < j1; j += 4) {
    int s = se[j].x;
    const float4* ap = (const float4*)(acc1 + (size_t)s * 24);
    float4 t5 = ap[5];
    add4(a0, ap[0]); add4(a1, ap[1]); add4(a2, ap[2]); add4(a3, ap[3]); add4(a4, ap[4]);
    dg += t5.x;
  }
  float v[24] = {a0.x, a0.y, a0.z, a0.w, a1.x, a1.y, a1.z, a1.w,
                 a2.x, a2.y, a2.z, a2.w, a3.x, a3.y, a3.z, a3.w,
                 a4.x, a4.y, a4.z, a4.w, dg, 0.f, 0.f, 0.f};
#pragma unroll
  for (int i = 0; i < 21; ++i) {
    v[i] += __shfl_xor(v[i], 1);
    v[i] += __shfl_xor(v[i], 2);
  }
  float4* out = (float4*)(acc2 + (size_t)n * 24);
  out[q] = make_float4(v[q * 4], v[q * 4 + 1], v[q * 4 + 2], v[q * 4 + 3]);
  if (q < 2) out[4 + q] = make_float4(v[16 + q * 4], v[17 + q * 4], v[18 + q * 4], v[19 + q * 4]);
}

// ---- U1 build (bf16 [sx,sea,x] pad 64) ---- flat, block=256
__global__ void u1_k(const float* __restrict__ acc1, const float* __restrict__ x,
                     u16* __restrict__ U, int N) {
  int tid = blockIdx.x * 256 + threadIdx.x;
  if (tid >= N * 64) return;
  int n = tid >> 6, t = tid & 63;
  float v = 0.f;
  if (t < 20) v = acc1[(size_t)n * 24 + t];
  else if (t < 36) v = x[(size_t)n * 16 + (t - 20)];
  U[tid] = f2bf(v);
}

// ---- U2 build (bf16 [sx2,sea2,sx] pad 64) + V tail cols [192..224) ---- flat
__global__ void u2v_k(const float* __restrict__ acc1, const float* __restrict__ acc2,
                      u16* __restrict__ U, u16* __restrict__ V, int N) {
  int tid = blockIdx.x * 256 + threadIdx.x;
  if (tid >= N * 64) return;
  int n = tid >> 6, t = tid & 63;
  float v = 0.f;
  if (t < 20) v = acc2[(size_t)n * 24 + t];
  else if (t < 36) v = acc1[(size_t)n * 24 + (t - 20)];
  U[tid] = f2bf(v);
  if (t < 32) {
    float w = (t < 16) ? acc1[(size_t)n * 24 + t] : 0.f;
    V[(size_t)n * 224 + 192 + t] = f2bf(w);
  }
}

// ---- GEMM1: h1pre = U@Wp1 + deg*(bm1+be1) + bs1 ---- block=256 (4 waves), B in LDS
__global__ void __launch_bounds__(256) gemm1_k(
    const u16* __restrict__ A, const u16* __restrict__ Bp, const float* __restrict__ acc1,
    const float* __restrict__ bm1, const float* __restrict__ be1,
    const float* __restrict__ bs1, float* __restrict__ h1pre, int MT) {
  __shared__ u16 Bs[8 * (192 * 8 + 8)];  // 24.7 KB
  int tid = threadIdx.x;
  stageB(Bp, Bs, 8, 0, 192, tid);
  __syncthreads();
  int lane = tid & 63;
  int mt = blockIdx.x * 4 + (tid >> 6);
  bool valid = mt < MT;
  int mtc = valid ? mt : MT - 1;
  int rc = lane & 15, qd = lane >> 4;
  f32x4 acc[12];
#pragma unroll
  for (int i = 0; i < 12; ++i) acc[i] = {0.f, 0.f, 0.f, 0.f};
  const u16* Ap = A + (size_t)(mtc * 16 + rc) * 64 + qd * 8;
#pragma unroll
  for (int kb = 0; kb < 2; ++kb) {
    short8 av = *(const short8*)(Ap + kb * 32);
#pragma unroll
    for (int nt = 0; nt < 12; ++nt) {
      short8 bv = *(const short8*)(Bs + (size_t)(kb * 4 + qd) * (192 * 8 + 8) + (nt * 16 + rc) * 8);
      acc[nt] = __builtin_amdgcn_mfma_f32_16x16x32_bf16(av, bv, acc[nt], 0, 0, 0);
    }
  }
  if (!valid) return;
  int m0 = mt * 16 + qd * 4;
  float deg[4];
#pragma unroll
  for (int r = 0; r < 4; ++r) deg[r] = acc1[(size_t)(m0 + r) * 24 + 20];
#pragma unroll
  for (int nt = 0; nt < 12; ++nt) {
    int col = nt * 16 + rc;
    float bb = bm1[col] + be1[col], bs = bs1[col];
#pragma unroll
    for (int r = 0; r < 4; ++r)
      h1pre[(size_t)(m0 + r) * 192 + col] = acc[nt][r] + deg[r] * bb + bs;
  }
}

// ---- GEMMQ2: V[.,0..192) = bf16((U2@Wp1 + sdeg*bsum + deg*bself)*s1 + deg*t1) ----
__global__ void __launch_bounds__(256) gemmq2_k(
    const u16* __restrict__ A, const u16* __restrict__ Bp, const float* __restrict__ acc1,
    const float* __restrict__ acc2, const float* __restrict__ bm1,
    const float* __restrict__ be1, const float* __restrict__ bs1,
    const float* __restrict__ st, u16* __restrict__ V, int MT) {
  __shared__ u16 Bs[8 * (192 * 8 + 8)];
  int tid = threadIdx.x;
  stageB(Bp, Bs, 8, 0, 192, tid);
  __syncthreads();
  int lane = tid & 63;
  int mt = blockIdx.x * 4 + (tid >> 6);
  bool valid = mt < MT;
  int mtc = valid ? mt : MT - 1;
  int rc = lane & 15, qd = lane >> 4;
  f32x4 acc[12];
#pragma unroll
  for (int i = 0; i < 12; ++i) acc[i] = {0.f, 0.f, 0.f, 0.f};
  const u16* Ap = A + (size_t)(mtc * 16 + rc) * 64 + qd * 8;
#pragma unroll
  for (int kb = 0; kb < 2; ++kb) {
    short8 av = *(const short8*)(Ap + kb * 32);
#pragma unroll
    for (int nt = 0; nt < 12; ++nt) {
      short8 bv = *(const short8*)(Bs + (size_t)(kb * 4 + qd) * (192 * 8 + 8) + (nt * 16 + rc) * 8);
      acc[nt] = __builtin_amdgcn_mfma_f32_16x16x32_bf16(av, bv, acc[nt], 0, 0, 0);
    }
  }
  if (!valid) return;
  int m0 = mt * 16 + qd * 4;
  float deg[4], sdeg[4];
#pragma unroll
  for (int r = 0; r < 4; ++r) {
    deg[r] = acc1[(size_t)(m0 + r) * 24 + 20];
    sdeg[r] = acc2[(size_t)(m0 + r) * 24 + 20];
  }
#pragma unroll
  for (int nt = 0; nt < 12; ++nt) {
    int col = nt * 16 + rc;
    float sc = st[col], sh = st[192 + col];
    float bsum = bm1[col] + be1[col], bself = bs1[col];
#pragma unroll
    for (int r = 0; r < 4; ++r) {
      float qv = acc[nt][r] + sdeg[r] * bsum + deg[r] * bself;
      V[(size_t)(m0 + r) * 224 + col] = f2bf(qv * sc + deg[r] * sh);
    }
  }
}

// ---- GEMM2 fused: h2pre = V@Wp2 + e.We2 + deg*(bm2+be2) + x1 ---- block=256, B in LDS (2 stages)
__global__ void __launch_bounds__(256) gemm2_k(
    const u16* __restrict__ A, const u16* __restrict__ Bp, const float* __restrict__ acc1,
    const float* __restrict__ h1pre, const float* __restrict__ x,
    const float* __restrict__ We2, const float* __restrict__ bm2,
    const float* __restrict__ be2, const float* __restrict__ st,
    float* __restrict__ h2pre, int MT) {
  __shared__ u16 Bs[16 * (208 * 8 + 8)];  // 53.5 KB
  const int GS = 208 * 8 + 8;
  int tid = threadIdx.x;
  int lane = tid & 63;
  int mt = blockIdx.x * 4 + (tid >> 6);
  bool valid = mt < MT;
  int mtc = valid ? mt : MT - 1;
  int rc = lane & 15, qd = lane >> 4;
  f32x4 acc[13];
#pragma unroll
  for (int i = 0; i < 13; ++i) acc[i] = {0.f, 0.f, 0.f, 0.f};
  const u16* Ap = A + (size_t)(mtc * 16 + rc) * 224 + qd * 8;
  stageB(Bp, Bs, 16, 0, 208, tid);
  __syncthreads();
#pragma unroll
  for (int kb = 0; kb < 4; ++kb) {
    short8 av = *(const short8*)(Ap + kb * 32);
#pragma unroll
    for (int nt = 0; nt < 13; ++nt) {
      short8 bv = *(const short8*)(Bs + (size_t)(kb * 4 + qd) * GS + (nt * 16 + rc) * 8);
      acc[nt] = __builtin_amdgcn_mfma_f32_16x16x32_bf16(av, bv, acc[nt], 0, 0, 0);
    }
  }
  __syncthreads();
  stageB(Bp, Bs, 12, 16, 208, tid);
  __syncthreads();
#pragma unroll
  for (int kb = 4; kb < 7; ++kb) {
    short8 av = *(const short8*)(Ap + kb * 32);
#pragma unroll
    for (int nt = 0; nt < 13; ++nt) {
      short8 bv = *(const short8*)(Bs + (size_t)((kb - 4) * 4 + qd) * GS + (nt * 16 + rc) * 8);
      acc[nt] = __builtin_amdgcn_mfma_f32_16x16x32_bf16(av, bv, acc[nt], 0, 0, 0);
    }
  }
  if (!valid) return;
  int m0 = mt * 16 + qd * 4;
  float e0[4], e1[4], e2[4], e3[4], deg[4];
#pragma unroll
  for (int r = 0; r < 4; ++r) {
    const float* a = acc1 + (size_t)(m0 + r) * 24;
    e0[r] = a[16]; e1[r] = a[17]; e2[r] = a[18]; e3[r] = a[19]; deg[r] = a[20];
  }
#pragma unroll
  for (int nt = 0; nt < 13; ++nt) {
    int col = nt * 16 + rc;
    float w0 = We2[col], w1 = We2[208 + col], w2 = We2[416 + col], w3 = We2[624 + col];
    float bb = bm2[col] + be2[col];
    bool c192 = col < 192;
    float sc = c192 ? st[col] : 0.f;
    float sh = c192 ? st[192 + col] : 0.f;
#pragma unroll
    for (int r = 0; r < 4; ++r) {
      int m = m0 + r;
      float x1 = c192 ? (h1pre[(size_t)m * 192 + col] * sc + sh)
                      : x[(size_t)m * 16 + (col - 192)];
      h2pre[(size_t)m * 208 + col] =
          acc[nt][r] + e0[r] * w0 + e1[r] * w1 + e2[r] * w2 + e3[r] * w3 + deg[r] * bb + x1;
    }
  }
}

// ---- BN column reduce ---- block=256, grid=ceil(N/128)
__global__ void bnred_k(const float* __restrict__ h, int N, int C, float* __restrict__ sums) {
  int t = threadIdx.x;
  if (t >= C) return;
  int r0 = blockIdx.x * 128;
  int r1 = min(r0 + 128, N);
  float s = 0.f, ss = 0.f;
  for (int n = r0; n < r1; ++n) {
    float v = h[(size_t)n * C + t];
    s += v;
    ss += v * v;
  }
  atomAddF(&sums[t], s);
  atomAddF(&sums[C + t], ss);
}

__global__ void bnfin_k(const float* __restrict__ sums, const float* __restrict__ g,
                        const float* __restrict__ be, int C, float Ninv, float* __restrict__ st) {
  int t = threadIdx.x;
  if (t >= C) return;
  float m = sums[t] * Ninv;
  float v = sums[C + t] * Ninv - m * m;
  float s = g[t] * rsqrtf(v + 1e-5f);
  st[t] = s;
  st[C + t] = be[t] - m * s;
}

// ---- pooling: x2 on the fly, sum + max per graph ---- grid=(64,8), block=256
__global__ void pool_k(const float* __restrict__ h2pre, const float* __restrict__ h1pre,
                       const float* __restrict__ x, const float* __restrict__ st,
                       const int* __restrict__ gstart, const int* __restrict__ gend,
                       float* __restrict__ psum, u32* __restrict__ pmaxu) {
  int b = blockIdx.x, sub = blockIdx.y;
  int s0 = gstart[b], e0 = gend[b];
  if (s0 > e0) return;
  int cnt = e0 - s0 + 1;
  int per = (cnt + 7) >> 3;
  int n0 = s0 + sub * per;
  int n1 = min(n0 + per, e0 + 1);
  if (n0 >= n1) return;
  const float* st1 = st;
  const float* st2 = st + 384;
  for (int f = threadIdx.x; f < 416; f += 256) {
    const float* src;
    int stride;
    float sc, sh;
    if (f < 208) { src = h2pre + f; stride = 208; sc = st2[f]; sh = st2[208 + f]; }
    else if (f < 400) { int j = f - 208; src = h1pre + j; stride = 192; sc = st1[j]; sh = st1[192 + j]; }
    else { src = x + (f - 400); stride = 16; sc = 1.f; sh = 0.f; }
    float s = 0.f, mx = -3.4e38f;
    for (int n = n0; n < n1; ++n) {
      float v = src[(size_t)n * stride] * sc + sh;
      s += v;
      mx = fmaxf(mx, v);
    }
    atomAddF(&psum[b * 416 + f], s);
    atomicMax(&pmaxu[b * 416 + f], fflip(mx));
  }
}

// ---- pooled -> bf16 A matrix [64 x 1248] ---- grid=64, block=256
__global__ void pooledprep_k(const float* __restrict__ psum, const u32* __restrict__ pmaxu,
                             const int* __restrict__ gstart, const int* __restrict__ gend,
                             u16* __restrict__ Apool) {
  int b = blockIdx.x, t = threadIdx.x;
  int cnt = gend[b] - gstart[b] + 1;
  float inv = 1.f / (float)max(cnt, 1);
  for (int f = t; f < 416; f += 256) {
    float s = psum[b * 416 + f];
    float m = funflip(pmaxu[b * 416 + f]);
    u16* row = Apool + (size_t)b * 1248;
    row[f] = f2bf(s);
    row[416 + f] = f2bf((cnt > 0) ? m : 0.f);
    row[832 + f] = f2bf(s * inv);
  }
}

// ---- MLP layer 1 via MFMA: hid = PReLU(Apool @ W1 + b1) ---- grid=(4,39), block=64
__global__ void mlpgemm_k(const u16* __restrict__ A, const u16* __restrict__ Bp,
                          const float* __restrict__ b1, const float* __restrict__ al,
                          float* __restrict__ hid) {
  int lane = threadIdx.x;
  int mt = blockIdx.x, nt = blockIdx.y;
  int rc = lane & 15, qd = lane >> 4;
  f32x4 acc = {0.f, 0.f, 0.f, 0.f};
  const u16* Ap = A + (size_t)(mt * 16 + rc) * 1248 + qd * 8;
  const u16* Bq = Bp + (size_t)(qd * 624 + nt * 16 + rc) * 8;
  for (int kb = 0; kb < 39; ++kb) {
    short8 av = *(const short8*)(Ap + kb * 32);
    short8 bv = *(const short8*)(Bq + (size_t)kb * 4 * 624 * 8);
    acc = __builtin_amdgcn_mfma_f32_16x16x32_bf16(av, bv, acc, 0, 0, 0);
  }
  int col = nt * 16 + rc;
  float bb = b1[col], alpha = al[0];
  int m0 = mt * 16 + qd * 4;
#pragma unroll
  for (int r = 0; r < 4; ++r) {
    float v = acc[r] + bb;
    hid[(size_t)(m0 + r) * 624 + col] = (v >= 0.f) ? v : alpha * v;
  }
}

// ---- logits + log_softmax ---- grid=64, block=64 (one wave)
__global__ void head_k(const float* __restrict__ hid, const float* __restrict__ W2,
                       const float* __restrict__ b2, float* __restrict__ out) {
  int b = blockIdx.x, t = threadIdx.x;
  float p0 = 0.f, p1 = 0.f;
  for (int k = t; k < 624; k += 64) {
    float h = hid[(size_t)b * 624 + k];
    p0 += h * W2[k * 2];
    p1 += h * W2[k * 2 + 1];
  }
#pragma unroll
  for (int off = 32; off > 0; off >>= 1) {
    p0 += __shfl_down(p0, off);
    p1 += __shfl_down(p1, off);
  }
  if (t == 0) {
    float l0 = p0 + b2[0], l1 = p1 + b2[1];
    float m = fmaxf(l0, l1);
    float lse = m + logf(expf(l0 - m) + expf(l1 - m));
    out[b * 2] = l0 - lse;
    out[b * 2 + 1] = l1 - lse;
  }
}

extern "C" void kernel_launch(void* const* d_in, const int* in_sizes, int n_in,
                              void* d_out, int out_size, void* d_ws, size_t ws_size,
                              hipStream_t stream) {
  const float* x = (const float*)d_in[0];
  const int* ei = (const int*)d_in[1];
  const float* ea = (const float*)d_in[2];
  const int* batch = (const int*)d_in[3];
  const float* Wm1 = (const float*)d_in[4];
  const float* bm1 = (const float*)d_in[5];
  const float* We1 = (const float*)d_in[6];
  const float* be1 = (const float*)d_in[7];
  const float* Ws1 = (const float*)d_in[8];
  const float* bs1 = (const float*)d_in[9];
  const float* g1 = (const float*)d_in[10];
  const float* bta1 = (const float*)d_in[11];
  const float* Wm2 = (const float*)d_in[12];
  const float* bm2 = (const float*)d_in[13];
  const float* We2 = (const float*)d_in[14];
  const float* be2 = (const float*)d_in[15];
  const float* g2 = (const float*)d_in[16];
  const float* bta2 = (const float*)d_in[17];
  const float* Wl1 = (const float*)d_in[18];
  const float* bl1 = (const float*)d_in[19];
  const float* alpha = (const float*)d_in[20];
  const float* Wl2 = (const float*)d_in[21];
  const float* bl2 = (const float*)d_in[22];
  float* out = (float*)d_out;

  const int N = in_sizes[3];      // 50000
  const int E = in_sizes[2] / 4;  // 800000
  const int MT = N / 16;          // 3125
  const int nb = (N + 255) / 256; // scan blocks (<=256 required)

  float* ws = (float*)d_ws;
  size_t o = 0;
  float* acc1 = ws + o;  o += (size_t)N * 24;
  float* acc2 = ws + o;  o += (size_t)N * 24;
  float* h1pre = ws + o; o += (size_t)N * 192;
  float* h2pre = ws + o; o += (size_t)N * 208;   // also aliased as CSR edge list (se)
  u16* U = (u16*)(ws + o);  o += (size_t)N * 32;   // N*64 u16
  u16* V = (u16*)(ws + o);  o += (size_t)N * 112;  // N*224 u16
  u16* Wp1 = (u16*)(ws + o); o += 6144;            // 64*192 u16
  u16* Wp2 = (u16*)(ws + o); o += 23296;           // 224*208 u16
  u16* Wp3 = (u16*)(ws + o); o += 389376;          // 1248*624 u16
  u16* Apool = (u16*)(ws + o); o += 39936;         // 64*1248 u16
  float* hid = ws + o;   o += 64 * 624;
  float* bns = ws + o;   o += 800;                 // bn1 sums(384) | bn2 sums(416)
  float* st = ws + o;    o += 800;                 // s1t1(384) | s2t2(416)
  float* psum = ws + o;  o += 64 * 416;
  u32* pmaxu = (u32*)(ws + o); o += 64 * 416;
  int* gstart = (int*)(ws + o); o += 64;
  int* gend = (int*)(ws + o);   o += 64;
  int* deg = (int*)(ws + o);    o += N;
  int* rowptr = (int*)(ws + o); o += N + 1;
  int* cur = (int*)(ws + o);    o += N + 1;
  int* bsum = (int*)(ws + o);   o += 256;
  int2* se = (int2*)h2pre;  // E int2 = 6.4 MB <= N*208*4B; h2pre written later

  hipMemsetAsync(deg, 0, (size_t)N * sizeof(int), stream);
  hipMemsetAsync(bns, 0, (size_t)(800 + 800 + 2 * 64 * 416) * sizeof(float), stream);

  int sb = (N + 255) / 256;  // 196 >= 224*208/256
  setup_k<<<sb, 256, 0, stream>>>(Wm1, We1, Ws1, Wm2, batch, Wp1, Wp2, gstart, gend, N);
  pack1_k<<<(1248 * 624 + 255) / 256, 256, 0, stream>>>(Wl1, Wp3);
  // CSR build
  count_k<<<(E + 255) / 256, 256, 0, stream>>>(ei, deg, E);
  scanA_k<<<nb, 256, 0, stream>>>(deg, bsum, N);
  scanB_k<<<1, 256, 0, stream>>>(bsum, nb);
  scanC_k<<<nb, 256, 0, stream>>>(deg, bsum, rowptr, cur, N);
  scatter_k<<<(E + 255) / 256, 256, 0, stream>>>(ei, cur, se, E);
  // layer 1
  gather1_k<<<(N + 63) / 64, 256, 0, stream>>>(se, rowptr, x, ea, acc1, N);
  u1_k<<<(N * 64 + 255) / 256, 256, 0, stream>>>(acc1, x, U, N);
  gemm1_k<<<(MT + 3) / 4, 256, 0, stream>>>(U, Wp1, acc1, bm1, be1, bs1, h1pre, MT);
  bnred_k<<<(N + 127) / 128, 256, 0, stream>>>(h1pre, N, 192, bns);
  bnfin_k<<<1, 256, 0, stream>>>(bns, g1, bta1, 192, 1.f / (float)N, st);
  // layer 2
  gather2_k<<<(N + 63) / 64, 256, 0, stream>>>(se, rowptr, acc1, acc2, N);
  u2v_k<<<(N * 64 + 255) / 256, 256, 0, stream>>>(acc1, acc2, U, V, N);
  gemmq2_k<<<(MT + 3) / 4, 256, 0, stream>>>(U, Wp1, acc1, acc2, bm1, be1, bs1, st, V, MT);
  gemm2_k<<<(MT + 3) / 4, 256, 0, stream>>>(V, Wp2, acc1, h1pre, x, We2, bm2, be2, st, h2pre, MT);
  bnred_k<<<(N + 127) / 128, 256, 0, stream>>>(h2pre, N, 208, bns + 384);
  bnfin_k<<<1, 256, 0, stream>>>(bns + 384, g2, bta2, 208, 1.f / (float)N, st + 384);
  // head
  pool_k<<<dim3(64, 8), 256, 0, stream>>>(h2pre, h1pre, x, st, gstart, gend, psum, pmaxu);
  pooledprep_k<<<64, 256, 0, stream>>>(psum, pmaxu, gstart, gend, Apool);
  mlpgemm_k<<<dim3(4, 39), 64, 0, stream>>>(Apool, Wp3, bl1, alpha, hid);
  head_k<<<64, 64, 0, stream>>>(hid, Wl2, bl2, out);
}

// Round 7
// 477.402 us; speedup vs baseline: 1.1989x; 1.1989x over previous
//
#include <hip/hip_runtime.h>

typedef __attribute__((ext_vector_type(8))) short short8;
typedef __attribute__((ext_vector_type(4))) float f32x4;
typedef unsigned short u16;
typedef unsigned int u32;

__device__ __forceinline__ u16 f2bf(float f) {
  u32 u = __float_as_uint(f);
  u = (u + 0x7fffu + ((u >> 16) & 1u)) >> 16;
  return (u16)u;
}
__device__ __forceinline__ void atomAddF(float* p, float v) { unsafeAtomicAdd(p, v); }
__device__ __forceinline__ u32 fflip(float f) {
  u32 u = __float_as_uint(f);
  return (u & 0x80000000u) ? ~u : (u | 0x80000000u);
}
__device__ __forceinline__ float funflip(u32 u) {
  return __uint_as_float((u & 0x80000000u) ? (u ^ 0x80000000u) : ~u);
}
__device__ __forceinline__ void add4(float4& a, const float4 b) {
  a.x += b.x; a.y += b.y; a.z += b.z; a.w += b.w;
}

// ---- setup: pack bf16 weights + graph bounds + zero deg/bns ----
__global__ void setup_k(const float* __restrict__ Wm1, const float* __restrict__ We1,
                        const float* __restrict__ Ws1, const float* __restrict__ Wm2,
                        const int* __restrict__ batch, u16* __restrict__ Wp1,
                        u16* __restrict__ Wp2, int* __restrict__ gstart,
                        int* __restrict__ gend, int* __restrict__ deg,
                        float* __restrict__ bns, int N) {
  int tid = blockIdx.x * 256 + threadIdx.x;
  if (tid < 64 * 192) {  // Wcat1 = [Wm1(16); We1(4); Ws1(16)] rows, pad K to 64
    int k = tid / 192, n = tid % 192;
    float v = 0.f;
    if (k < 16) v = Wm1[k * 192 + n];
    else if (k < 20) v = We1[(k - 16) * 192 + n];
    else if (k < 36) v = Ws1[(k - 20) * 192 + n];
    Wp1[((k >> 3) * 192 + n) * 8 + (k & 7)] = f2bf(v);
  }
  if (tid < 224 * 208) {  // W_msg2, pad K 208->224
    int k = tid / 208, n = tid % 208;
    float v = (k < 208) ? Wm2[k * 208 + n] : 0.f;
    Wp2[((k >> 3) * 208 + n) * 8 + (k & 7)] = f2bf(v);
  }
  if (tid < N) {
    int b = batch[tid];
    if (tid == 0 || batch[tid - 1] != b) gstart[b] = tid;
    if (tid == N - 1 || batch[tid + 1] != b) gend[b] = tid;
    deg[tid] = 0;
  }
  if (tid < 800) bns[tid] = 0.f;
}

// ---- pack W_l1 to bf16 B-frag layout + zero psum/pmaxu ----
__global__ void pack1_k(const float* __restrict__ W1, u16* __restrict__ Wp3,
                        float* __restrict__ psum, u32* __restrict__ pmaxu) {
  int tid = blockIdx.x * 256 + threadIdx.x;
  if (tid < 64 * 416) psum[tid] = 0.f;
  else if (tid < 2 * 64 * 416) pmaxu[tid - 64 * 416] = 0u;  // 0 < fflip(any finite)
  if (tid >= 1248 * 624) return;
  int k = tid / 624, n = tid % 624;
  Wp3[((size_t)(k >> 3) * 624 + n) * 8 + (k & 7)] = f2bf(W1[(size_t)k * 624 + n]);
}

// ---- CSR build ----
__global__ void count_k(const int* __restrict__ ei, int* __restrict__ deg, int E) {
  int e = blockIdx.x * 256 + threadIdx.x;
  if (e >= E) return;
  atomicAdd(&deg[ei[E + e]], 1);
}

__global__ void scanA_k(const int* __restrict__ deg, int* __restrict__ bsum, int N) {
  __shared__ int sh[256];
  int t = threadIdx.x;
  int i = blockIdx.x * 256 + t;
  sh[t] = (i < N) ? deg[i] : 0;
  __syncthreads();
  for (int off = 128; off > 0; off >>= 1) {
    if (t < off) sh[t] += sh[t + off];
    __syncthreads();
  }
  if (t == 0) bsum[blockIdx.x] = sh[0];
}

// merged: scan block sums in-block, then local exclusive scan
__global__ void scanC_k(const int* __restrict__ deg, const int* __restrict__ bsum,
                        int* __restrict__ rowptr, int* __restrict__ cur, int N, int nb) {
  __shared__ int sb2[256];
  __shared__ int sh[256];
  int t = threadIdx.x;
  int bv = (t < nb) ? bsum[t] : 0;
  sb2[t] = bv;
  __syncthreads();
  for (int off = 1; off < 256; off <<= 1) {
    int u = (t >= off) ? sb2[t - off] : 0;
    __syncthreads();
    sb2[t] += u;
    __syncthreads();
  }
  int bpref = (blockIdx.x == 0) ? 0 : sb2[blockIdx.x - 1];
  int i = blockIdx.x * 256 + t;
  int d = (i < N) ? deg[i] : 0;
  sh[t] = d;
  __syncthreads();
  for (int off = 1; off < 256; off <<= 1) {
    int u = (t >= off) ? sh[t - off] : 0;
    __syncthreads();
    sh[t] += u;
    __syncthreads();
  }
  int excl = sh[t] - d + bpref;
  if (i < N) {
    rowptr[i] = excl;
    cur[i] = excl;
    if (i == N - 1) rowptr[N] = excl + d;
  }
}

__global__ void scatter_k(const int* __restrict__ ei, int* __restrict__ cur,
                          int2* __restrict__ se, int E) {
  int e = blockIdx.x * 256 + threadIdx.x;
  if (e >= E) return;
  int s = ei[e], d = ei[E + e];
  int slot = atomicAdd(&cur[d], 1);
  se[slot] = make_int2(s, e);
}

// ---- gather pass 1 (+ fused U1 build): 4 lanes/node ---- block=256
__global__ void gather1_k(const int2* __restrict__ se, const int* __restrict__ rowptr,
                          const float* __restrict__ x, const float* __restrict__ ea,
                          float* __restrict__ acc1, u16* __restrict__ U, int N) {
  int tid = blockIdx.x * 256 + threadIdx.x;
  int n = tid >> 2, q = tid & 3;
  if (n >= N) return;
  int j0 = rowptr[n], j1 = rowptr[n + 1];
  float4 a0 = {0, 0, 0, 0}, a1 = a0, a2 = a0, a3 = a0, a4 = a0;
  for (int j = j0 + q; j < j1; j += 4) {
    int2 p = se[j];
    const float4* xs = (const float4*)(x + (size_t)p.x * 16);
    float4 w = *(const float4*)(ea + (size_t)p.y * 4);
    add4(a0, xs[0]); add4(a1, xs[1]); add4(a2, xs[2]); add4(a3, xs[3]); add4(a4, w);
  }
  float v[24] = {a0.x, a0.y, a0.z, a0.w, a1.x, a1.y, a1.z, a1.w,
                 a2.x, a2.y, a2.z, a2.w, a3.x, a3.y, a3.z, a3.w,
                 a4.x, a4.y, a4.z, a4.w, (float)(j1 - j0), 0.f, 0.f, 0.f};
#pragma unroll
  for (int i = 0; i < 20; ++i) {
    v[i] += __shfl_xor(v[i], 1);
    v[i] += __shfl_xor(v[i], 2);
  }
  float4* out = (float4*)(acc1 + (size_t)n * 24);
  out[q] = make_float4(v[q * 4], v[q * 4 + 1], v[q * 4 + 2], v[q * 4 + 3]);
  if (q < 2) out[4 + q] = make_float4(v[16 + q * 4], v[17 + q * 4], v[18 + q * 4], v[19 + q * 4]);
  // fused U row: [v(20), x(16), 0...] -> 64 bf16; lane q writes u16[16q..16q+15]
  const float* xr = x + (size_t)n * 16;
  u32 w8[8];
#pragma unroll
  for (int j = 0; j < 8; ++j) {
    int t0 = q * 16 + 2 * j, t1 = t0 + 1;
    float f0 = (t0 < 20) ? v[t0] : ((t0 < 36) ? xr[t0 - 20] : 0.f);
    float f1 = (t1 < 20) ? v[t1] : ((t1 < 36) ? xr[t1 - 20] : 0.f);
    w8[j] = (u32)f2bf(f0) | ((u32)f2bf(f1) << 16);
  }
  uint4* Urow = (uint4*)(U + (size_t)n * 64);
  Urow[q * 2] = make_uint4(w8[0], w8[1], w8[2], w8[3]);
  Urow[q * 2 + 1] = make_uint4(w8[4], w8[5], w8[6], w8[7]);
}

// ---- gather pass 2 (+ fused U2 build + V tail) ---- block=256
__global__ void gather2_k(const int2* __restrict__ se, const int* __restrict__ rowptr,
                          const float* __restrict__ acc1, float* __restrict__ acc2,
                          u16* __restrict__ U, u16* __restrict__ V, int N) {
  int tid = blockIdx.x * 256 + threadIdx.x;
  int n = tid >> 2, q = tid & 3;
  if (n >= N) return;
  int j0 = rowptr[n], j1 = rowptr[n + 1];
  float4 a0 = {0, 0, 0, 0}, a1 = a0, a2 = a0, a3 = a0, a4 = a0;
  float dg = 0.f;
  for (int j = j0 + q; j < j1; j += 4) {
    int s = se[j].x;
    const float4* ap = (const float4*)(acc1 + (size_t)s * 24);
    float4 t5 = ap[5];
    add4(a0, ap[0]); add4(a1, ap[1]); add4(a2, ap[2]); add4(a3, ap[3]); add4(a4, ap[4]);
    dg += t5.x;
  }
  float v[24] = {a0.x, a0.y, a0.z, a0.w, a1.x, a1.y, a1.z, a1.w,
                 a2.x, a2.y, a2.z, a2.w, a3.x, a3.y, a3.z, a3.w,
                 a4.x, a4.y, a4.z, a4.w, dg, 0.f, 0.f, 0.f};
#pragma unroll
  for (int i = 0; i < 21; ++i) {
    v[i] += __shfl_xor(v[i], 1);
    v[i] += __shfl_xor(v[i], 2);
  }
  float4* out = (float4*)(acc2 + (size_t)n * 24);
  out[q] = make_float4(v[q * 4], v[q * 4 + 1], v[q * 4 + 2], v[q * 4 + 3]);
  if (q < 2) out[4 + q] = make_float4(v[16 + q * 4], v[17 + q * 4], v[18 + q * 4], v[19 + q * 4]);
  // fused U2 row: [v(20), acc1[n][0..15], 0...]
  const float* a1r = acc1 + (size_t)n * 24;
  u32 w8[8];
#pragma unroll
  for (int j = 0; j < 8; ++j) {
    int t0 = q * 16 + 2 * j, t1 = t0 + 1;
    float f0 = (t0 < 20) ? v[t0] : ((t0 < 36) ? a1r[t0 - 20] : 0.f);
    float f1 = (t1 < 20) ? v[t1] : ((t1 < 36) ? a1r[t1 - 20] : 0.f);
    w8[j] = (u32)f2bf(f0) | ((u32)f2bf(f1) << 16);
  }
  uint4* Urow = (uint4*)(U + (size_t)n * 64);
  Urow[q * 2] = make_uint4(w8[0], w8[1], w8[2], w8[3]);
  Urow[q * 2 + 1] = make_uint4(w8[4], w8[5], w8[6], w8[7]);
  // fused V tail cols [192..224): bf16(acc1[n][0..15]), pad 0
  u32 wv[4];
#pragma unroll
  for (int j = 0; j < 4; ++j) {
    int t0 = q * 8 + 2 * j;
    float f0 = (t0 < 16) ? a1r[t0] : 0.f;
    float f1 = (t0 + 1 < 16) ? a1r[t0 + 1] : 0.f;
    wv[j] = (u32)f2bf(f0) | ((u32)f2bf(f1) << 16);
  }
  ((uint4*)(V + (size_t)n * 224 + 192))[q] = make_uint4(wv[0], wv[1], wv[2], wv[3]);
}

// ---- GEMM1: h1pre = U@Wp1 + deg*(bm1+be1) + bs1, fused bn1 reduce ----
// grid (ceil(MT/4), 3), block 256; wave owns 1 m-tile x 4 n-tiles (cols y*64..y*64+63)
__global__ void __launch_bounds__(256) gemm1_k(
    const u16* __restrict__ A, const u16* __restrict__ Bp, const float* __restrict__ acc1,
    const float* __restrict__ bm1, const float* __restrict__ be1,
    const float* __restrict__ bs1, float* __restrict__ h1pre, float* __restrict__ bns,
    int MT) {
  __shared__ float lred[4][64][2];
  int tid = threadIdx.x, w = tid >> 6, lane = tid & 63;
  int rc = lane & 15, qd = lane >> 4;
  int mt = blockIdx.x * 4 + w;
  bool valid = mt < MT;
  int mtc = valid ? mt : MT - 1;
  int nt0 = blockIdx.y * 4;
  f32x4 acc[4];
#pragma unroll
  for (int i = 0; i < 4; ++i) acc[i] = {0.f, 0.f, 0.f, 0.f};
  const u16* Ap = A + (size_t)(mtc * 16 + rc) * 64 + qd * 8;
#pragma unroll
  for (int kb = 0; kb < 2; ++kb) {
    short8 av = *(const short8*)(Ap + kb * 32);
#pragma unroll
    for (int i = 0; i < 4; ++i) {
      short8 bv = *(const short8*)(Bp + (size_t)((kb * 4 + qd) * 192 + (nt0 + i) * 16 + rc) * 8);
      acc[i] = __builtin_amdgcn_mfma_f32_16x16x32_bf16(av, bv, acc[i], 0, 0, 0);
    }
  }
  int m0 = mtc * 16 + qd * 4;
  float deg4[4];
#pragma unroll
  for (int r = 0; r < 4; ++r) deg4[r] = acc1[(size_t)(m0 + r) * 24 + 20];
#pragma unroll
  for (int i = 0; i < 4; ++i) {
    int col = (nt0 + i) * 16 + rc;
    float bb = bm1[col] + be1[col], bsv = bs1[col];
    float ps = 0.f, pq = 0.f;
#pragma unroll
    for (int r = 0; r < 4; ++r) {
      float val = acc[i][r] + deg4[r] * bb + bsv;
      if (valid) h1pre[(size_t)(m0 + r) * 192 + col] = val;
      ps += val;
      pq += val * val;
    }
    if (!valid) { ps = 0.f; pq = 0.f; }
    ps += __shfl_xor(ps, 16); ps += __shfl_xor(ps, 32);
    pq += __shfl_xor(pq, 16); pq += __shfl_xor(pq, 32);
    if (qd == 0) { lred[w][i * 16 + rc][0] = ps; lred[w][i * 16 + rc][1] = pq; }
  }
  __syncthreads();
  if (tid < 128) {
    int c = tid & 63, part = tid >> 6;
    float s = lred[0][c][part] + lred[1][c][part] + lred[2][c][part] + lred[3][c][part];
    atomAddF(&bns[part * 192 + blockIdx.y * 64 + c], s);
  }
}

// ---- GEMMQ2: V[:,0..192) = bf16(bn1(U2@Wp1 + sdeg*bsum + deg*bself)) ---- grid (.,3)
__global__ void __launch_bounds__(256) gemmq2_k(
    const u16* __restrict__ A, const u16* __restrict__ Bp, const float* __restrict__ acc1,
    const float* __restrict__ acc2, const float* __restrict__ bm1,
    const float* __restrict__ be1, const float* __restrict__ bs1,
    const float* __restrict__ g1, const float* __restrict__ bta1,
    const float* __restrict__ bns, float Ninv, u16* __restrict__ V, int MT) {
  int tid = threadIdx.x, w = tid >> 6, lane = tid & 63;
  int rc = lane & 15, qd = lane >> 4;
  int mt = blockIdx.x * 4 + w;
  bool valid = mt < MT;
  int mtc = valid ? mt : MT - 1;
  int nt0 = blockIdx.y * 4;
  f32x4 acc[4];
#pragma unroll
  for (int i = 0; i < 4; ++i) acc[i] = {0.f, 0.f, 0.f, 0.f};
  const u16* Ap = A + (size_t)(mtc * 16 + rc) * 64 + qd * 8;
#pragma unroll
  for (int kb = 0; kb < 2; ++kb) {
    short8 av = *(const short8*)(Ap + kb * 32);
#pragma unroll
    for (int i = 0; i < 4; ++i) {
      short8 bv = *(const short8*)(Bp + (size_t)((kb * 4 + qd) * 192 + (nt0 + i) * 16 + rc) * 8);
      acc[i] = __builtin_amdgcn_mfma_f32_16x16x32_bf16(av, bv, acc[i], 0, 0, 0);
    }
  }
  if (!valid) return;
  int m0 = mtc * 16 + qd * 4;
  float deg4[4], sdeg[4];
#pragma unroll
  for (int r = 0; r < 4; ++r) {
    deg4[r] = acc1[(size_t)(m0 + r) * 24 + 20];
    sdeg[r] = acc2[(size_t)(m0 + r) * 24 + 20];
  }
#pragma unroll
  for (int i = 0; i < 4; ++i) {
    int col = (nt0 + i) * 16 + rc;
    float m1 = bns[col] * Ninv;
    float var = bns[192 + col] * Ninv - m1 * m1;
    float s1 = g1[col] * rsqrtf(var + 1e-5f);
    float t1 = bta1[col] - m1 * s1;
    float bb = bm1[col] + be1[col], bsv = bs1[col];
#pragma unroll
    for (int r = 0; r < 4; ++r) {
      float qv = acc[i][r] + sdeg[r] * bb + deg4[r] * bsv;
      V[(size_t)(m0 + r) * 224 + col] = f2bf(qv * s1 + deg4[r] * t1);
    }
  }
}

// ---- GEMM2: h2pre = V@Wp2 + e.We2 + deg*(bm2+be2) + x1, fused bn2 reduce ----
// grid (ceil(MT/4), 4): y0 -> nt 0..3, y1 -> 4..6, y2 -> 7..9, y3 -> 10..12
__global__ void __launch_bounds__(256) gemm2_k(
    const u16* __restrict__ A, const u16* __restrict__ Bp, const float* __restrict__ acc1,
    const float* __restrict__ h1pre, const float* __restrict__ x,
    const float* __restrict__ We2, const float* __restrict__ bm2,
    const float* __restrict__ be2, const float* __restrict__ g1,
    const float* __restrict__ bta1, float* __restrict__ bns, float Ninv,
    float* __restrict__ h2pre, int MT) {
  __shared__ float lred[4][64][2];
  int tid = threadIdx.x, w = tid >> 6, lane = tid & 63;
  int rc = lane & 15, qd = lane >> 4;
  int mt = blockIdx.x * 4 + w;
  bool valid = mt < MT;
  int mtc = valid ? mt : MT - 1;
  int y = blockIdx.y;
  int ntn = (y == 0) ? 4 : 3;
  int nt0 = (y == 0) ? 0 : 1 + y * 3;
  f32x4 acc[4];
#pragma unroll
  for (int i = 0; i < 4; ++i) acc[i] = {0.f, 0.f, 0.f, 0.f};
  const u16* Ap = A + (size_t)(mtc * 16 + rc) * 224 + qd * 8;
#pragma unroll
  for (int kb = 0; kb < 7; ++kb) {
    short8 av = *(const short8*)(Ap + kb * 32);
    for (int i = 0; i < 4; ++i) {
      if (i >= ntn) break;
      short8 bv = *(const short8*)(Bp + (size_t)((kb * 4 + qd) * 208 + (nt0 + i) * 16 + rc) * 8);
      acc[i] = __builtin_amdgcn_mfma_f32_16x16x32_bf16(av, bv, acc[i], 0, 0, 0);
    }
  }
  int m0 = mtc * 16 + qd * 4;
  float e0[4], e1[4], e2[4], e3[4], deg4[4];
#pragma unroll
  for (int r = 0; r < 4; ++r) {
    const float* a = acc1 + (size_t)(m0 + r) * 24;
    e0[r] = a[16]; e1[r] = a[17]; e2[r] = a[18]; e3[r] = a[19]; deg4[r] = a[20];
  }
  for (int i = 0; i < 4; ++i) {
    if (i >= ntn) break;
    int col = (nt0 + i) * 16 + rc;
    float w0 = We2[col], w1 = We2[208 + col], w2 = We2[416 + col], w3 = We2[624 + col];
    float bb = bm2[col] + be2[col];
    bool c192 = col < 192;
    float s1 = 0.f, t1 = 0.f;
    if (c192) {
      float m1 = bns[col] * Ninv;
      float var = bns[192 + col] * Ninv - m1 * m1;
      s1 = g1[col] * rsqrtf(var + 1e-5f);
      t1 = bta1[col] - m1 * s1;
    }
    float ps = 0.f, pq = 0.f;
#pragma unroll
    for (int r = 0; r < 4; ++r) {
      int m = m0 + r;
      float x1 = c192 ? (h1pre[(size_t)m * 192 + col] * s1 + t1)
                      : x[(size_t)m * 16 + (col - 192)];
      float val = acc[i][r] + e0[r] * w0 + e1[r] * w1 + e2[r] * w2 + e3[r] * w3 +
                  deg4[r] * bb + x1;
      if (valid) h2pre[(size_t)m * 208 + col] = val;
      ps += val;
      pq += val * val;
    }
    if (!valid) { ps = 0.f; pq = 0.f; }
    ps += __shfl_xor(ps, 16); ps += __shfl_xor(ps, 32);
    pq += __shfl_xor(pq, 16); pq += __shfl_xor(pq, 32);
    if (qd == 0) { lred[w][i * 16 + rc][0] = ps; lred[w][i * 16 + rc][1] = pq; }
  }
  __syncthreads();
  if (tid < 128) {
    int c = tid & 63, part = tid >> 6;
    if (c < ntn * 16) {
      float s = lred[0][c][part] + lred[1][c][part] + lred[2][c][part] + lred[3][c][part];
      int col = (nt0 + (c >> 4)) * 16 + (c & 15);
      atomAddF(&bns[384 + part * 208 + col], s);
    }
  }
}

// ---- pooling: x2 on the fly (inline BN), sum + max per graph ---- grid=(64,8), block=256
__global__ void pool_k(const float* __restrict__ h2pre, const float* __restrict__ h1pre,
                       const float* __restrict__ x, const float* __restrict__ g1,
                       const float* __restrict__ bta1, const float* __restrict__ g2,
                       const float* __restrict__ bta2, const float* __restrict__ bns,
                       float Ninv, const int* __restrict__ gstart,
                       const int* __restrict__ gend, float* __restrict__ psum,
                       u32* __restrict__ pmaxu) {
  int b = blockIdx.x, sub = blockIdx.y;
  int s0 = gstart[b], e0 = gend[b];
  if (s0 > e0) return;
  int cnt = e0 - s0 + 1;
  int per = (cnt + 7) >> 3;
  int n0 = s0 + sub * per;
  int n1 = min(n0 + per, e0 + 1);
  if (n0 >= n1) return;
  for (int f = threadIdx.x; f < 416; f += 256) {
    const float* src;
    int stride;
    float sc, sh;
    if (f < 208) {
      float m2 = bns[384 + f] * Ninv;
      float var = bns[592 + f] * Ninv - m2 * m2;
      sc = g2[f] * rsqrtf(var + 1e-5f);
      sh = bta2[f] - m2 * sc;
      src = h2pre + f; stride = 208;
    } else if (f < 400) {
      int j = f - 208;
      float m1 = bns[j] * Ninv;
      float var = bns[192 + j] * Ninv - m1 * m1;
      sc = g1[j] * rsqrtf(var + 1e-5f);
      sh = bta1[j] - m1 * sc;
      src = h1pre + j; stride = 192;
    } else {
      src = x + (f - 400); stride = 16; sc = 1.f; sh = 0.f;
    }
    float s = 0.f, mx = -3.4e38f;
    for (int n = n0; n < n1; ++n) {
      float v = src[(size_t)n * stride] * sc + sh;
      s += v;
      mx = fmaxf(mx, v);
    }
    atomAddF(&psum[b * 416 + f], s);
    atomicMax(&pmaxu[b * 416 + f], fflip(mx));
  }
}

// ---- pooled -> bf16 A matrix [64 x 1248] ---- grid=64, block=256
__global__ void pooledprep_k(const float* __restrict__ psum, const u32* __restrict__ pmaxu,
                             const int* __restrict__ gstart, const int* __restrict__ gend,
                             u16* __restrict__ Apool) {
  int b = blockIdx.x, t = threadIdx.x;
  int cnt = gend[b] - gstart[b] + 1;
  float inv = 1.f / (float)max(cnt, 1);
  for (int f = t; f < 416; f += 256) {
    float s = psum[b * 416 + f];
    float m = funflip(pmaxu[b * 416 + f]);
    u16* row = Apool + (size_t)b * 1248;
    row[f] = f2bf(s);
    row[416 + f] = f2bf((cnt > 0) ? m : 0.f);
    row[832 + f] = f2bf(s * inv);
  }
}

// ---- MLP layer 1 via MFMA ---- grid=(4,39), block=64
__global__ void mlpgemm_k(const u16* __restrict__ A, const u16* __restrict__ Bp,
                          const float* __restrict__ b1, const float* __restrict__ al,
                          float* __restrict__ hid) {
  int lane = threadIdx.x;
  int mt = blockIdx.x, nt = blockIdx.y;
  int rc = lane & 15, qd = lane >> 4;
  f32x4 acc = {0.f, 0.f, 0.f, 0.f};
  const u16* Ap = A + (size_t)(mt * 16 + rc) * 1248 + qd * 8;
  const u16* Bq = Bp + (size_t)(qd * 624 + nt * 16 + rc) * 8;
  for (int kb = 0; kb < 39; ++kb) {
    short8 av = *(const short8*)(Ap + kb * 32);
    short8 bv = *(const short8*)(Bq + (size_t)kb * 4 * 624 * 8);
    acc = __builtin_amdgcn_mfma_f32_16x16x32_bf16(av, bv, acc, 0, 0, 0);
  }
  int col = nt * 16 + rc;
  float bb = b1[col], alpha = al[0];
  int m0 = mt * 16 + qd * 4;
#pragma unroll
  for (int r = 0; r < 4; ++r) {
    float v = acc[r] + bb;
    hid[(size_t)(m0 + r) * 624 + col] = (v >= 0.f) ? v : alpha * v;
  }
}

// ---- logits + log_softmax ---- grid=64, block=64
__global__ void head_k(const float* __restrict__ hid, const float* __restrict__ W2,
                       const float* __restrict__ b2, float* __restrict__ out) {
  int b = blockIdx.x, t = threadIdx.x;
  float p0 = 0.f, p1 = 0.f;
  for (int k = t; k < 624; k += 64) {
    float h = hid[(size_t)b * 624 + k];
    p0 += h * W2[k * 2];
    p1 += h * W2[k * 2 + 1];
  }
#pragma unroll
  for (int off = 32; off > 0; off >>= 1) {
    p0 += __shfl_down(p0, off);
    p1 += __shfl_down(p1, off);
  }
  if (t == 0) {
    float l0 = p0 + b2[0], l1 = p1 + b2[1];
    float m = fmaxf(l0, l1);
    float lse = m + logf(expf(l0 - m) + expf(l1 - m));
    out[b * 2] = l0 - lse;
    out[b * 2 + 1] = l1 - lse;
  }
}

extern "C" void kernel_launch(void* const* d_in, const int* in_sizes, int n_in,
                              void* d_out, int out_size, void* d_ws, size_t ws_size,
                              hipStream_t stream) {
  const float* x = (const float*)d_in[0];
  const int* ei = (const int*)d_in[1];
  const float* ea = (const float*)d_in[2];
  const int* batch = (const int*)d_in[3];
  const float* Wm1 = (const float*)d_in[4];
  const float* bm1 = (const float*)d_in[5];
  const float* We1 = (const float*)d_in[6];
  const float* be1 = (const float*)d_in[7];
  const float* Ws1 = (const float*)d_in[8];
  const float* bs1 = (const float*)d_in[9];
  const float* g1 = (const float*)d_in[10];
  const float* bta1 = (const float*)d_in[11];
  const float* Wm2 = (const float*)d_in[12];
  const float* bm2 = (const float*)d_in[13];
  const float* We2 = (const float*)d_in[14];
  const float* be2 = (const float*)d_in[15];
  const float* g2 = (const float*)d_in[16];
  const float* bta2 = (const float*)d_in[17];
  const float* Wl1 = (const float*)d_in[18];
  const float* bl1 = (const float*)d_in[19];
  const float* alpha = (const float*)d_in[20];
  const float* Wl2 = (const float*)d_in[21];
  const float* bl2 = (const float*)d_in[22];
  float* out = (float*)d_out;

  const int N = in_sizes[3];      // 50000
  const int E = in_sizes[2] / 4;  // 800000
  const int MT = N / 16;          // 3125
  const int nb = (N + 255) / 256; // scan blocks (<=256)
  const float Ninv = 1.f / (float)N;

  float* ws = (float*)d_ws;
  size_t o = 0;
  float* acc1 = ws + o;  o += (size_t)N * 24;
  float* acc2 = ws + o;  o += (size_t)N * 24;
  float* h1pre = ws + o; o += (size_t)N * 192;
  float* h2pre = ws + o; o += (size_t)N * 208;   // aliased as CSR edge list (se)
  u16* U = (u16*)(ws + o);  o += (size_t)N * 32;   // N*64 u16
  u16* V = (u16*)(ws + o);  o += (size_t)N * 112;  // N*224 u16
  u16* Wp1 = (u16*)(ws + o); o += 6144;
  u16* Wp2 = (u16*)(ws + o); o += 23296;
  u16* Wp3 = (u16*)(ws + o); o += 389376;
  u16* Apool = (u16*)(ws + o); o += 39936;
  float* hid = ws + o;   o += 64 * 624;
  float* bns = ws + o;   o += 800;   // bn1 sums(192)+sq(192) | bn2 sums(208)+sq(208)
  float* psum = ws + o;  o += 64 * 416;
  u32* pmaxu = (u32*)(ws + o); o += 64 * 416;
  int* gstart = (int*)(ws + o); o += 64;
  int* gend = (int*)(ws + o);   o += 64;
  int* deg = (int*)(ws + o);    o += N;
  int* rowptr = (int*)(ws + o); o += N + 1;
  int* cur = (int*)(ws + o);    o += N + 1;
  int* bsum = (int*)(ws + o);   o += 256;
  int2* se = (int2*)h2pre;  // h2pre written only after se consumed

  int sb = (N + 255) / 256;
  int gx = (MT + 3) / 4;  // 782
  setup_k<<<sb, 256, 0, stream>>>(Wm1, We1, Ws1, Wm2, batch, Wp1, Wp2, gstart, gend, deg, bns, N);
  pack1_k<<<(1248 * 624 + 255) / 256, 256, 0, stream>>>(Wl1, Wp3, psum, pmaxu);
  count_k<<<(E + 255) / 256, 256, 0, stream>>>(ei, deg, E);
  scanA_k<<<nb, 256, 0, stream>>>(deg, bsum, N);
  scanC_k<<<nb, 256, 0, stream>>>(deg, bsum, rowptr, cur, N, nb);
  scatter_k<<<(E + 255) / 256, 256, 0, stream>>>(ei, cur, se, E);
  gather1_k<<<(N * 4 + 255) / 256, 256, 0, stream>>>(se, rowptr, x, ea, acc1, U, N);
  gemm1_k<<<dim3(gx, 3), 256, 0, stream>>>(U, Wp1, acc1, bm1, be1, bs1, h1pre, bns, MT);
  gather2_k<<<(N * 4 + 255) / 256, 256, 0, stream>>>(se, rowptr, acc1, acc2, U, V, N);
  gemmq2_k<<<dim3(gx, 3), 256, 0, stream>>>(U, Wp1, acc1, acc2, bm1, be1, bs1, g1, bta1, bns,
                                            Ninv, V, MT);
  gemm2_k<<<dim3(gx, 4), 256, 0, stream>>>(V, Wp2, acc1, h1pre, x, We2, bm2, be2, g1, bta1,
                                           bns, Ninv, h2pre, MT);
  pool_k<<<dim3(64, 8), 256, 0, stream>>>(h2pre, h1pre, x, g1, bta1, g2, bta2, bns, Ninv,
                                          gstart, gend, psum, pmaxu);
  pooledprep_k<<<64, 256, 0, stream>>>(psum, pmaxu, gstart, gend, Apool);
  mlpgemm_k<<<dim3(4, 39), 64, 0, stream>>>(Apool, Wp3, bl1, alpha, hid);
  head_k<<<64, 64, 0, stream>>>(hid, Wl2, bl2, out);
}

// Round 9
// 453.219 us; speedup vs baseline: 1.2629x; 1.0534x over previous
//
#include <hip/hip_runtime.h>

typedef __attribute__((ext_vector_type(8))) short short8;
typedef __attribute__((ext_vector_type(4))) float f32x4;
typedef unsigned short u16;
typedef unsigned int u32;

__device__ __forceinline__ u16 f2bf(float f) {
  u32 u = __float_as_uint(f);
  u = (u + 0x7fffu + ((u >> 16) & 1u)) >> 16;
  return (u16)u;
}
__device__ __forceinline__ float bf2f(u16 v) { return __uint_as_float((u32)v << 16); }
__device__ __forceinline__ void atomAddF(float* p, float v) { unsafeAtomicAdd(p, v); }
__device__ __forceinline__ u32 fflip(float f) {
  u32 u = __float_as_uint(f);
  return (u & 0x80000000u) ? ~u : (u | 0x80000000u);
}
__device__ __forceinline__ float funflip(u32 u) {
  return __uint_as_float((u & 0x80000000u) ? (u ^ 0x80000000u) : ~u);
}
__device__ __forceinline__ void add4(float4& a, const float4 b) {
  a.x += b.x; a.y += b.y; a.z += b.z; a.w += b.w;
}

// ---- prep: pack all bf16 weights + graph bounds + zero scratch ---- grid 3042x256
__global__ void prep_k(const float* __restrict__ Wm1, const float* __restrict__ We1,
                       const float* __restrict__ Ws1, const float* __restrict__ Wm2,
                       const float* __restrict__ Wl1, const int* __restrict__ batch,
                       u16* __restrict__ Wp1, u16* __restrict__ Wp2, u16* __restrict__ Wp3,
                       int* __restrict__ gstart, int* __restrict__ gend,
                       int* __restrict__ deg, float* __restrict__ bns,
                       float* __restrict__ bns2p, float* __restrict__ psum,
                       u32* __restrict__ pmaxu, int N) {
  int tid = blockIdx.x * 256 + threadIdx.x;
  if (tid < 64 * 192) {  // Wcat1 = [Wm1(16); We1(4); Ws1(16)], pad K to 64
    int k = tid / 192, n = tid % 192;
    float v = 0.f;
    if (k < 16) v = Wm1[k * 192 + n];
    else if (k < 20) v = We1[(k - 16) * 192 + n];
    else if (k < 36) v = Ws1[(k - 20) * 192 + n];
    Wp1[((k >> 3) * 192 + n) * 8 + (k & 7)] = f2bf(v);
  }
  if (tid < 224 * 208) {  // W_msg2, pad K 208->224
    int k = tid / 208, n = tid % 208;
    float v = (k < 208) ? Wm2[k * 208 + n] : 0.f;
    Wp2[((k >> 3) * 208 + n) * 8 + (k & 7)] = f2bf(v);
  }
  if (tid < N) {
    int b = batch[tid];
    if (tid == 0 || batch[tid - 1] != b) gstart[b] = tid;
    if (tid == N - 1 || batch[tid + 1] != b) gend[b] = tid;
    deg[tid] = 0;
  }
  if (tid < 384) bns[tid] = 0.f;
  if (tid < 64 * 832) bns2p[tid] = 0.f;
  if (tid < 64 * 416) psum[tid] = 0.f;
  else if (tid < 2 * 64 * 416) pmaxu[tid - 64 * 416] = 0u;  // 0 < fflip(any finite)
  if (tid < 1248 * 624) {
    int k = tid / 624, n = tid % 624;
    Wp3[((size_t)(k >> 3) * 624 + n) * 8 + (k & 7)] = f2bf(Wl1[(size_t)k * 624 + n]);
  }
}

// ---- CSR build ----
__global__ void count_k(const int* __restrict__ ei, int* __restrict__ deg, int E) {
  int e = blockIdx.x * 256 + threadIdx.x;
  if (e >= E) return;
  atomicAdd(&deg[ei[E + e]], 1);
}

__global__ void scanA_k(const int* __restrict__ deg, int* __restrict__ bsum, int N) {
  __shared__ int sh[256];
  int t = threadIdx.x;
  int i = blockIdx.x * 256 + t;
  sh[t] = (i < N) ? deg[i] : 0;
  __syncthreads();
  for (int off = 128; off > 0; off >>= 1) {
    if (t < off) sh[t] += sh[t + off];
    __syncthreads();
  }
  if (t == 0) bsum[blockIdx.x] = sh[0];
}

__global__ void scanC_k(const int* __restrict__ deg, const int* __restrict__ bsum,
                        int* __restrict__ rowptr, int* __restrict__ cur, int N, int nb) {
  __shared__ int sb2[256];
  __shared__ int sh[256];
  int t = threadIdx.x;
  int bv = (t < nb) ? bsum[t] : 0;
  sb2[t] = bv;
  __syncthreads();
  for (int off = 1; off < 256; off <<= 1) {
    int u = (t >= off) ? sb2[t - off] : 0;
    __syncthreads();
    sb2[t] += u;
    __syncthreads();
  }
  int bpref = (blockIdx.x == 0) ? 0 : sb2[blockIdx.x - 1];
  int i = blockIdx.x * 256 + t;
  int d = (i < N) ? deg[i] : 0;
  sh[t] = d;
  __syncthreads();
  for (int off = 1; off < 256; off <<= 1) {
    int u = (t >= off) ? sh[t - off] : 0;
    __syncthreads();
    sh[t] += u;
    __syncthreads();
  }
  int excl = sh[t] - d + bpref;
  if (i < N) {
    rowptr[i] = excl;
    cur[i] = excl;
    if (i == N - 1) rowptr[N] = excl + d;
  }
}

__global__ void scatter_k(const int* __restrict__ ei, int* __restrict__ cur,
                          int2* __restrict__ se, int E) {
  int e = blockIdx.x * 256 + threadIdx.x;
  if (e >= E) return;
  int s = ei[e], d = ei[E + e];
  int slot = atomicAdd(&cur[d], 1);
  se[slot] = make_int2(s, e);
}

// ---- gather pass 1 (+ fused U1 build): 8 lanes/node, se prefetch ---- block=256
__global__ void gather1_k(const int2* __restrict__ se, const int* __restrict__ rowptr,
                          const float* __restrict__ x, const float* __restrict__ ea,
                          float* __restrict__ acc1, u16* __restrict__ U, int N) {
  int tid = blockIdx.x * 256 + threadIdx.x;
  int n = tid >> 3, q = tid & 7;
  if (n >= N) return;
  int j0 = rowptr[n], j1 = rowptr[n + 1];
  float4 a0 = {0, 0, 0, 0}, a1 = a0, a2 = a0, a3 = a0, a4 = a0;
  int j = j0 + q;
  if (j < j1) {
    int2 p = se[j];
    for (;;) {
      int jn = j + 8;
      bool more = jn < j1;
      int2 pn = more ? se[jn] : p;
      const float4* xs = (const float4*)(x + (size_t)p.x * 16);
      float4 w = *(const float4*)(ea + (size_t)p.y * 4);
      add4(a0, xs[0]); add4(a1, xs[1]); add4(a2, xs[2]); add4(a3, xs[3]); add4(a4, w);
      if (!more) break;
      j = jn; p = pn;
    }
  }
  float v[24] = {a0.x, a0.y, a0.z, a0.w, a1.x, a1.y, a1.z, a1.w,
                 a2.x, a2.y, a2.z, a2.w, a3.x, a3.y, a3.z, a3.w,
                 a4.x, a4.y, a4.z, a4.w, (float)(j1 - j0), 0.f, 0.f, 0.f};
#pragma unroll
  for (int i = 0; i < 20; ++i) {
    v[i] += __shfl_xor(v[i], 1);
    v[i] += __shfl_xor(v[i], 2);
    v[i] += __shfl_xor(v[i], 4);
  }
  if (q < 6) {
    float4* out = (float4*)(acc1 + (size_t)n * 24);
    out[q] = make_float4(v[q * 4], v[q * 4 + 1], v[q * 4 + 2], v[q * 4 + 3]);
  }
  const float* xr = x + (size_t)n * 16;
  u32 w4[4];
#pragma unroll
  for (int jj = 0; jj < 4; ++jj) {
    int t0 = q * 8 + 2 * jj, t1 = t0 + 1;
    float f0 = (t0 < 20) ? v[t0] : ((t0 < 36) ? xr[t0 - 20] : 0.f);
    float f1 = (t1 < 20) ? v[t1] : ((t1 < 36) ? xr[t1 - 20] : 0.f);
    w4[jj] = (u32)f2bf(f0) | ((u32)f2bf(f1) << 16);
  }
  ((uint4*)(U + (size_t)n * 64))[q] = make_uint4(w4[0], w4[1], w4[2], w4[3]);
}

// ---- gather pass 2 (+ fused U2 build + V tail): 8 lanes/node ---- block=256
__global__ void gather2_k(const int2* __restrict__ se, const int* __restrict__ rowptr,
                          const float* __restrict__ acc1, float* __restrict__ acc2,
                          u16* __restrict__ U, u16* __restrict__ V, int N) {
  int tid = blockIdx.x * 256 + threadIdx.x;
  int n = tid >> 3, q = tid & 7;
  if (n >= N) return;
  int j0 = rowptr[n], j1 = rowptr[n + 1];
  float4 a0 = {0, 0, 0, 0}, a1 = a0, a2 = a0, a3 = a0, a4 = a0;
  float dg = 0.f;
  int j = j0 + q;
  if (j < j1) {
    int s = se[j].x;
    for (;;) {
      int jn = j + 8;
      bool more = jn < j1;
      int sn = more ? se[jn].x : s;
      const float4* ap = (const float4*)(acc1 + (size_t)s * 24);
      float4 t5 = ap[5];
      add4(a0, ap[0]); add4(a1, ap[1]); add4(a2, ap[2]); add4(a3, ap[3]); add4(a4, ap[4]);
      dg += t5.x;
      if (!more) break;
      j = jn; s = sn;
    }
  }
  float v[24] = {a0.x, a0.y, a0.z, a0.w, a1.x, a1.y, a1.z, a1.w,
                 a2.x, a2.y, a2.z, a2.w, a3.x, a3.y, a3.z, a3.w,
                 a4.x, a4.y, a4.z, a4.w, dg, 0.f, 0.f, 0.f};
#pragma unroll
  for (int i = 0; i < 21; ++i) {
    v[i] += __shfl_xor(v[i], 1);
    v[i] += __shfl_xor(v[i], 2);
    v[i] += __shfl_xor(v[i], 4);
  }
  if (q < 6) {
    float4* out = (float4*)(acc2 + (size_t)n * 24);
    out[q] = make_float4(v[q * 4], v[q * 4 + 1], v[q * 4 + 2], v[q * 4 + 3]);
  }
  const float* a1r = acc1 + (size_t)n * 24;
  u32 w4[4];
#pragma unroll
  for (int jj = 0; jj < 4; ++jj) {
    int t0 = q * 8 + 2 * jj, t1 = t0 + 1;
    float f0 = (t0 < 20) ? v[t0] : ((t0 < 36) ? a1r[t0 - 20] : 0.f);
    float f1 = (t1 < 20) ? v[t1] : ((t1 < 36) ? a1r[t1 - 20] : 0.f);
    w4[jj] = (u32)f2bf(f0) | ((u32)f2bf(f1) << 16);
  }
  ((uint4*)(U + (size_t)n * 64))[q] = make_uint4(w4[0], w4[1], w4[2], w4[3]);
  if (q < 4) {  // V tail cols [192..224): bf16(sx), pad 0
    u32 wv[4];
#pragma unroll
    for (int jj = 0; jj < 4; ++jj) {
      int t0 = q * 8 + 2 * jj;
      float f0 = (t0 < 16) ? a1r[t0] : 0.f;
      float f1 = (t0 + 1 < 16) ? a1r[t0 + 1] : 0.f;
      wv[jj] = (u32)f2bf(f0) | ((u32)f2bf(f1) << 16);
    }
    ((uint4*)(V + (size_t)n * 224 + 192))[q] = make_uint4(wv[0], wv[1], wv[2], wv[3]);
  }
}

// ---- GEMM1: h1bf = bf16(U@Wp1 + deg*(bm1+be1) + bs1) + bn1 stats ----
// grid (ceil(MT/4), 3), block 256
__global__ void __launch_bounds__(256) gemm1_k(
    const u16* __restrict__ A, const u16* __restrict__ Bp, const float* __restrict__ acc1,
    const float* __restrict__ bm1, const float* __restrict__ be1,
    const float* __restrict__ bs1, u16* __restrict__ h1bf, float* __restrict__ bns,
    int MT) {
  __shared__ float lred[4][64][2];
  int tid = threadIdx.x, w = tid >> 6, lane = tid & 63;
  int rc = lane & 15, qd = lane >> 4;
  int mt = blockIdx.x * 4 + w;
  bool valid = mt < MT;
  int mtc = valid ? mt : MT - 1;
  int nt0 = blockIdx.y * 4;
  f32x4 acc[4];
#pragma unroll
  for (int i = 0; i < 4; ++i) acc[i] = {0.f, 0.f, 0.f, 0.f};
  const u16* Ap = A + (size_t)(mtc * 16 + rc) * 64 + qd * 8;
#pragma unroll
  for (int kb = 0; kb < 2; ++kb) {
    short8 av = *(const short8*)(Ap + kb * 32);
#pragma unroll
    for (int i = 0; i < 4; ++i) {
      short8 bv = *(const short8*)(Bp + (size_t)((kb * 4 + qd) * 192 + (nt0 + i) * 16 + rc) * 8);
      acc[i] = __builtin_amdgcn_mfma_f32_16x16x32_bf16(av, bv, acc[i], 0, 0, 0);
    }
  }
  int m0 = mtc * 16 + qd * 4;
  float deg4[4];
#pragma unroll
  for (int r = 0; r < 4; ++r) deg4[r] = acc1[(size_t)(m0 + r) * 24 + 20];
#pragma unroll
  for (int i = 0; i < 4; ++i) {
    int col = (nt0 + i) * 16 + rc;
    float bb = bm1[col] + be1[col], bsv = bs1[col];
    float ps = 0.f, pq = 0.f;
#pragma unroll
    for (int r = 0; r < 4; ++r) {
      float val = acc[i][r] + deg4[r] * bb + bsv;
      if (valid) h1bf[(size_t)(m0 + r) * 192 + col] = f2bf(val);
      ps += val;
      pq += val * val;
    }
    if (!valid) { ps = 0.f; pq = 0.f; }
    ps += __shfl_xor(ps, 16); ps += __shfl_xor(ps, 32);
    pq += __shfl_xor(pq, 16); pq += __shfl_xor(pq, 32);
    if (qd == 0) { lred[w][i * 16 + rc][0] = ps; lred[w][i * 16 + rc][1] = pq; }
  }
  __syncthreads();
  if (tid < 128) {
    int c = tid & 63, part = tid >> 6;
    float s = lred[0][c][part] + lred[1][c][part] + lred[2][c][part] + lred[3][c][part];
    atomAddF(&bns[part * 192 + blockIdx.y * 64 + c], s);
  }
}

// ---- GEMMQ2: V[:,0..192) = bf16(bn1(U2@Wp1 + sdeg*bsum + deg*bself)) ---- grid (.,3)
__global__ void __launch_bounds__(256) gemmq2_k(
    const u16* __restrict__ A, const u16* __restrict__ Bp, const float* __restrict__ acc1,
    const float* __restrict__ acc2, const float* __restrict__ bm1,
    const float* __restrict__ be1, const float* __restrict__ bs1,
    const float* __restrict__ g1, const float* __restrict__ bta1,
    const float* __restrict__ bns, float Ninv, u16* __restrict__ V, int MT) {
  int tid = threadIdx.x, w = tid >> 6, lane = tid & 63;
  int rc = lane & 15, qd = lane >> 4;
  int mt = blockIdx.x * 4 + w;
  bool valid = mt < MT;
  int mtc = valid ? mt : MT - 1;
  int nt0 = blockIdx.y * 4;
  f32x4 acc[4];
#pragma unroll
  for (int i = 0; i < 4; ++i) acc[i] = {0.f, 0.f, 0.f, 0.f};
  const u16* Ap = A + (size_t)(mtc * 16 + rc) * 64 + qd * 8;
#pragma unroll
  for (int kb = 0; kb < 2; ++kb) {
    short8 av = *(const short8*)(Ap + kb * 32);
#pragma unroll
    for (int i = 0; i < 4; ++i) {
      short8 bv = *(const short8*)(Bp + (size_t)((kb * 4 + qd) * 192 + (nt0 + i) * 16 + rc) * 8);
      acc[i] = __builtin_amdgcn_mfma_f32_16x16x32_bf16(av, bv, acc[i], 0, 0, 0);
    }
  }
  if (!valid) return;
  int m0 = mtc * 16 + qd * 4;
  float deg4[4], sdeg[4];
#pragma unroll
  for (int r = 0; r < 4; ++r) {
    deg4[r] = acc1[(size_t)(m0 + r) * 24 + 20];
    sdeg[r] = acc2[(size_t)(m0 + r) * 24 + 20];
  }
#pragma unroll
  for (int i = 0; i < 4; ++i) {
    int col = (nt0 + i) * 16 + rc;
    float m1 = bns[col] * Ninv;
    float var = bns[192 + col] * Ninv - m1 * m1;
    float s1 = g1[col] * rsqrtf(var + 1e-5f);
    float t1 = bta1[col] - m1 * s1;
    float bb = bm1[col] + be1[col], bsv = bs1[col];
#pragma unroll
    for (int r = 0; r < 4; ++r) {
      float qv = acc[i][r] + sdeg[r] * bb + deg4[r] * bsv;
      V[(size_t)(m0 + r) * 224 + col] = f2bf(qv * s1 + deg4[r] * t1);
    }
  }
}

// ---- GEMM2: h2bf = bf16(V@Wp2 + e.We2 + deg*(bm2+be2) + x1), fused bn2 slice-reduce ----
// grid (MT), block 256; wave w n-slice {0..3 | 4..6 | 7..9 | 10..12}; x1 = bn1(h1bf) | x
__global__ void __launch_bounds__(256) gemm2_k(
    const u16* __restrict__ A, const u16* __restrict__ Bp, const float* __restrict__ acc1,
    const u16* __restrict__ h1bf, const float* __restrict__ x,
    const float* __restrict__ We2, const float* __restrict__ bm2,
    const float* __restrict__ be2, const float* __restrict__ g1,
    const float* __restrict__ bta1, const float* __restrict__ bns, float Ninv,
    float* __restrict__ bns2p, u16* __restrict__ h2bf) {
  int tid = threadIdx.x, w = tid >> 6, lane = tid & 63;
  int rc = lane & 15, qd = lane >> 4;
  int mt = blockIdx.x;
  int ntn = (w == 0) ? 4 : 3;
  int nt0 = (w == 0) ? 0 : 1 + w * 3;
  f32x4 acc[4];
#pragma unroll
  for (int i = 0; i < 4; ++i) acc[i] = {0.f, 0.f, 0.f, 0.f};
  const u16* Ap = A + (size_t)(mt * 16 + rc) * 224 + qd * 8;
#pragma unroll
  for (int kb = 0; kb < 7; ++kb) {
    short8 av = *(const short8*)(Ap + kb * 32);
    for (int i = 0; i < 4; ++i) {
      if (i >= ntn) break;
      short8 bv = *(const short8*)(Bp + (size_t)((kb * 4 + qd) * 208 + (nt0 + i) * 16 + rc) * 8);
      acc[i] = __builtin_amdgcn_mfma_f32_16x16x32_bf16(av, bv, acc[i], 0, 0, 0);
    }
  }
  int m0 = mt * 16 + qd * 4;
  float e0[4], e1[4], e2[4], e3[4], deg4[4];
#pragma unroll
  for (int r = 0; r < 4; ++r) {
    const float* a = acc1 + (size_t)(m0 + r) * 24;
    e0[r] = a[16]; e1[r] = a[17]; e2[r] = a[18]; e3[r] = a[19]; deg4[r] = a[20];
  }
  int slice = (blockIdx.x & 63) * 832;
  for (int i = 0; i < 4; ++i) {
    if (i >= ntn) break;
    int col = (nt0 + i) * 16 + rc;
    float w0 = We2[col], w1 = We2[208 + col], w2 = We2[416 + col], w3 = We2[624 + col];
    float bb = bm2[col] + be2[col];
    bool c192 = col < 192;
    float s1 = 0.f, t1 = 0.f;
    if (c192) {
      float m1 = bns[col] * Ninv;
      float var = bns[192 + col] * Ninv - m1 * m1;
      s1 = g1[col] * rsqrtf(var + 1e-5f);
      t1 = bta1[col] - m1 * s1;
    }
    float ps = 0.f, pq = 0.f;
#pragma unroll
    for (int r = 0; r < 4; ++r) {
      int m = m0 + r;
      float x1 = c192 ? (bf2f(h1bf[(size_t)m * 192 + col]) * s1 + t1)
                      : x[(size_t)m * 16 + (col - 192)];
      float val = acc[i][r] + e0[r] * w0 + e1[r] * w1 + e2[r] * w2 + e3[r] * w3 +
                  deg4[r] * bb + x1;
      h2bf[(size_t)m * 208 + col] = f2bf(val);
      ps += val;
      pq += val * val;
    }
    ps += __shfl_xor(ps, 16); ps += __shfl_xor(ps, 32);
    pq += __shfl_xor(pq, 16); pq += __shfl_xor(pq, 32);
    if (qd == 0) {
      atomAddF(&bns2p[slice + col], ps);
      atomAddF(&bns2p[slice + 416 + col], pq);
    }
  }
}

// ---- pooling: bn2(h2bf) | bn1(h1bf) | x, sum + max per graph ---- grid=(64,8), block=256
__global__ void pool_k(const u16* __restrict__ h2bf, const u16* __restrict__ h1bf,
                       const float* __restrict__ x, const float* __restrict__ g1,
                       const float* __restrict__ bta1, const float* __restrict__ g2,
                       const float* __restrict__ bta2, const float* __restrict__ bns,
                       const float* __restrict__ bns2p, float Ninv,
                       const int* __restrict__ gstart, const int* __restrict__ gend,
                       float* __restrict__ psum, u32* __restrict__ pmaxu) {
  int b = blockIdx.x, sub = blockIdx.y;
  int s0 = gstart[b], e0 = gend[b];
  if (s0 > e0) return;
  int cnt = e0 - s0 + 1;
  int per = (cnt + 7) >> 3;
  int n0 = s0 + sub * per;
  int n1 = min(n0 + per, e0 + 1);
  if (n0 >= n1) return;
  for (int f = threadIdx.x; f < 416; f += 256) {
    float s = 0.f, mx = -3.4e38f;
    if (f < 208) {
      float sm = 0.f, sq = 0.f;
      for (int k = 0; k < 64; ++k) {
        sm += bns2p[k * 832 + f];
        sq += bns2p[k * 832 + 416 + f];
      }
      float m2 = sm * Ninv;
      float var = sq * Ninv - m2 * m2;
      float sc = g2[f] * rsqrtf(var + 1e-5f);
      float sh = bta2[f] - m2 * sc;
      for (int n = n0; n < n1; ++n) {
        float v = bf2f(h2bf[(size_t)n * 208 + f]) * sc + sh;
        s += v;
        mx = fmaxf(mx, v);
      }
    } else if (f < 400) {
      int jc = f - 208;
      float m1 = bns[jc] * Ninv;
      float var = bns[192 + jc] * Ninv - m1 * m1;
      float sc = g1[jc] * rsqrtf(var + 1e-5f);
      float sh = bta1[jc] - m1 * sc;
      for (int n = n0; n < n1; ++n) {
        float v = bf2f(h1bf[(size_t)n * 192 + jc]) * sc + sh;
        s += v;
        mx = fmaxf(mx, v);
      }
    } else {
      int jc = f - 400;
      for (int n = n0; n < n1; ++n) {
        float v = x[(size_t)n * 16 + jc];
        s += v;
        mx = fmaxf(mx, v);
      }
    }
    atomAddF(&psum[b * 416 + f], s);
    atomicMax(&pmaxu[b * 416 + f], fflip(mx));
  }
}

// ---- pooled -> bf16 A matrix [64 x 1248] ---- grid=64, block=256
__global__ void pooledprep_k(const float* __restrict__ psum, const u32* __restrict__ pmaxu,
                             const int* __restrict__ gstart, const int* __restrict__ gend,
                             u16* __restrict__ Apool) {
  int b = blockIdx.x, t = threadIdx.x;
  int cnt = gend[b] - gstart[b] + 1;
  float inv = 1.f / (float)max(cnt, 1);
  for (int f = t; f < 416; f += 256) {
    float s = psum[b * 416 + f];
    float m = funflip(pmaxu[b * 416 + f]);
    u16* row = Apool + (size_t)b * 1248;
    row[f] = f2bf(s);
    row[416 + f] = f2bf((cnt > 0) ? m : 0.f);
    row[832 + f] = f2bf(s * inv);
  }
}

// ---- MLP layer 1 via MFMA ---- grid=(4,39), block=64
__global__ void mlpgemm_k(const u16* __restrict__ A, const u16* __restrict__ Bp,
                          const float* __restrict__ b1, const float* __restrict__ al,
                          float* __restrict__ hid) {
  int lane = threadIdx.x;
  int mt = blockIdx.x, nt = blockIdx.y;
  int rc = lane & 15, qd = lane >> 4;
  f32x4 acc = {0.f, 0.f, 0.f, 0.f};
  const u16* Ap = A + (size_t)(mt * 16 + rc) * 1248 + qd * 8;
  const u16* Bq = Bp + (size_t)(qd * 624 + nt * 16 + rc) * 8;
  for (int kb = 0; kb < 39; ++kb) {
    short8 av = *(const short8*)(Ap + kb * 32);
    short8 bv = *(const short8*)(Bq + (size_t)kb * 4 * 624 * 8);
    acc = __builtin_amdgcn_mfma_f32_16x16x32_bf16(av, bv, acc, 0, 0, 0);
  }
  int col = nt * 16 + rc;
  float bb = b1[col], alpha = al[0];
  int m0 = mt * 16 + qd * 4;
#pragma unroll
  for (int r = 0; r < 4; ++r) {
    float v = acc[r] + bb;
    hid[(size_t)(m0 + r) * 624 + col] = (v >= 0.f) ? v : alpha * v;
  }
}

// ---- logits + log_softmax ---- grid=64, block=64
__global__ void head_k(const float* __restrict__ hid, const float* __restrict__ W2,
                       const float* __restrict__ b2, float* __restrict__ out) {
  int b = blockIdx.x, t = threadIdx.x;
  float p0 = 0.f, p1 = 0.f;
  for (int k = t; k < 624; k += 64) {
    float h = hid[(size_t)b * 624 + k];
    p0 += h * W2[k * 2];
    p1 += h * W2[k * 2 + 1];
  }
#pragma unroll
  for (int off = 32; off > 0; off >>= 1) {
    p0 += __shfl_down(p0, off);
    p1 += __shfl_down(p1, off);
  }
  if (t == 0) {
    float l0 = p0 + b2[0], l1 = p1 + b2[1];
    float m = fmaxf(l0, l1);
    float lse = m + logf(expf(l0 - m) + expf(l1 - m));
    out[b * 2] = l0 - lse;
    out[b * 2 + 1] = l1 - lse;
  }
}

extern "C" void kernel_launch(void* const* d_in, const int* in_sizes, int n_in,
                              void* d_out, int out_size, void* d_ws, size_t ws_size,
                              hipStream_t stream) {
  const float* x = (const float*)d_in[0];
  const int* ei = (const int*)d_in[1];
  const float* ea = (const float*)d_in[2];
  const int* batch = (const int*)d_in[3];
  const float* Wm1 = (const float*)d_in[4];
  const float* bm1 = (const float*)d_in[5];
  const float* We1 = (const float*)d_in[6];
  const float* be1 = (const float*)d_in[7];
  const float* Ws1 = (const float*)d_in[8];
  const float* bs1 = (const float*)d_in[9];
  const float* g1 = (const float*)d_in[10];
  const float* bta1 = (const float*)d_in[11];
  const float* Wm2 = (const float*)d_in[12];
  const float* bm2 = (const float*)d_in[13];
  const float* We2 = (const float*)d_in[14];
  const float* be2 = (const float*)d_in[15];
  const float* g2 = (const float*)d_in[16];
  const float* bta2 = (const float*)d_in[17];
  const float* Wl1 = (const float*)d_in[18];
  const float* bl1 = (const float*)d_in[19];
  const float* alpha = (const float*)d_in[20];
  const float* Wl2 = (const float*)d_in[21];
  const float* bl2 = (const float*)d_in[22];
  float* out = (float*)d_out;

  const int N = in_sizes[3];      // 50000
  const int E = in_sizes[2] / 4;  // 800000
  const int MT = N / 16;          // 3125
  const int nb = (N + 255) / 256; // 196 (<=256)
  const float Ninv = 1.f / (float)N;

  float* ws = (float*)d_ws;
  size_t o = 0;
  float* acc1 = ws + o;  o += (size_t)N * 24;
  float* acc2 = ws + o;  o += (size_t)N * 24;
  u16* h2bf = (u16*)(ws + o); o += (size_t)N * 104;  // N*208 u16; aliased as se (int2)
  u16* h1bf = (u16*)(ws + o); o += (size_t)N * 96;   // N*192 u16
  u16* U = (u16*)(ws + o);  o += (size_t)N * 32;     // N*64 u16
  u16* V = (u16*)(ws + o);  o += (size_t)N * 112;    // N*224 u16
  u16* Wp1 = (u16*)(ws + o); o += 6144;
  u16* Wp2 = (u16*)(ws + o); o += 23296;
  u16* Wp3 = (u16*)(ws + o); o += 389376;
  u16* Apool = (u16*)(ws + o); o += 39936;
  float* hid = ws + o;    o += 64 * 624;
  float* bns = ws + o;    o += 384;          // bn1: sum(192)+sq(192)
  float* bns2p = ws + o;  o += 64 * 832;     // bn2 slices: [64][sum 416 | sq 416]
  float* psum = ws + o;   o += 64 * 416;
  u32* pmaxu = (u32*)(ws + o); o += 64 * 416;
  int* gstart = (int*)(ws + o); o += 64;
  int* gend = (int*)(ws + o);   o += 64;
  int* deg = (int*)(ws + o);    o += N;
  int* rowptr = (int*)(ws + o); o += N + 1;
  int* cur = (int*)(ws + o);    o += N + 1;
  int* bsum = (int*)(ws + o);   o += 256;
  int2* se = (int2*)h2bf;  // h2bf written only after se fully consumed (gather2)

  int gx = (MT + 3) / 4;  // 782
  prep_k<<<3042, 256, 0, stream>>>(Wm1, We1, Ws1, Wm2, Wl1, batch, Wp1, Wp2, Wp3, gstart,
                                   gend, deg, bns, bns2p, psum, pmaxu, N);
  count_k<<<(E + 255) / 256, 256, 0, stream>>>(ei, deg, E);
  scanA_k<<<nb, 256, 0, stream>>>(deg, bsum, N);
  scanC_k<<<nb, 256, 0, stream>>>(deg, bsum, rowptr, cur, N, nb);
  scatter_k<<<(E + 255) / 256, 256, 0, stream>>>(ei, cur, se, E);
  gather1_k<<<(N * 8 + 255) / 256, 256, 0, stream>>>(se, rowptr, x, ea, acc1, U, N);
  gemm1_k<<<dim3(gx, 3), 256, 0, stream>>>(U, Wp1, acc1, bm1, be1, bs1, h1bf, bns, MT);
  gather2_k<<<(N * 8 + 255) / 256, 256, 0, stream>>>(se, rowptr, acc1, acc2, U, V, N);
  gemmq2_k<<<dim3(gx, 3), 256, 0, stream>>>(U, Wp1, acc1, acc2, bm1, be1, bs1, g1, bta1, bns,
                                            Ninv, V, MT);
  gemm2_k<<<MT, 256, 0, stream>>>(V, Wp2, acc1, h1bf, x, We2, bm2, be2, g1, bta1, bns, Ninv,
                                  bns2p, h2bf);
  pool_k<<<dim3(64, 8), 256, 0, stream>>>(h2bf, h1bf, x, g1, bta1, g2, bta2, bns, bns2p,
                                          Ninv, gstart, gend, psum, pmaxu);
  pooledprep_k<<<64, 256, 0, stream>>>(psum, pmaxu, gstart, gend, Apool);
  mlpgemm_k<<<dim3(4, 39), 64, 0, stream>>>(Apool, Wp3, bl1, alpha, hid);
  head_k<<<64, 64, 0, stream>>>(hid, Wl2, bl2, out);
}

// Round 10
// 419.417 us; speedup vs baseline: 1.3647x; 1.0806x over previous
//
#include <hip/hip_runtime.h>

typedef __attribute__((ext_vector_type(8))) short short8;
typedef __attribute__((ext_vector_type(4))) float f32x4;
typedef unsigned short u16;
typedef unsigned int u32;

__device__ __forceinline__ u16 f2bf(float f) {
  u32 u = __float_as_uint(f);
  u = (u + 0x7fffu + ((u >> 16) & 1u)) >> 16;
  return (u16)u;
}
__device__ __forceinline__ float bf2f(u16 v) { return __uint_as_float((u32)v << 16); }
__device__ __forceinline__ void atomAddF(float* p, float v) { unsafeAtomicAdd(p, v); }
__device__ __forceinline__ void add4(float4& a, const float4 b) {
  a.x += b.x; a.y += b.y; a.z += b.z; a.w += b.w;
}

// ---- prep: pack all bf16 weights + graph bounds + zero scratch ---- grid 3042x256
__global__ void prep_k(const float* __restrict__ Wm1, const float* __restrict__ We1,
                       const float* __restrict__ Ws1, const float* __restrict__ Wm2,
                       const float* __restrict__ Wl1, const int* __restrict__ batch,
                       u16* __restrict__ Wp1, u16* __restrict__ Wp2, u16* __restrict__ Wp3,
                       int* __restrict__ gstart, int* __restrict__ gend,
                       int* __restrict__ deg, float* __restrict__ bns,
                       float* __restrict__ bns2p, int N) {
  int tid = blockIdx.x * 256 + threadIdx.x;
  if (tid < 64 * 192) {  // Wcat1 = [Wm1(16); We1(4); Ws1(16)], pad K to 64
    int k = tid / 192, n = tid % 192;
    float v = 0.f;
    if (k < 16) v = Wm1[k * 192 + n];
    else if (k < 20) v = We1[(k - 16) * 192 + n];
    else if (k < 36) v = Ws1[(k - 20) * 192 + n];
    Wp1[((k >> 3) * 192 + n) * 8 + (k & 7)] = f2bf(v);
  }
  if (tid < 224 * 208) {  // W_msg2, pad K 208->224
    int k = tid / 208, n = tid % 208;
    float v = (k < 208) ? Wm2[k * 208 + n] : 0.f;
    Wp2[((k >> 3) * 208 + n) * 8 + (k & 7)] = f2bf(v);
  }
  if (tid < N) {
    int b = batch[tid];
    if (tid == 0 || batch[tid - 1] != b) gstart[b] = tid;
    if (tid == N - 1 || batch[tid + 1] != b) gend[b] = tid;
    deg[tid] = 0;
  }
  if (tid < 384) bns[tid] = 0.f;
  if (tid < 64 * 832) bns2p[tid] = 0.f;
  if (tid < 1248 * 624) {
    int k = tid / 624, n = tid % 624;
    Wp3[((size_t)(k >> 3) * 624 + n) * 8 + (k & 7)] = f2bf(Wl1[(size_t)k * 624 + n]);
  }
}

// ---- CSR build ----
__global__ void count_k(const int* __restrict__ ei, int* __restrict__ deg, int E) {
  int e = blockIdx.x * 256 + threadIdx.x;
  if (e >= E) return;
  atomicAdd(&deg[ei[E + e]], 1);
}

__global__ void scanA_k(const int* __restrict__ deg, int* __restrict__ bsum, int N) {
  __shared__ int sh[256];
  int t = threadIdx.x;
  int i = blockIdx.x * 256 + t;
  sh[t] = (i < N) ? deg[i] : 0;
  __syncthreads();
  for (int off = 128; off > 0; off >>= 1) {
    if (t < off) sh[t] += sh[t + off];
    __syncthreads();
  }
  if (t == 0) bsum[blockIdx.x] = sh[0];
}

__global__ void scanC_k(const int* __restrict__ deg, const int* __restrict__ bsum,
                        int* __restrict__ rowptr, int* __restrict__ cur, int N, int nb) {
  __shared__ int sb2[256];
  __shared__ int sh[256];
  int t = threadIdx.x;
  int bv = (t < nb) ? bsum[t] : 0;
  sb2[t] = bv;
  __syncthreads();
  for (int off = 1; off < 256; off <<= 1) {
    int u = (t >= off) ? sb2[t - off] : 0;
    __syncthreads();
    sb2[t] += u;
    __syncthreads();
  }
  int bpref = (blockIdx.x == 0) ? 0 : sb2[blockIdx.x - 1];
  int i = blockIdx.x * 256 + t;
  int d = (i < N) ? deg[i] : 0;
  sh[t] = d;
  __syncthreads();
  for (int off = 1; off < 256; off <<= 1) {
    int u = (t >= off) ? sh[t - off] : 0;
    __syncthreads();
    sh[t] += u;
    __syncthreads();
  }
  int excl = sh[t] - d + bpref;
  if (i < N) {
    rowptr[i] = excl;
    cur[i] = excl;
    if (i == N - 1) rowptr[N] = excl + d;
  }
}

__global__ void scatter_k(const int* __restrict__ ei, int* __restrict__ cur,
                          int2* __restrict__ se, int E) {
  int e = blockIdx.x * 256 + threadIdx.x;
  if (e >= E) return;
  int s = ei[e], d = ei[E + e];
  int slot = atomicAdd(&cur[d], 1);
  se[slot] = make_int2(s, e);
}

// ---- gather pass 1 (+ fused U1 build): 8 lanes/node, se prefetch ---- block=256
__global__ void gather1_k(const int2* __restrict__ se, const int* __restrict__ rowptr,
                          const float* __restrict__ x, const float* __restrict__ ea,
                          float* __restrict__ acc1, u16* __restrict__ U, int N) {
  int tid = blockIdx.x * 256 + threadIdx.x;
  int n = tid >> 3, q = tid & 7;
  if (n >= N) return;
  int j0 = rowptr[n], j1 = rowptr[n + 1];
  float4 a0 = {0, 0, 0, 0}, a1 = a0, a2 = a0, a3 = a0, a4 = a0;
  int j = j0 + q;
  if (j < j1) {
    int2 p = se[j];
    for (;;) {
      int jn = j + 8;
      bool more = jn < j1;
      int2 pn = more ? se[jn] : p;
      const float4* xs = (const float4*)(x + (size_t)p.x * 16);
      float4 w = *(const float4*)(ea + (size_t)p.y * 4);
      add4(a0, xs[0]); add4(a1, xs[1]); add4(a2, xs[2]); add4(a3, xs[3]); add4(a4, w);
      if (!more) break;
      j = jn; p = pn;
    }
  }
  float v[24] = {a0.x, a0.y, a0.z, a0.w, a1.x, a1.y, a1.z, a1.w,
                 a2.x, a2.y, a2.z, a2.w, a3.x, a3.y, a3.z, a3.w,
                 a4.x, a4.y, a4.z, a4.w, (float)(j1 - j0), 0.f, 0.f, 0.f};
#pragma unroll
  for (int i = 0; i < 20; ++i) {
    v[i] += __shfl_xor(v[i], 1);
    v[i] += __shfl_xor(v[i], 2);
    v[i] += __shfl_xor(v[i], 4);
  }
  if (q < 6) {
    float4* out = (float4*)(acc1 + (size_t)n * 24);
    out[q] = make_float4(v[q * 4], v[q * 4 + 1], v[q * 4 + 2], v[q * 4 + 3]);
  }
  const float* xr = x + (size_t)n * 16;
  u32 w4[4];
#pragma unroll
  for (int jj = 0; jj < 4; ++jj) {
    int t0 = q * 8 + 2 * jj, t1 = t0 + 1;
    float f0 = (t0 < 20) ? v[t0] : ((t0 < 36) ? xr[t0 - 20] : 0.f);
    float f1 = (t1 < 20) ? v[t1] : ((t1 < 36) ? xr[t1 - 20] : 0.f);
    w4[jj] = (u32)f2bf(f0) | ((u32)f2bf(f1) << 16);
  }
  ((uint4*)(U + (size_t)n * 64))[q] = make_uint4(w4[0], w4[1], w4[2], w4[3]);
}

// ---- gather pass 2 (+ fused U2 build + V tail): 8 lanes/node ---- block=256
__global__ void gather2_k(const int2* __restrict__ se, const int* __restrict__ rowptr,
                          const float* __restrict__ acc1, float* __restrict__ acc2,
                          u16* __restrict__ U, u16* __restrict__ V, int N) {
  int tid = blockIdx.x * 256 + threadIdx.x;
  int n = tid >> 3, q = tid & 7;
  if (n >= N) return;
  int j0 = rowptr[n], j1 = rowptr[n + 1];
  float4 a0 = {0, 0, 0, 0}, a1 = a0, a2 = a0, a3 = a0, a4 = a0;
  float dg = 0.f;
  int j = j0 + q;
  if (j < j1) {
    int s = se[j].x;
    for (;;) {
      int jn = j + 8;
      bool more = jn < j1;
      int sn = more ? se[jn].x : s;
      const float4* ap = (const float4*)(acc1 + (size_t)s * 24);
      float4 t5 = ap[5];
      add4(a0, ap[0]); add4(a1, ap[1]); add4(a2, ap[2]); add4(a3, ap[3]); add4(a4, ap[4]);
      dg += t5.x;
      if (!more) break;
      j = jn; s = sn;
    }
  }
  float v[24] = {a0.x, a0.y, a0.z, a0.w, a1.x, a1.y, a1.z, a1.w,
                 a2.x, a2.y, a2.z, a2.w, a3.x, a3.y, a3.z, a3.w,
                 a4.x, a4.y, a4.z, a4.w, dg, 0.f, 0.f, 0.f};
#pragma unroll
  for (int i = 0; i < 21; ++i) {
    v[i] += __shfl_xor(v[i], 1);
    v[i] += __shfl_xor(v[i], 2);
    v[i] += __shfl_xor(v[i], 4);
  }
  if (q < 6) {
    float4* out = (float4*)(acc2 + (size_t)n * 24);
    out[q] = make_float4(v[q * 4], v[q * 4 + 1], v[q * 4 + 2], v[q * 4 + 3]);
  }
  const float* a1r = acc1 + (size_t)n * 24;
  u32 w4[4];
#pragma unroll
  for (int jj = 0; jj < 4; ++jj) {
    int t0 = q * 8 + 2 * jj, t1 = t0 + 1;
    float f0 = (t0 < 20) ? v[t0] : ((t0 < 36) ? a1r[t0 - 20] : 0.f);
    float f1 = (t1 < 20) ? v[t1] : ((t1 < 36) ? a1r[t1 - 20] : 0.f);
    w4[jj] = (u32)f2bf(f0) | ((u32)f2bf(f1) << 16);
  }
  ((uint4*)(U + (size_t)n * 64))[q] = make_uint4(w4[0], w4[1], w4[2], w4[3]);
  if (q < 4) {  // V tail cols [192..224): bf16(sx), pad 0
    u32 wv[4];
#pragma unroll
    for (int jj = 0; jj < 4; ++jj) {
      int t0 = q * 8 + 2 * jj;
      float f0 = (t0 < 16) ? a1r[t0] : 0.f;
      float f1 = (t0 + 1 < 16) ? a1r[t0 + 1] : 0.f;
      wv[jj] = (u32)f2bf(f0) | ((u32)f2bf(f1) << 16);
    }
    ((uint4*)(V + (size_t)n * 224 + 192))[q] = make_uint4(wv[0], wv[1], wv[2], wv[3]);
  }
}

// ---- GEMM1: h1bf = bf16(U@Wp1 + deg*(bm1+be1) + bs1) + bn1 stats ----
// grid (ceil(MT/4), 3), block 256
__global__ void __launch_bounds__(256) gemm1_k(
    const u16* __restrict__ A, const u16* __restrict__ Bp, const float* __restrict__ acc1,
    const float* __restrict__ bm1, const float* __restrict__ be1,
    const float* __restrict__ bs1, u16* __restrict__ h1bf, float* __restrict__ bns,
    int MT) {
  __shared__ float lred[4][64][2];
  int tid = threadIdx.x, w = tid >> 6, lane = tid & 63;
  int rc = lane & 15, qd = lane >> 4;
  int mt = blockIdx.x * 4 + w;
  bool valid = mt < MT;
  int mtc = valid ? mt : MT - 1;
  int nt0 = blockIdx.y * 4;
  f32x4 acc[4];
#pragma unroll
  for (int i = 0; i < 4; ++i) acc[i] = {0.f, 0.f, 0.f, 0.f};
  const u16* Ap = A + (size_t)(mtc * 16 + rc) * 64 + qd * 8;
#pragma unroll
  for (int kb = 0; kb < 2; ++kb) {
    short8 av = *(const short8*)(Ap + kb * 32);
#pragma unroll
    for (int i = 0; i < 4; ++i) {
      short8 bv = *(const short8*)(Bp + (size_t)((kb * 4 + qd) * 192 + (nt0 + i) * 16 + rc) * 8);
      acc[i] = __builtin_amdgcn_mfma_f32_16x16x32_bf16(av, bv, acc[i], 0, 0, 0);
    }
  }
  int m0 = mtc * 16 + qd * 4;
  float deg4[4];
#pragma unroll
  for (int r = 0; r < 4; ++r) deg4[r] = acc1[(size_t)(m0 + r) * 24 + 20];
#pragma unroll
  for (int i = 0; i < 4; ++i) {
    int col = (nt0 + i) * 16 + rc;
    float bb = bm1[col] + be1[col], bsv = bs1[col];
    float ps = 0.f, pq = 0.f;
#pragma unroll
    for (int r = 0; r < 4; ++r) {
      float val = acc[i][r] + deg4[r] * bb + bsv;
      if (valid) h1bf[(size_t)(m0 + r) * 192 + col] = f2bf(val);
      ps += val;
      pq += val * val;
    }
    if (!valid) { ps = 0.f; pq = 0.f; }
    ps += __shfl_xor(ps, 16); ps += __shfl_xor(ps, 32);
    pq += __shfl_xor(pq, 16); pq += __shfl_xor(pq, 32);
    if (qd == 0) { lred[w][i * 16 + rc][0] = ps; lred[w][i * 16 + rc][1] = pq; }
  }
  __syncthreads();
  if (tid < 128) {
    int c = tid & 63, part = tid >> 6;
    float s = lred[0][c][part] + lred[1][c][part] + lred[2][c][part] + lred[3][c][part];
    atomAddF(&bns[part * 192 + blockIdx.y * 64 + c], s);
  }
}

// ---- GEMMQ2: V[:,0..192) = bf16(bn1(U2@Wp1 + sdeg*bsum + deg*bself)) ---- grid (.,3)
__global__ void __launch_bounds__(256) gemmq2_k(
    const u16* __restrict__ A, const u16* __restrict__ Bp, const float* __restrict__ acc1,
    const float* __restrict__ acc2, const float* __restrict__ bm1,
    const float* __restrict__ be1, const float* __restrict__ bs1,
    const float* __restrict__ g1, const float* __restrict__ bta1,
    const float* __restrict__ bns, float Ninv, u16* __restrict__ V, int MT) {
  int tid = threadIdx.x, w = tid >> 6, lane = tid & 63;
  int rc = lane & 15, qd = lane >> 4;
  int mt = blockIdx.x * 4 + w;
  bool valid = mt < MT;
  int mtc = valid ? mt : MT - 1;
  int nt0 = blockIdx.y * 4;
  f32x4 acc[4];
#pragma unroll
  for (int i = 0; i < 4; ++i) acc[i] = {0.f, 0.f, 0.f, 0.f};
  const u16* Ap = A + (size_t)(mtc * 16 + rc) * 64 + qd * 8;
#pragma unroll
  for (int kb = 0; kb < 2; ++kb) {
    short8 av = *(const short8*)(Ap + kb * 32);
#pragma unroll
    for (int i = 0; i < 4; ++i) {
      short8 bv = *(const short8*)(Bp + (size_t)((kb * 4 + qd) * 192 + (nt0 + i) * 16 + rc) * 8);
      acc[i] = __builtin_amdgcn_mfma_f32_16x16x32_bf16(av, bv, acc[i], 0, 0, 0);
    }
  }
  if (!valid) return;
  int m0 = mtc * 16 + qd * 4;
  float deg4[4], sdeg[4];
#pragma unroll
  for (int r = 0; r < 4; ++r) {
    deg4[r] = acc1[(size_t)(m0 + r) * 24 + 20];
    sdeg[r] = acc2[(size_t)(m0 + r) * 24 + 20];
  }
#pragma unroll
  for (int i = 0; i < 4; ++i) {
    int col = (nt0 + i) * 16 + rc;
    float m1 = bns[col] * Ninv;
    float var = bns[192 + col] * Ninv - m1 * m1;
    float s1 = g1[col] * rsqrtf(var + 1e-5f);
    float t1 = bta1[col] - m1 * s1;
    float bb = bm1[col] + be1[col], bsv = bs1[col];
#pragma unroll
    for (int r = 0; r < 4; ++r) {
      float qv = acc[i][r] + sdeg[r] * bb + deg4[r] * bsv;
      V[(size_t)(m0 + r) * 224 + col] = f2bf(qv * s1 + deg4[r] * t1);
    }
  }
}

// ---- GEMM2: h2bf = bf16(V@Wp2 + e.We2 + deg*(bm2+be2) + x1), fused bn2 slice-reduce ----
__global__ void __launch_bounds__(256) gemm2_k(
    const u16* __restrict__ A, const u16* __restrict__ Bp, const float* __restrict__ acc1,
    const u16* __restrict__ h1bf, const float* __restrict__ x,
    const float* __restrict__ We2, const float* __restrict__ bm2,
    const float* __restrict__ be2, const float* __restrict__ g1,
    const float* __restrict__ bta1, const float* __restrict__ bns, float Ninv,
    float* __restrict__ bns2p, u16* __restrict__ h2bf) {
  int tid = threadIdx.x, w = tid >> 6, lane = tid & 63;
  int rc = lane & 15, qd = lane >> 4;
  int mt = blockIdx.x;
  int ntn = (w == 0) ? 4 : 3;
  int nt0 = (w == 0) ? 0 : 1 + w * 3;
  f32x4 acc[4];
#pragma unroll
  for (int i = 0; i < 4; ++i) acc[i] = {0.f, 0.f, 0.f, 0.f};
  const u16* Ap = A + (size_t)(mt * 16 + rc) * 224 + qd * 8;
#pragma unroll
  for (int kb = 0; kb < 7; ++kb) {
    short8 av = *(const short8*)(Ap + kb * 32);
    for (int i = 0; i < 4; ++i) {
      if (i >= ntn) break;
      short8 bv = *(const short8*)(Bp + (size_t)((kb * 4 + qd) * 208 + (nt0 + i) * 16 + rc) * 8);
      acc[i] = __builtin_amdgcn_mfma_f32_16x16x32_bf16(av, bv, acc[i], 0, 0, 0);
    }
  }
  int m0 = mt * 16 + qd * 4;
  float e0[4], e1[4], e2[4], e3[4], deg4[4];
#pragma unroll
  for (int r = 0; r < 4; ++r) {
    const float* a = acc1 + (size_t)(m0 + r) * 24;
    e0[r] = a[16]; e1[r] = a[17]; e2[r] = a[18]; e3[r] = a[19]; deg4[r] = a[20];
  }
  int slice = (blockIdx.x & 63) * 832;
  for (int i = 0; i < 4; ++i) {
    if (i >= ntn) break;
    int col = (nt0 + i) * 16 + rc;
    float w0 = We2[col], w1 = We2[208 + col], w2 = We2[416 + col], w3 = We2[624 + col];
    float bb = bm2[col] + be2[col];
    bool c192 = col < 192;
    float s1 = 0.f, t1 = 0.f;
    if (c192) {
      float m1 = bns[col] * Ninv;
      float var = bns[192 + col] * Ninv - m1 * m1;
      s1 = g1[col] * rsqrtf(var + 1e-5f);
      t1 = bta1[col] - m1 * s1;
    }
    float ps = 0.f, pq = 0.f;
#pragma unroll
    for (int r = 0; r < 4; ++r) {
      int m = m0 + r;
      float x1 = c192 ? (bf2f(h1bf[(size_t)m * 192 + col]) * s1 + t1)
                      : x[(size_t)m * 16 + (col - 192)];
      float val = acc[i][r] + e0[r] * w0 + e1[r] * w1 + e2[r] * w2 + e3[r] * w3 +
                  deg4[r] * bb + x1;
      h2bf[(size_t)m * 208 + col] = f2bf(val);
      ps += val;
      pq += val * val;
    }
    ps += __shfl_xor(ps, 16); ps += __shfl_xor(ps, 32);
    pq += __shfl_xor(pq, 16); pq += __shfl_xor(pq, 32);
    if (qd == 0) {
      atomAddF(&bns2p[slice + col], ps);
      atomAddF(&bns2p[slice + 416 + col], pq);
    }
  }
}

// ---- bn finalize: unified affine table aff[f]=scale, aff[416+f]=shift ---- grid 2x256
__global__ void bnfin2_k(const float* __restrict__ bns, const float* __restrict__ bns2p,
                         const float* __restrict__ g1, const float* __restrict__ bta1,
                         const float* __restrict__ g2, const float* __restrict__ bta2,
                         float Ninv, float* __restrict__ aff) {
  int f = blockIdx.x * 256 + threadIdx.x;
  if (f >= 416) return;
  float sc, sh;
  if (f < 208) {
    float sm = 0.f, sq = 0.f;
    for (int k = 0; k < 64; ++k) {
      sm += bns2p[k * 832 + f];
      sq += bns2p[k * 832 + 416 + f];
    }
    float m2 = sm * Ninv;
    float var = sq * Ninv - m2 * m2;
    sc = g2[f] * rsqrtf(var + 1e-5f);
    sh = bta2[f] - m2 * sc;
  } else if (f < 400) {
    int j = f - 208;
    float m1 = bns[j] * Ninv;
    float var = bns[192 + j] * Ninv - m1 * m1;
    sc = g1[j] * rsqrtf(var + 1e-5f);
    sh = bta1[j] - m1 * sc;
  } else {
    sc = 1.f;
    sh = 0.f;
  }
  aff[f] = sc;
  aff[416 + f] = sh;
}

// ---- pooling: thread owns feature pair, partial stores (no atomics) ----
// grid=(64,16), block=256 (t<208 active)
__global__ void pool_k(const u16* __restrict__ h2bf, const u16* __restrict__ h1bf,
                       const float* __restrict__ x, const float* __restrict__ aff,
                       const int* __restrict__ gstart, const int* __restrict__ gend,
                       float* __restrict__ psp, float* __restrict__ pmp) {
  int b = blockIdx.x, sub = blockIdx.y;
  int t = threadIdx.x;
  if (t >= 208) return;
  int s0 = gstart[b], e0 = gend[b];
  int cnt = (s0 <= e0) ? e0 - s0 + 1 : 0;
  int per = (cnt + 15) >> 4;
  int n0 = s0 + sub * per;
  int n1 = min(n0 + per, s0 + cnt);
  int f = 2 * t;  // global feature pair (f, f+1); region boundaries (208,400) are even
  float sc0 = aff[f], sc1 = aff[f + 1];
  float sh0 = aff[416 + f], sh1 = aff[417 + f];
  float s0f = 0.f, s1f = 0.f, m0f = -3.4e38f, m1f = -3.4e38f;
  if (f < 208) {
    for (int n = n0; n < n1; ++n) {
      u32 p = *(const u32*)(h2bf + (size_t)n * 208 + f);
      float v0 = bf2f((u16)p) * sc0 + sh0;
      float v1 = bf2f((u16)(p >> 16)) * sc1 + sh1;
      s0f += v0; s1f += v1;
      m0f = fmaxf(m0f, v0); m1f = fmaxf(m1f, v1);
    }
  } else if (f < 400) {
    int j = f - 208;
    for (int n = n0; n < n1; ++n) {
      u32 p = *(const u32*)(h1bf + (size_t)n * 192 + j);
      float v0 = bf2f((u16)p) * sc0 + sh0;
      float v1 = bf2f((u16)(p >> 16)) * sc1 + sh1;
      s0f += v0; s1f += v1;
      m0f = fmaxf(m0f, v0); m1f = fmaxf(m1f, v1);
    }
  } else {
    int j = f - 400;
    for (int n = n0; n < n1; ++n) {
      float2 p = *(const float2*)(x + (size_t)n * 16 + j);
      s0f += p.x; s1f += p.y;
      m0f = fmaxf(m0f, p.x); m1f = fmaxf(m1f, p.y);
    }
  }
  size_t idx = ((size_t)(b * 16 + sub)) * 416 + f;
  *(float2*)(psp + idx) = make_float2(s0f, s1f);
  *(float2*)(pmp + idx) = make_float2(m0f, m1f);
}

// ---- pooled partial reduce -> bf16 A matrix [64 x 1248] ---- grid=64, block=256
__global__ void pooledprep_k(const float* __restrict__ psp, const float* __restrict__ pmp,
                             const int* __restrict__ gstart, const int* __restrict__ gend,
                             u16* __restrict__ Apool) {
  int b = blockIdx.x, t = threadIdx.x;
  int cnt = gend[b] - gstart[b] + 1;
  float inv = 1.f / (float)max(cnt, 1);
  for (int f = t; f < 416; f += 256) {
    float s = 0.f, m = -3.4e38f;
    for (int k = 0; k < 16; ++k) {
      size_t idx = ((size_t)(b * 16 + k)) * 416 + f;
      s += psp[idx];
      m = fmaxf(m, pmp[idx]);
    }
    u16* row = Apool + (size_t)b * 1248;
    row[f] = f2bf(s);
    row[416 + f] = f2bf((cnt > 0) ? m : 0.f);
    row[832 + f] = f2bf(s * inv);
  }
}

// ---- MLP layer 1 via MFMA ---- grid=(4,39), block=64
__global__ void mlpgemm_k(const u16* __restrict__ A, const u16* __restrict__ Bp,
                          const float* __restrict__ b1, const float* __restrict__ al,
                          float* __restrict__ hid) {
  int lane = threadIdx.x;
  int mt = blockIdx.x, nt = blockIdx.y;
  int rc = lane & 15, qd = lane >> 4;
  f32x4 acc = {0.f, 0.f, 0.f, 0.f};
  const u16* Ap = A + (size_t)(mt * 16 + rc) * 1248 + qd * 8;
  const u16* Bq = Bp + (size_t)(qd * 624 + nt * 16 + rc) * 8;
  for (int kb = 0; kb < 39; ++kb) {
    short8 av = *(const short8*)(Ap + kb * 32);
    short8 bv = *(const short8*)(Bq + (size_t)kb * 4 * 624 * 8);
    acc = __builtin_amdgcn_mfma_f32_16x16x32_bf16(av, bv, acc, 0, 0, 0);
  }
  int col = nt * 16 + rc;
  float bb = b1[col], alpha = al[0];
  int m0 = mt * 16 + qd * 4;
#pragma unroll
  for (int r = 0; r < 4; ++r) {
    float v = acc[r] + bb;
    hid[(size_t)(m0 + r) * 624 + col] = (v >= 0.f) ? v : alpha * v;
  }
}

// ---- logits + log_softmax ---- grid=64, block=64
__global__ void head_k(const float* __restrict__ hid, const float* __restrict__ W2,
                       const float* __restrict__ b2, float* __restrict__ out) {
  int b = blockIdx.x, t = threadIdx.x;
  float p0 = 0.f, p1 = 0.f;
  for (int k = t; k < 624; k += 64) {
    float h = hid[(size_t)b * 624 + k];
    p0 += h * W2[k * 2];
    p1 += h * W2[k * 2 + 1];
  }
#pragma unroll
  for (int off = 32; off > 0; off >>= 1) {
    p0 += __shfl_down(p0, off);
    p1 += __shfl_down(p1, off);
  }
  if (t == 0) {
    float l0 = p0 + b2[0], l1 = p1 + b2[1];
    float m = fmaxf(l0, l1);
    float lse = m + logf(expf(l0 - m) + expf(l1 - m));
    out[b * 2] = l0 - lse;
    out[b * 2 + 1] = l1 - lse;
  }
}

extern "C" void kernel_launch(void* const* d_in, const int* in_sizes, int n_in,
                              void* d_out, int out_size, void* d_ws, size_t ws_size,
                              hipStream_t stream) {
  const float* x = (const float*)d_in[0];
  const int* ei = (const int*)d_in[1];
  const float* ea = (const float*)d_in[2];
  const int* batch = (const int*)d_in[3];
  const float* Wm1 = (const float*)d_in[4];
  const float* bm1 = (const float*)d_in[5];
  const float* We1 = (const float*)d_in[6];
  const float* be1 = (const float*)d_in[7];
  const float* Ws1 = (const float*)d_in[8];
  const float* bs1 = (const float*)d_in[9];
  const float* g1 = (const float*)d_in[10];
  const float* bta1 = (const float*)d_in[11];
  const float* Wm2 = (const float*)d_in[12];
  const float* bm2 = (const float*)d_in[13];
  const float* We2 = (const float*)d_in[14];
  const float* be2 = (const float*)d_in[15];
  const float* g2 = (const float*)d_in[16];
  const float* bta2 = (const float*)d_in[17];
  const float* Wl1 = (const float*)d_in[18];
  const float* bl1 = (const float*)d_in[19];
  const float* alpha = (const float*)d_in[20];
  const float* Wl2 = (const float*)d_in[21];
  const float* bl2 = (const float*)d_in[22];
  float* out = (float*)d_out;

  const int N = in_sizes[3];      // 50000
  const int E = in_sizes[2] / 4;  // 800000
  const int MT = N / 16;          // 3125
  const int nb = (N + 255) / 256; // 196 (<=256)
  const float Ninv = 1.f / (float)N;

  float* ws = (float*)d_ws;
  size_t o = 0;
  float* acc1 = ws + o;  o += (size_t)N * 24;
  float* acc2 = ws + o;  o += (size_t)N * 24;
  u16* h2bf = (u16*)(ws + o); o += (size_t)N * 104;  // N*208 u16; aliased as se (int2)
  u16* h1bf = (u16*)(ws + o); o += (size_t)N * 96;   // N*192 u16
  u16* U = (u16*)(ws + o);  o += (size_t)N * 32;     // N*64 u16
  u16* V = (u16*)(ws + o);  o += (size_t)N * 112;    // N*224 u16
  u16* Wp1 = (u16*)(ws + o); o += 6144;
  u16* Wp2 = (u16*)(ws + o); o += 23296;
  u16* Wp3 = (u16*)(ws + o); o += 389376;
  u16* Apool = (u16*)(ws + o); o += 39936;
  float* hid = ws + o;    o += 64 * 624;
  float* bns = ws + o;    o += 384;          // bn1: sum(192)+sq(192)
  float* bns2p = ws + o;  o += 64 * 832;     // bn2 slices: [64][sum 416 | sq 416]
  float* aff = ws + o;    o += 832;          // affine table sc(416)+sh(416)
  float* psp = ws + o;    o += (size_t)64 * 16 * 416;
  float* pmp = ws + o;    o += (size_t)64 * 16 * 416;
  int* gstart = (int*)(ws + o); o += 64;
  int* gend = (int*)(ws + o);   o += 64;
  int* deg = (int*)(ws + o);    o += N;
  int* rowptr = (int*)(ws + o); o += N + 1;
  int* cur = (int*)(ws + o);    o += N + 1;
  int* bsum = (int*)(ws + o);   o += 256;
  int2* se = (int2*)h2bf;  // h2bf written only after se fully consumed (gather2)

  int gx = (MT + 3) / 4;  // 782
  prep_k<<<3042, 256, 0, stream>>>(Wm1, We1, Ws1, Wm2, Wl1, batch, Wp1, Wp2, Wp3, gstart,
                                   gend, deg, bns, bns2p, N);
  count_k<<<(E + 255) / 256, 256, 0, stream>>>(ei, deg, E);
  scanA_k<<<nb, 256, 0, stream>>>(deg, bsum, N);
  scanC_k<<<nb, 256, 0, stream>>>(deg, bsum, rowptr, cur, N, nb);
  scatter_k<<<(E + 255) / 256, 256, 0, stream>>>(ei, cur, se, E);
  gather1_k<<<(N * 8 + 255) / 256, 256, 0, stream>>>(se, rowptr, x, ea, acc1, U, N);
  gemm1_k<<<dim3(gx, 3), 256, 0, stream>>>(U, Wp1, acc1, bm1, be1, bs1, h1bf, bns, MT);
  gather2_k<<<(N * 8 + 255) / 256, 256, 0, stream>>>(se, rowptr, acc1, acc2, U, V, N);
  gemmq2_k<<<dim3(gx, 3), 256, 0, stream>>>(U, Wp1, acc1, acc2, bm1, be1, bs1, g1, bta1, bns,
                                            Ninv, V, MT);
  gemm2_k<<<MT, 256, 0, stream>>>(V, Wp2, acc1, h1bf, x, We2, bm2, be2, g1, bta1, bns, Ninv,
                                  bns2p, h2bf);
  bnfin2_k<<<2, 256, 0, stream>>>(bns, bns2p, g1, bta1, g2, bta2, Ninv, aff);
  pool_k<<<dim3(64, 16), 256, 0, stream>>>(h2bf, h1bf, x, aff, gstart, gend, psp, pmp);
  pooledprep_k<<<64, 256, 0, stream>>>(psp, pmp, gstart, gend, Apool);
  mlpgemm_k<<<dim3(4, 39), 64, 0, stream>>>(Apool, Wp3, bl1, alpha, hid);
  head_k<<<64, 64, 0, stream>>>(hid, Wl2, bl2, out);
}

// Round 11
// 372.876 us; speedup vs baseline: 1.5350x; 1.1248x over previous
//
#include <hip/hip_runtime.h>

typedef __attribute__((ext_vector_type(8))) short short8;
typedef __attribute__((ext_vector_type(4))) float f32x4;
typedef unsigned short u16;
typedef unsigned int u32;

__device__ __forceinline__ u16 f2bf(float f) {
  u32 u = __float_as_uint(f);
  u = (u + 0x7fffu + ((u >> 16) & 1u)) >> 16;
  return (u16)u;
}
__device__ __forceinline__ float bf2f(u16 v) { return __uint_as_float((u32)v << 16); }
__device__ __forceinline__ void atomAddF(float* p, float v) { unsafeAtomicAdd(p, v); }
__device__ __forceinline__ void add4(float4& a, const float4 b) {
  a.x += b.x; a.y += b.y; a.z += b.z; a.w += b.w;
}
__device__ __forceinline__ void addp(float* v, u32 p) {
  v[0] += bf2f((u16)p);
  v[1] += bf2f((u16)(p >> 16));
}

// ---- prep: pack bf16 weights + graph bounds + zero scratch ---- grid 3042x256
__global__ void prep_k(const float* __restrict__ Wm1, const float* __restrict__ We1,
                       const float* __restrict__ Ws1, const float* __restrict__ Wm2,
                       const float* __restrict__ Wl1, const int* __restrict__ batch,
                       u16* __restrict__ Wp1, u16* __restrict__ Wp2, u16* __restrict__ Wp3,
                       int* __restrict__ gstart, int* __restrict__ gend,
                       int* __restrict__ deg, float* __restrict__ bns1p,
                       float* __restrict__ bns2p, int N) {
  int tid = blockIdx.x * 256 + threadIdx.x;
  if (tid < 64 * 192) {  // Wcat1 = [Wm1(16); We1(4); Ws1(16)], pad K to 64
    int k = tid / 192, n = tid % 192;
    float v = 0.f;
    if (k < 16) v = Wm1[k * 192 + n];
    else if (k < 20) v = We1[(k - 16) * 192 + n];
    else if (k < 36) v = Ws1[(k - 20) * 192 + n];
    Wp1[((k >> 3) * 192 + n) * 8 + (k & 7)] = f2bf(v);
  }
  if (tid < 224 * 208) {  // W_msg2, pad K 208->224
    int k = tid / 208, n = tid % 208;
    float v = (k < 208) ? Wm2[k * 208 + n] : 0.f;
    Wp2[((k >> 3) * 208 + n) * 8 + (k & 7)] = f2bf(v);
  }
  if (tid < N) {
    int b = batch[tid];
    if (tid == 0 || batch[tid - 1] != b) gstart[b] = tid;
    if (tid == N - 1 || batch[tid + 1] != b) gend[b] = tid;
    deg[tid] = 0;
  }
  if (tid < 64 * 384) bns1p[tid] = 0.f;
  if (tid < 64 * 832) bns2p[tid] = 0.f;
  if (tid < 1248 * 624) {
    int k = tid / 624, n = tid % 624;
    Wp3[((size_t)(k >> 3) * 624 + n) * 8 + (k & 7)] = f2bf(Wl1[(size_t)k * 624 + n]);
  }
}

// ---- CSR build ----
__global__ void count_k(const int* __restrict__ ei, int* __restrict__ deg, int E) {
  int e = blockIdx.x * 256 + threadIdx.x;
  if (e >= E) return;
  atomicAdd(&deg[ei[E + e]], 1);
}

__global__ void scanA_k(const int* __restrict__ deg, int* __restrict__ bsum, int N) {
  __shared__ int sh[256];
  int t = threadIdx.x;
  int i = blockIdx.x * 256 + t;
  sh[t] = (i < N) ? deg[i] : 0;
  __syncthreads();
  for (int off = 128; off > 0; off >>= 1) {
    if (t < off) sh[t] += sh[t + off];
    __syncthreads();
  }
  if (t == 0) bsum[blockIdx.x] = sh[0];
}

__global__ void scanC_k(const int* __restrict__ deg, const int* __restrict__ bsum,
                        int* __restrict__ rowptr, int* __restrict__ cur, int N, int nb) {
  __shared__ int sb2[256];
  __shared__ int sh[256];
  int t = threadIdx.x;
  int bv = (t < nb) ? bsum[t] : 0;
  sb2[t] = bv;
  __syncthreads();
  for (int off = 1; off < 256; off <<= 1) {
    int u = (t >= off) ? sb2[t - off] : 0;
    __syncthreads();
    sb2[t] += u;
    __syncthreads();
  }
  int bpref = (blockIdx.x == 0) ? 0 : sb2[blockIdx.x - 1];
  int i = blockIdx.x * 256 + t;
  int d = (i < N) ? deg[i] : 0;
  sh[t] = d;
  __syncthreads();
  for (int off = 1; off < 256; off <<= 1) {
    int u = (t >= off) ? sh[t - off] : 0;
    __syncthreads();
    sh[t] += u;
    __syncthreads();
  }
  int excl = sh[t] - d + bpref;
  if (i < N) {
    rowptr[i] = excl;
    cur[i] = excl;
    if (i == N - 1) rowptr[N] = excl + d;
  }
}

__global__ void scatter_k(const int* __restrict__ ei, int* __restrict__ cur,
                          int2* __restrict__ se, int E) {
  int e = blockIdx.x * 256 + threadIdx.x;
  if (e >= E) return;
  int s = ei[e], d = ei[E + e];
  int slot = atomicAdd(&cur[d], 1);
  se[slot] = make_int2(s, e);
}

// ---- CONV1: gather1 + U1(LDS) + gemm1 MFMA + h1bf + bn1 sliced stats ----
// grid ceil(N/32), block 256. Phase A: 8 lanes/node. Phase B: 24 MFMA jobs.
__global__ void __launch_bounds__(256) conv1_k(
    const int2* __restrict__ se, const int* __restrict__ rowptr,
    const float* __restrict__ x, const float* __restrict__ ea,
    const u16* __restrict__ Bp, const float* __restrict__ bm1,
    const float* __restrict__ be1, const float* __restrict__ bs1,
    u16* __restrict__ acc1c, u16* __restrict__ h1bf, float* __restrict__ bns1p, int N) {
  __shared__ __align__(16) u16 Uls[32][72];
  __shared__ float degls[32];
  int tid = threadIdx.x;
  int nl = tid >> 3, q = tid & 7;
  int n = blockIdx.x * 32 + nl;
  bool nval = n < N;
  int j0 = nval ? rowptr[n] : 0;
  int j1 = nval ? rowptr[n + 1] : 0;
  float4 a0 = {0, 0, 0, 0}, a1 = a0, a2 = a0, a3 = a0, a4 = a0;
  int j = j0 + q;
  if (j < j1) {
    int2 p = se[j];
    for (;;) {
      int jn = j + 8;
      bool more = jn < j1;
      int2 pn = more ? se[jn] : p;
      const float4* xs = (const float4*)(x + (size_t)p.x * 16);
      float4 w = *(const float4*)(ea + (size_t)p.y * 4);
      add4(a0, xs[0]); add4(a1, xs[1]); add4(a2, xs[2]); add4(a3, xs[3]); add4(a4, w);
      if (!more) break;
      j = jn; p = pn;
    }
  }
  float v[20] = {a0.x, a0.y, a0.z, a0.w, a1.x, a1.y, a1.z, a1.w,
                 a2.x, a2.y, a2.z, a2.w, a3.x, a3.y, a3.z, a3.w,
                 a4.x, a4.y, a4.z, a4.w};
#pragma unroll
  for (int i = 0; i < 20; ++i) {
    v[i] += __shfl_xor(v[i], 1);
    v[i] += __shfl_xor(v[i], 2);
    v[i] += __shfl_xor(v[i], 4);
  }
  float degf = (float)(j1 - j0);
  // U1 row -> LDS: [sums20, x(n)16, 0..]; lane q writes elems q*8..q*8+7
  const float* xr = x + (size_t)n * 16;
  {
    u32 w4[4];
#pragma unroll
    for (int jj = 0; jj < 4; ++jj) {
      int t0 = q * 8 + 2 * jj, t1 = t0 + 1;
      float f0 = (t0 < 20) ? v[t0] : ((t0 < 36 && nval) ? xr[t0 - 20] : 0.f);
      float f1 = (t1 < 20) ? v[t1] : ((t1 < 36 && nval) ? xr[t1 - 20] : 0.f);
      w4[jj] = (u32)f2bf(f0) | ((u32)f2bf(f1) << 16);
    }
    *(uint4*)&Uls[nl][q * 8] = make_uint4(w4[0], w4[1], w4[2], w4[3]);
  }
  // acc1c row (global): [sx16, sea4, deg, 0..11] as 32 bf16; lane q -> elems q*4..q*4+3
  if (nval) {
    u32 c2[2];
#pragma unroll
    for (int jj = 0; jj < 2; ++jj) {
      int t0 = q * 4 + 2 * jj, t1 = t0 + 1;
      float f0 = (t0 < 20) ? v[t0] : ((t0 == 20) ? degf : 0.f);
      float f1 = (t1 < 20) ? v[t1] : ((t1 == 20) ? degf : 0.f);
      c2[jj] = (u32)f2bf(f0) | ((u32)f2bf(f1) << 16);
    }
    *(uint2*)(acc1c + (size_t)n * 32 + q * 4) = make_uint2(c2[0], c2[1]);
  }
  if (q == 0) degls[nl] = degf;
  __syncthreads();
  // Phase B: 2 m-tiles x 12 n-tiles
  int w = tid >> 6, lane = tid & 63, rc = lane & 15, qd = lane >> 4;
  int slice = (blockIdx.x & 63) * 384;
  for (int jb = w; jb < 24; jb += 4) {
    int mt_l = jb & 1, nt = jb >> 1;
    f32x4 acc = {0.f, 0.f, 0.f, 0.f};
#pragma unroll
    for (int kb = 0; kb < 2; ++kb) {
      short8 av = *(const short8*)&Uls[mt_l * 16 + rc][kb * 32 + qd * 8];
      short8 bv = *(const short8*)(Bp + (size_t)((kb * 4 + qd) * 192 + nt * 16 + rc) * 8);
      acc = __builtin_amdgcn_mfma_f32_16x16x32_bf16(av, bv, acc, 0, 0, 0);
    }
    int col = nt * 16 + rc;
    float bb = bm1[col] + be1[col], bsv = bs1[col];
    int ml0 = mt_l * 16 + qd * 4;
    float ps = 0.f, pq = 0.f;
#pragma unroll
    for (int r = 0; r < 4; ++r) {
      int ml = ml0 + r;
      int m = blockIdx.x * 32 + ml;
      float val = acc[r] + degls[ml] * bb + bsv;
      bool mv = m < N;
      if (mv) {
        h1bf[(size_t)m * 192 + col] = f2bf(val);
        ps += val;
        pq += val * val;
      }
    }
    ps += __shfl_xor(ps, 16); ps += __shfl_xor(ps, 32);
    pq += __shfl_xor(pq, 16); pq += __shfl_xor(pq, 32);
    if (qd == 0) {
      atomAddF(&bns1p[slice + col], ps);
      atomAddF(&bns1p[slice + 192 + col], pq);
    }
  }
}

// ---- bn1 finalize: aff1[c]=scale, aff1[192+c]=shift ---- 1 block, 256 threads
__global__ void bnfin1_k(const float* __restrict__ bns1p, const float* __restrict__ g1,
                         const float* __restrict__ bta1, float Ninv,
                         float* __restrict__ aff1) {
  int c = threadIdx.x;
  if (c >= 192) return;
  float sm = 0.f, sq = 0.f;
  for (int k = 0; k < 64; ++k) {
    sm += bns1p[k * 384 + c];
    sq += bns1p[k * 384 + 192 + c];
  }
  float m1 = sm * Ninv;
  float var = sq * Ninv - m1 * m1;
  float s1 = g1[c] * rsqrtf(var + 1e-5f);
  aff1[c] = s1;
  aff1[192 + c] = bta1[c] - m1 * s1;
}

// ---- CONV2: gather2 + U2(LDS) + gemmq2 (V in LDS) + gemm2 + h2bf + bn2 stats ----
// grid ceil(N/32), block 256
__global__ void __launch_bounds__(256) conv2_k(
    const int2* __restrict__ se, const int* __restrict__ rowptr,
    const u16* __restrict__ acc1c, const u16* __restrict__ h1bf,
    const float* __restrict__ x, const u16* __restrict__ Bp1, const u16* __restrict__ Bp2,
    const float* __restrict__ bm1, const float* __restrict__ be1,
    const float* __restrict__ bs1, const float* __restrict__ aff1,
    const float* __restrict__ We2, const float* __restrict__ bm2,
    const float* __restrict__ be2, float* __restrict__ bns2p,
    u16* __restrict__ h2bf, int N) {
  __shared__ __align__(16) u16 Uls[32][72];
  __shared__ __align__(16) u16 Vls[32][232];
  __shared__ float degls[32], sdegls[32], eals[32][4];
  int tid = threadIdx.x;
  int nl = tid >> 3, q = tid & 7;
  int n = blockIdx.x * 32 + nl;
  bool nval = n < N;
  int j0 = nval ? rowptr[n] : 0;
  int j1 = nval ? rowptr[n + 1] : 0;
  float v[21];
#pragma unroll
  for (int i = 0; i < 21; ++i) v[i] = 0.f;
  for (int j = j0 + q; j < j1; j += 8) {
    int s = se[j].x;
    const uint4* cr = (const uint4*)(acc1c + (size_t)s * 32);
    uint4 c0 = cr[0], c1 = cr[1], c2 = cr[2];
    addp(v + 0, c0.x); addp(v + 2, c0.y); addp(v + 4, c0.z); addp(v + 6, c0.w);
    addp(v + 8, c1.x); addp(v + 10, c1.y); addp(v + 12, c1.z); addp(v + 14, c1.w);
    addp(v + 16, c2.x); addp(v + 18, c2.y);
    v[20] += bf2f((u16)c2.z);
  }
#pragma unroll
  for (int i = 0; i < 21; ++i) {
    v[i] += __shfl_xor(v[i], 1);
    v[i] += __shfl_xor(v[i], 2);
    v[i] += __shfl_xor(v[i], 4);
  }
  const u16* selfr = acc1c + (size_t)n * 32;
  // U2 row -> LDS: [sums20, self sx16, 0..]
  {
    u32 w4[4];
#pragma unroll
    for (int jj = 0; jj < 4; ++jj) {
      int t0 = q * 8 + 2 * jj, t1 = t0 + 1;
      u16 b0 = (t0 < 20) ? f2bf(v[t0]) : ((t0 < 36 && nval) ? selfr[t0 - 20] : (u16)0);
      u16 b1 = (t1 < 20) ? f2bf(v[t1]) : ((t1 < 36 && nval) ? selfr[t1 - 20] : (u16)0);
      w4[jj] = (u32)b0 | ((u32)b1 << 16);
    }
    *(uint4*)&Uls[nl][q * 8] = make_uint4(w4[0], w4[1], w4[2], w4[3]);
  }
  // V tail cols [192..224): self sx16 then zeros
  if (q < 4) {
    u32 w4[4];
#pragma unroll
    for (int jj = 0; jj < 4; ++jj) {
      int t0 = q * 8 + 2 * jj, t1 = t0 + 1;
      u16 b0 = (t0 < 16 && nval) ? selfr[t0] : (u16)0;
      u16 b1 = (t1 < 16 && nval) ? selfr[t1] : (u16)0;
      w4[jj] = (u32)b0 | ((u32)b1 << 16);
    }
    *(uint4*)&Vls[nl][192 + q * 8] = make_uint4(w4[0], w4[1], w4[2], w4[3]);
  }
  if (q == 0) sdegls[nl] = v[20];
  if (q == 1) degls[nl] = nval ? bf2f(selfr[20]) : 0.f;
  if (q == 2) {
#pragma unroll
    for (int k = 0; k < 4; ++k) eals[nl][k] = nval ? bf2f(selfr[16 + k]) : 0.f;
  }
  __syncthreads();
  // Phase B: gemmq2 -> Vls[:,0..192)
  int w = tid >> 6, lane = tid & 63, rc = lane & 15, qd = lane >> 4;
  for (int jb = w; jb < 24; jb += 4) {
    int mt_l = jb & 1, nt = jb >> 1;
    f32x4 acc = {0.f, 0.f, 0.f, 0.f};
#pragma unroll
    for (int kb = 0; kb < 2; ++kb) {
      short8 av = *(const short8*)&Uls[mt_l * 16 + rc][kb * 32 + qd * 8];
      short8 bv = *(const short8*)(Bp1 + (size_t)((kb * 4 + qd) * 192 + nt * 16 + rc) * 8);
      acc = __builtin_amdgcn_mfma_f32_16x16x32_bf16(av, bv, acc, 0, 0, 0);
    }
    int col = nt * 16 + rc;
    float s1 = aff1[col], t1 = aff1[192 + col];
    float bb = bm1[col] + be1[col], bsv = bs1[col];
    int ml0 = mt_l * 16 + qd * 4;
#pragma unroll
    for (int r = 0; r < 4; ++r) {
      int ml = ml0 + r;
      float qv = acc[r] + sdegls[ml] * bb + degls[ml] * bsv;
      Vls[ml][col] = f2bf(qv * s1 + degls[ml] * t1);
    }
  }
  __syncthreads();
  // Phase C: gemm2, A = Vls
  int slice = (blockIdx.x & 63) * 832;
  for (int jb = w; jb < 26; jb += 4) {
    int mt_l = jb & 1, nt = jb >> 1;
    f32x4 acc = {0.f, 0.f, 0.f, 0.f};
#pragma unroll
    for (int kb = 0; kb < 7; ++kb) {
      short8 av = *(const short8*)&Vls[mt_l * 16 + rc][kb * 32 + qd * 8];
      short8 bv = *(const short8*)(Bp2 + (size_t)((kb * 4 + qd) * 208 + nt * 16 + rc) * 8);
      acc = __builtin_amdgcn_mfma_f32_16x16x32_bf16(av, bv, acc, 0, 0, 0);
    }
    int col = nt * 16 + rc;
    float w0 = We2[col], w1 = We2[208 + col], w2 = We2[416 + col], w3 = We2[624 + col];
    float bb2 = bm2[col] + be2[col];
    bool c192 = col < 192;
    float s1 = c192 ? aff1[col] : 0.f;
    float t1 = c192 ? aff1[192 + col] : 0.f;
    int ml0 = mt_l * 16 + qd * 4;
    float ps = 0.f, pq = 0.f;
#pragma unroll
    for (int r = 0; r < 4; ++r) {
      int ml = ml0 + r;
      int m = blockIdx.x * 32 + ml;
      bool mv = m < N;
      float x1 = 0.f;
      if (mv) {
        x1 = c192 ? (bf2f(h1bf[(size_t)m * 192 + col]) * s1 + t1)
                  : x[(size_t)m * 16 + (col - 192)];
      }
      float val = acc[r] + eals[ml][0] * w0 + eals[ml][1] * w1 + eals[ml][2] * w2 +
                  eals[ml][3] * w3 + degls[ml] * bb2 + x1;
      if (mv) {
        h2bf[(size_t)m * 208 + col] = f2bf(val);
        ps += val;
        pq += val * val;
      }
    }
    ps += __shfl_xor(ps, 16); ps += __shfl_xor(ps, 32);
    pq += __shfl_xor(pq, 16); pq += __shfl_xor(pq, 32);
    if (qd == 0) {
      atomAddF(&bns2p[slice + col], ps);
      atomAddF(&bns2p[slice + 416 + col], pq);
    }
  }
}

// ---- bn finalize: unified affine table aff[f]=scale, aff[416+f]=shift ---- grid 2x256
__global__ void bnfin2_k(const float* __restrict__ bns2p, const float* __restrict__ aff1,
                         const float* __restrict__ g2, const float* __restrict__ bta2,
                         float Ninv, float* __restrict__ aff) {
  int f = blockIdx.x * 256 + threadIdx.x;
  if (f >= 416) return;
  float sc, sh;
  if (f < 208) {
    float sm = 0.f, sq = 0.f;
    for (int k = 0; k < 64; ++k) {
      sm += bns2p[k * 832 + f];
      sq += bns2p[k * 832 + 416 + f];
    }
    float m2 = sm * Ninv;
    float var = sq * Ninv - m2 * m2;
    sc = g2[f] * rsqrtf(var + 1e-5f);
    sh = bta2[f] - m2 * sc;
  } else if (f < 400) {
    sc = aff1[f - 208];
    sh = aff1[192 + (f - 208)];
  } else {
    sc = 1.f;
    sh = 0.f;
  }
  aff[f] = sc;
  aff[416 + f] = sh;
}

// ---- pooling: feature-pair threads, partial stores ---- grid=(64,16), block=256
__global__ void pool_k(const u16* __restrict__ h2bf, const u16* __restrict__ h1bf,
                       const float* __restrict__ x, const float* __restrict__ aff,
                       const int* __restrict__ gstart, const int* __restrict__ gend,
                       float* __restrict__ psp, float* __restrict__ pmp) {
  int b = blockIdx.x, sub = blockIdx.y;
  int t = threadIdx.x;
  if (t >= 208) return;
  int s0 = gstart[b], e0 = gend[b];
  int cnt = (s0 <= e0) ? e0 - s0 + 1 : 0;
  int per = (cnt + 15) >> 4;
  int n0 = s0 + sub * per;
  int n1 = min(n0 + per, s0 + cnt);
  int f = 2 * t;
  float sc0 = aff[f], sc1 = aff[f + 1];
  float sh0 = aff[416 + f], sh1 = aff[417 + f];
  float s0f = 0.f, s1f = 0.f, m0f = -3.4e38f, m1f = -3.4e38f;
  if (f < 208) {
    for (int n = n0; n < n1; ++n) {
      u32 p = *(const u32*)(h2bf + (size_t)n * 208 + f);
      float v0 = bf2f((u16)p) * sc0 + sh0;
      float v1 = bf2f((u16)(p >> 16)) * sc1 + sh1;
      s0f += v0; s1f += v1;
      m0f = fmaxf(m0f, v0); m1f = fmaxf(m1f, v1);
    }
  } else if (f < 400) {
    int jc = f - 208;
    for (int n = n0; n < n1; ++n) {
      u32 p = *(const u32*)(h1bf + (size_t)n * 192 + jc);
      float v0 = bf2f((u16)p) * sc0 + sh0;
      float v1 = bf2f((u16)(p >> 16)) * sc1 + sh1;
      s0f += v0; s1f += v1;
      m0f = fmaxf(m0f, v0); m1f = fmaxf(m1f, v1);
    }
  } else {
    int jc = f - 400;
    for (int n = n0; n < n1; ++n) {
      float2 p = *(const float2*)(x + (size_t)n * 16 + jc);
      s0f += p.x; s1f += p.y;
      m0f = fmaxf(m0f, p.x); m1f = fmaxf(m1f, p.y);
    }
  }
  size_t idx = ((size_t)(b * 16 + sub)) * 416 + f;
  *(float2*)(psp + idx) = make_float2(s0f, s1f);
  *(float2*)(pmp + idx) = make_float2(m0f, m1f);
}

// ---- pooled partial reduce -> bf16 A matrix [64 x 1248] ---- grid=64, block=256
__global__ void pooledprep_k(const float* __restrict__ psp, const float* __restrict__ pmp,
                             const int* __restrict__ gstart, const int* __restrict__ gend,
                             u16* __restrict__ Apool) {
  int b = blockIdx.x, t = threadIdx.x;
  int cnt = gend[b] - gstart[b] + 1;
  float inv = 1.f / (float)max(cnt, 1);
  for (int f = t; f < 416; f += 256) {
    float s = 0.f, m = -3.4e38f;
    for (int k = 0; k < 16; ++k) {
      size_t idx = ((size_t)(b * 16 + k)) * 416 + f;
      s += psp[idx];
      m = fmaxf(m, pmp[idx]);
    }
    u16* row = Apool + (size_t)b * 1248;
    row[f] = f2bf(s);
    row[416 + f] = f2bf((cnt > 0) ? m : 0.f);
    row[832 + f] = f2bf(s * inv);
  }
}

// ---- MLP layer 1 via MFMA ---- grid=(4,39), block=64
__global__ void mlpgemm_k(const u16* __restrict__ A, const u16* __restrict__ Bp,
                          const float* __restrict__ b1, const float* __restrict__ al,
                          float* __restrict__ hid) {
  int lane = threadIdx.x;
  int mt = blockIdx.x, nt = blockIdx.y;
  int rc = lane & 15, qd = lane >> 4;
  f32x4 acc = {0.f, 0.f, 0.f, 0.f};
  const u16* Ap = A + (size_t)(mt * 16 + rc) * 1248 + qd * 8;
  const u16* Bq = Bp + (size_t)(qd * 624 + nt * 16 + rc) * 8;
  for (int kb = 0; kb < 39; ++kb) {
    short8 av = *(const short8*)(Ap + kb * 32);
    short8 bv = *(const short8*)(Bq + (size_t)kb * 4 * 624 * 8);
    acc = __builtin_amdgcn_mfma_f32_16x16x32_bf16(av, bv, acc, 0, 0, 0);
  }
  int col = nt * 16 + rc;
  float bb = b1[col], alpha = al[0];
  int m0 = mt * 16 + qd * 4;
#pragma unroll
  for (int r = 0; r < 4; ++r) {
    float v = acc[r] + bb;
    hid[(size_t)(m0 + r) * 624 + col] = (v >= 0.f) ? v : alpha * v;
  }
}

// ---- logits + log_softmax ---- grid=64, block=64
__global__ void head_k(const float* __restrict__ hid, const float* __restrict__ W2,
                       const float* __restrict__ b2, float* __restrict__ out) {
  int b = blockIdx.x, t = threadIdx.x;
  float p0 = 0.f, p1 = 0.f;
  for (int k = t; k < 624; k += 64) {
    float h = hid[(size_t)b * 624 + k];
    p0 += h * W2[k * 2];
    p1 += h * W2[k * 2 + 1];
  }
#pragma unroll
  for (int off = 32; off > 0; off >>= 1) {
    p0 += __shfl_down(p0, off);
    p1 += __shfl_down(p1, off);
  }
  if (t == 0) {
    float l0 = p0 + b2[0], l1 = p1 + b2[1];
    float m = fmaxf(l0, l1);
    float lse = m + logf(expf(l0 - m) + expf(l1 - m));
    out[b * 2] = l0 - lse;
    out[b * 2 + 1] = l1 - lse;
  }
}

extern "C" void kernel_launch(void* const* d_in, const int* in_sizes, int n_in,
                              void* d_out, int out_size, void* d_ws, size_t ws_size,
                              hipStream_t stream) {
  const float* x = (const float*)d_in[0];
  const int* ei = (const int*)d_in[1];
  const float* ea = (const float*)d_in[2];
  const int* batch = (const int*)d_in[3];
  const float* Wm1 = (const float*)d_in[4];
  const float* bm1 = (const float*)d_in[5];
  const float* We1 = (const float*)d_in[6];
  const float* be1 = (const float*)d_in[7];
  const float* Ws1 = (const float*)d_in[8];
  const float* bs1 = (const float*)d_in[9];
  const float* g1 = (const float*)d_in[10];
  const float* bta1 = (const float*)d_in[11];
  const float* Wm2 = (const float*)d_in[12];
  const float* bm2 = (const float*)d_in[13];
  const float* We2 = (const float*)d_in[14];
  const float* be2 = (const float*)d_in[15];
  const float* g2 = (const float*)d_in[16];
  const float* bta2 = (const float*)d_in[17];
  const float* Wl1 = (const float*)d_in[18];
  const float* bl1 = (const float*)d_in[19];
  const float* alpha = (const float*)d_in[20];
  const float* Wl2 = (const float*)d_in[21];
  const float* bl2 = (const float*)d_in[22];
  float* out = (float*)d_out;

  const int N = in_sizes[3];      // 50000
  const int E = in_sizes[2] / 4;  // 800000
  const int nb = (N + 255) / 256; // 196 (<=256)
  const float Ninv = 1.f / (float)N;

  float* ws = (float*)d_ws;
  size_t o = 0;
  u16* acc1c = (u16*)(ws + o); o += (size_t)N * 16;  // N*32 u16
  u16* h2bf = (u16*)(ws + o);  o += (size_t)N * 104; // N*208 u16
  u16* h1bf = (u16*)(ws + o);  o += (size_t)N * 96;  // N*192 u16
  u16* Wp1 = (u16*)(ws + o);   o += 6144;
  u16* Wp2 = (u16*)(ws + o);   o += 23296;
  u16* Wp3 = (u16*)(ws + o);   o += 389376;
  u16* Apool = (u16*)(ws + o); o += 39936;
  float* hid = ws + o;    o += 64 * 624;
  float* bns1p = ws + o;  o += 64 * 384;
  float* bns2p = ws + o;  o += 64 * 832;
  float* aff1 = ws + o;   o += 384;
  float* aff = ws + o;    o += 832;
  float* psp = ws + o;    o += (size_t)64 * 16 * 416;
  float* pmp = ws + o;    o += (size_t)64 * 16 * 416;
  int* gstart = (int*)(ws + o); o += 64;
  int* gend = (int*)(ws + o);   o += 64;
  int* deg = (int*)(ws + o);    o += N;
  int* rowptr = (int*)(ws + o); o += N + 1;
  int* cur = (int*)(ws + o);    o += N + 1;
  int* bsum = (int*)(ws + o);   o += 256;
  int2* se = (int2*)(ws + o);   o += (size_t)2 * E;  // standalone: conv2 reads se while writing h2bf

  const int gconv = (N + 31) / 32;  // 1563
  prep_k<<<3042, 256, 0, stream>>>(Wm1, We1, Ws1, Wm2, Wl1, batch, Wp1, Wp2, Wp3, gstart,
                                   gend, deg, bns1p, bns2p, N);
  count_k<<<(E + 255) / 256, 256, 0, stream>>>(ei, deg, E);
  scanA_k<<<nb, 256, 0, stream>>>(deg, bsum, N);
  scanC_k<<<nb, 256, 0, stream>>>(deg, bsum, rowptr, cur, N, nb);
  scatter_k<<<(E + 255) / 256, 256, 0, stream>>>(ei, cur, se, E);
  conv1_k<<<gconv, 256, 0, stream>>>(se, rowptr, x, ea, Wp1, bm1, be1, bs1, acc1c, h1bf,
                                     bns1p, N);
  bnfin1_k<<<1, 256, 0, stream>>>(bns1p, g1, bta1, Ninv, aff1);
  conv2_k<<<gconv, 256, 0, stream>>>(se, rowptr, acc1c, h1bf, x, Wp1, Wp2, bm1, be1, bs1,
                                     aff1, We2, bm2, be2, bns2p, h2bf, N);
  bnfin2_k<<<2, 256, 0, stream>>>(bns2p, aff1, g2, bta2, Ninv, aff);
  pool_k<<<dim3(64, 16), 256, 0, stream>>>(h2bf, h1bf, x, aff, gstart, gend, psp, pmp);
  pooledprep_k<<<64, 256, 0, stream>>>(psp, pmp, gstart, gend, Apool);
  mlpgemm_k<<<dim3(4, 39), 64, 0, stream>>>(Apool, Wp3, bl1, alpha, hid);
  head_k<<<64, 64, 0, stream>>>(hid, Wl2, bl2, out);
}

// Round 12
// 368.045 us; speedup vs baseline: 1.5552x; 1.0131x over previous
//
#include <hip/hip_runtime.h>

typedef __attribute__((ext_vector_type(8))) short short8;
typedef __attribute__((ext_vector_type(4))) float f32x4;
typedef unsigned short u16;
typedef unsigned int u32;

__device__ __forceinline__ u16 f2bf(float f) {
  u32 u = __float_as_uint(f);
  u = (u + 0x7fffu + ((u >> 16) & 1u)) >> 16;
  return (u16)u;
}
__device__ __forceinline__ float bf2f(u16 v) { return __uint_as_float((u32)v << 16); }
__device__ __forceinline__ void atomAddF(float* p, float v) { unsafeAtomicAdd(p, v); }
__device__ __forceinline__ void addp(float* v, u32 p) {
  v[0] += bf2f((u16)p);
  v[1] += bf2f((u16)(p >> 16));
}

// ---- prep: pack bf16 weights + ea->bf16 + graph bounds + zero scratch ---- grid 3125x256
__global__ void prep_k(const float* __restrict__ Wm1, const float* __restrict__ We1,
                       const float* __restrict__ Ws1, const float* __restrict__ Wm2,
                       const float* __restrict__ Wl1, const float* __restrict__ ea,
                       const int* __restrict__ batch, u16* __restrict__ Wp1,
                       u16* __restrict__ Wp2, u16* __restrict__ Wp3,
                       u16* __restrict__ eabf, int* __restrict__ gstart,
                       int* __restrict__ gend, int* __restrict__ deg,
                       float* __restrict__ bns1p, float* __restrict__ bns2p, int N, int E) {
  int tid = blockIdx.x * 256 + threadIdx.x;
  if (tid < 64 * 192) {  // Wcat1 = [Wm1(16); We1(4); Ws1(16)], pad K to 64
    int k = tid / 192, n = tid % 192;
    float v = 0.f;
    if (k < 16) v = Wm1[k * 192 + n];
    else if (k < 20) v = We1[(k - 16) * 192 + n];
    else if (k < 36) v = Ws1[(k - 20) * 192 + n];
    Wp1[((k >> 3) * 192 + n) * 8 + (k & 7)] = f2bf(v);
  }
  if (tid < 224 * 208) {  // W_msg2, pad K 208->224
    int k = tid / 208, n = tid % 208;
    float v = (k < 208) ? Wm2[k * 208 + n] : 0.f;
    Wp2[((k >> 3) * 208 + n) * 8 + (k & 7)] = f2bf(v);
  }
  if (tid < E) {
    float4 w = *(const float4*)(ea + (size_t)tid * 4);
    uint2 p;
    p.x = (u32)f2bf(w.x) | ((u32)f2bf(w.y) << 16);
    p.y = (u32)f2bf(w.z) | ((u32)f2bf(w.w) << 16);
    *(uint2*)(eabf + (size_t)tid * 4) = p;
  }
  if (tid < N) {
    int b = batch[tid];
    if (tid == 0 || batch[tid - 1] != b) gstart[b] = tid;
    if (tid == N - 1 || batch[tid + 1] != b) gend[b] = tid;
    deg[tid] = 0;
  }
  if (tid < 64 * 384) bns1p[tid] = 0.f;
  if (tid < 64 * 832) bns2p[tid] = 0.f;
  if (tid < 1248 * 624) {
    int k = tid / 624, n = tid % 624;
    Wp3[((size_t)(k >> 3) * 624 + n) * 8 + (k & 7)] = f2bf(Wl1[(size_t)k * 624 + n]);
  }
}

// ---- CSR build ----
__global__ void count_k(const int* __restrict__ ei, int* __restrict__ deg, int E) {
  int e = blockIdx.x * 256 + threadIdx.x;
  if (e >= E) return;
  atomicAdd(&deg[ei[E + e]], 1);
}

__global__ void scanA_k(const int* __restrict__ deg, int* __restrict__ bsum, int N) {
  __shared__ int sh[256];
  int t = threadIdx.x;
  int i = blockIdx.x * 256 + t;
  sh[t] = (i < N) ? deg[i] : 0;
  __syncthreads();
  for (int off = 128; off > 0; off >>= 1) {
    if (t < off) sh[t] += sh[t + off];
    __syncthreads();
  }
  if (t == 0) bsum[blockIdx.x] = sh[0];
}

__global__ void scanC_k(const int* __restrict__ deg, const int* __restrict__ bsum,
                        int* __restrict__ rowptr, int* __restrict__ cur, int N, int nb) {
  __shared__ int sb2[256];
  __shared__ int sh[256];
  int t = threadIdx.x;
  int bv = (t < nb) ? bsum[t] : 0;
  sb2[t] = bv;
  __syncthreads();
  for (int off = 1; off < 256; off <<= 1) {
    int u = (t >= off) ? sb2[t - off] : 0;
    __syncthreads();
    sb2[t] += u;
    __syncthreads();
  }
  int bpref = (blockIdx.x == 0) ? 0 : sb2[blockIdx.x - 1];
  int i = blockIdx.x * 256 + t;
  int d = (i < N) ? deg[i] : 0;
  sh[t] = d;
  __syncthreads();
  for (int off = 1; off < 256; off <<= 1) {
    int u = (t >= off) ? sh[t - off] : 0;
    __syncthreads();
    sh[t] += u;
    __syncthreads();
  }
  int excl = sh[t] - d + bpref;
  if (i < N) {
    rowptr[i] = excl;
    cur[i] = excl;
    if (i == N - 1) rowptr[N] = excl + d;
  }
}

__global__ void scatter_k(const int* __restrict__ ei, int* __restrict__ cur,
                          int2* __restrict__ se, int E) {
  int e = blockIdx.x * 256 + threadIdx.x;
  if (e >= E) return;
  int s = ei[e], d = ei[E + e];
  int slot = atomicAdd(&cur[d], 1);
  se[slot] = make_int2(s, e);
}

// ---- CONV1: gather1 + U1(LDS) + gemm1 MFMA + h1bf + bn1 sliced stats ----
// grid ceil(N/16), block 128 (2 waves). Phase A: 8 lanes/node.
__global__ void __launch_bounds__(128) conv1_k(
    const int2* __restrict__ se, const int* __restrict__ rowptr,
    const float* __restrict__ x, const u16* __restrict__ eabf,
    const u16* __restrict__ Bp, const float* __restrict__ bm1,
    const float* __restrict__ be1, const float* __restrict__ bs1,
    u16* __restrict__ acc1c, u16* __restrict__ h1bf, float* __restrict__ bns1p, int N) {
  __shared__ __align__(16) u16 Uls[16][72];
  __shared__ float degls[16];
  int tid = threadIdx.x;
  int nl = tid >> 3, q = tid & 7;
  int n = blockIdx.x * 16 + nl;
  bool nval = n < N;
  int j0 = nval ? rowptr[n] : 0;
  int j1 = nval ? rowptr[n + 1] : 0;
  float v[20];
#pragma unroll
  for (int i = 0; i < 20; ++i) v[i] = 0.f;
  for (int j = j0 + q; j < j1; j += 8) {
    int2 p = se[j];
    const float4* xs = (const float4*)(x + (size_t)p.x * 16);
    float4 t0 = xs[0], t1 = xs[1], t2 = xs[2], t3 = xs[3];
    uint2 w = *(const uint2*)(eabf + (size_t)p.y * 4);
    v[0] += t0.x; v[1] += t0.y; v[2] += t0.z; v[3] += t0.w;
    v[4] += t1.x; v[5] += t1.y; v[6] += t1.z; v[7] += t1.w;
    v[8] += t2.x; v[9] += t2.y; v[10] += t2.z; v[11] += t2.w;
    v[12] += t3.x; v[13] += t3.y; v[14] += t3.z; v[15] += t3.w;
    addp(v + 16, w.x); addp(v + 18, w.y);
  }
#pragma unroll
  for (int i = 0; i < 20; ++i) {
    v[i] += __shfl_xor(v[i], 1);
    v[i] += __shfl_xor(v[i], 2);
    v[i] += __shfl_xor(v[i], 4);
  }
  float degf = (float)(j1 - j0);
  const float* xr = x + (size_t)n * 16;
  {  // U1 row -> LDS: [sums20, x(n)16, 0..]; lane q writes elems q*8..q*8+7
    u32 w4[4];
#pragma unroll
    for (int jj = 0; jj < 4; ++jj) {
      int t0 = q * 8 + 2 * jj, t1 = t0 + 1;
      float f0 = (t0 < 20) ? v[t0] : ((t0 < 36 && nval) ? xr[t0 - 20] : 0.f);
      float f1 = (t1 < 20) ? v[t1] : ((t1 < 36 && nval) ? xr[t1 - 20] : 0.f);
      w4[jj] = (u32)f2bf(f0) | ((u32)f2bf(f1) << 16);
    }
    *(uint4*)&Uls[nl][q * 8] = make_uint4(w4[0], w4[1], w4[2], w4[3]);
  }
  if (nval) {  // acc1c row: [sx16, sea4, deg, 0..]; lane q -> elems q*4..q*4+3
    u32 c2[2];
#pragma unroll
    for (int jj = 0; jj < 2; ++jj) {
      int t0 = q * 4 + 2 * jj, t1 = t0 + 1;
      float f0 = (t0 < 20) ? v[t0] : ((t0 == 20) ? degf : 0.f);
      float f1 = (t1 < 20) ? v[t1] : ((t1 == 20) ? degf : 0.f);
      c2[jj] = (u32)f2bf(f0) | ((u32)f2bf(f1) << 16);
    }
    *(uint2*)(acc1c + (size_t)n * 32 + q * 4) = make_uint2(c2[0], c2[1]);
  }
  if (q == 0) degls[nl] = degf;
  __syncthreads();
  // Phase B: 12 n-tile jobs over 2 waves
  int w = tid >> 6, lane = tid & 63, rc = lane & 15, qd = lane >> 4;
  int slice = (blockIdx.x & 63) * 384;
  for (int nt = w; nt < 12; nt += 2) {
    f32x4 acc = {0.f, 0.f, 0.f, 0.f};
#pragma unroll
    for (int kb = 0; kb < 2; ++kb) {
      short8 av = *(const short8*)&Uls[rc][kb * 32 + qd * 8];
      short8 bv = *(const short8*)(Bp + (size_t)((kb * 4 + qd) * 192 + nt * 16 + rc) * 8);
      acc = __builtin_amdgcn_mfma_f32_16x16x32_bf16(av, bv, acc, 0, 0, 0);
    }
    int col = nt * 16 + rc;
    float bb = bm1[col] + be1[col], bsv = bs1[col];
    float ps = 0.f, pq = 0.f;
#pragma unroll
    for (int r = 0; r < 4; ++r) {
      int ml = qd * 4 + r;
      int m = blockIdx.x * 16 + ml;
      float val = acc[r] + degls[ml] * bb + bsv;
      if (m < N) {
        h1bf[(size_t)m * 192 + col] = f2bf(val);
        ps += val;
        pq += val * val;
      }
    }
    ps += __shfl_xor(ps, 16); ps += __shfl_xor(ps, 32);
    pq += __shfl_xor(pq, 16); pq += __shfl_xor(pq, 32);
    if (qd == 0) {
      atomAddF(&bns1p[slice + col], ps);
      atomAddF(&bns1p[slice + 192 + col], pq);
    }
  }
}

// ---- bn1 finalize ---- 1 block, 256 threads
__global__ void bnfin1_k(const float* __restrict__ bns1p, const float* __restrict__ g1,
                         const float* __restrict__ bta1, float Ninv,
                         float* __restrict__ aff1) {
  int c = threadIdx.x;
  if (c >= 192) return;
  float sm = 0.f, sq = 0.f;
  for (int k = 0; k < 64; ++k) {
    sm += bns1p[k * 384 + c];
    sq += bns1p[k * 384 + 192 + c];
  }
  float m1 = sm * Ninv;
  float var = sq * Ninv - m1 * m1;
  float s1 = g1[c] * rsqrtf(var + 1e-5f);
  aff1[c] = s1;
  aff1[192 + c] = bta1[c] - m1 * s1;
}

// ---- CONV2: gather2 + U2(LDS) + gemmq2 (V in LDS) + gemm2 + h2bf + bn2 stats ----
// grid ceil(N/16), block 128 (2 waves)
__global__ void __launch_bounds__(128) conv2_k(
    const int2* __restrict__ se, const int* __restrict__ rowptr,
    const u16* __restrict__ acc1c, const u16* __restrict__ h1bf,
    const float* __restrict__ x, const u16* __restrict__ Bp1, const u16* __restrict__ Bp2,
    const float* __restrict__ bm1, const float* __restrict__ be1,
    const float* __restrict__ bs1, const float* __restrict__ aff1,
    const float* __restrict__ We2, const float* __restrict__ bm2,
    const float* __restrict__ be2, float* __restrict__ bns2p,
    u16* __restrict__ h2bf, int N) {
  __shared__ __align__(16) u16 Uls[16][72];
  __shared__ __align__(16) u16 Vls[16][232];
  __shared__ float degls[16], sdegls[16], eals[16][4];
  int tid = threadIdx.x;
  int nl = tid >> 3, q = tid & 7;
  int n = blockIdx.x * 16 + nl;
  bool nval = n < N;
  int j0 = nval ? rowptr[n] : 0;
  int j1 = nval ? rowptr[n + 1] : 0;
  float v[21];
#pragma unroll
  for (int i = 0; i < 21; ++i) v[i] = 0.f;
  for (int j = j0 + q; j < j1; j += 8) {
    int s = se[j].x;
    const uint4* cr = (const uint4*)(acc1c + (size_t)s * 32);
    uint4 c0 = cr[0], c1 = cr[1], c2 = cr[2];
    addp(v + 0, c0.x); addp(v + 2, c0.y); addp(v + 4, c0.z); addp(v + 6, c0.w);
    addp(v + 8, c1.x); addp(v + 10, c1.y); addp(v + 12, c1.z); addp(v + 14, c1.w);
    addp(v + 16, c2.x); addp(v + 18, c2.y);
    v[20] += bf2f((u16)c2.z);
  }
#pragma unroll
  for (int i = 0; i < 21; ++i) {
    v[i] += __shfl_xor(v[i], 1);
    v[i] += __shfl_xor(v[i], 2);
    v[i] += __shfl_xor(v[i], 4);
  }
  const u16* selfr = acc1c + (size_t)n * 32;
  {  // U2 row -> LDS: [sums20, self sx16, 0..]
    u32 w4[4];
#pragma unroll
    for (int jj = 0; jj < 4; ++jj) {
      int t0 = q * 8 + 2 * jj, t1 = t0 + 1;
      u16 b0 = (t0 < 20) ? f2bf(v[t0]) : ((t0 < 36 && nval) ? selfr[t0 - 20] : (u16)0);
      u16 b1 = (t1 < 20) ? f2bf(v[t1]) : ((t1 < 36 && nval) ? selfr[t1 - 20] : (u16)0);
      w4[jj] = (u32)b0 | ((u32)b1 << 16);
    }
    *(uint4*)&Uls[nl][q * 8] = make_uint4(w4[0], w4[1], w4[2], w4[3]);
  }
  if (q < 4) {  // V tail cols [192..224): self sx16 then zeros
    u32 w4[4];
#pragma unroll
    for (int jj = 0; jj < 4; ++jj) {
      int t0 = q * 8 + 2 * jj, t1 = t0 + 1;
      u16 b0 = (t0 < 16 && nval) ? selfr[t0] : (u16)0;
      u16 b1 = (t1 < 16 && nval) ? selfr[t1] : (u16)0;
      w4[jj] = (u32)b0 | ((u32)b1 << 16);
    }
    *(uint4*)&Vls[nl][192 + q * 8] = make_uint4(w4[0], w4[1], w4[2], w4[3]);
  }
  if (q == 0) sdegls[nl] = v[20];
  if (q == 1) degls[nl] = nval ? bf2f(selfr[20]) : 0.f;
  if (q == 2) {
#pragma unroll
    for (int k = 0; k < 4; ++k) eals[nl][k] = nval ? bf2f(selfr[16 + k]) : 0.f;
  }
  __syncthreads();
  // Phase B: gemmq2 -> Vls[:,0..192), 12 jobs / 2 waves
  int w = tid >> 6, lane = tid & 63, rc = lane & 15, qd = lane >> 4;
  for (int nt = w; nt < 12; nt += 2) {
    f32x4 acc = {0.f, 0.f, 0.f, 0.f};
#pragma unroll
    for (int kb = 0; kb < 2; ++kb) {
      short8 av = *(const short8*)&Uls[rc][kb * 32 + qd * 8];
      short8 bv = *(const short8*)(Bp1 + (size_t)((kb * 4 + qd) * 192 + nt * 16 + rc) * 8);
      acc = __builtin_amdgcn_mfma_f32_16x16x32_bf16(av, bv, acc, 0, 0, 0);
    }
    int col = nt * 16 + rc;
    float s1 = aff1[col], t1 = aff1[192 + col];
    float bb = bm1[col] + be1[col], bsv = bs1[col];
#pragma unroll
    for (int r = 0; r < 4; ++r) {
      int ml = qd * 4 + r;
      float qv = acc[r] + sdegls[ml] * bb + degls[ml] * bsv;
      Vls[ml][col] = f2bf(qv * s1 + degls[ml] * t1);
    }
  }
  __syncthreads();
  // Phase C: gemm2, A = Vls, 13 jobs / 2 waves
  int slice = (blockIdx.x & 63) * 832;
  for (int nt = w; nt < 13; nt += 2) {
    f32x4 acc = {0.f, 0.f, 0.f, 0.f};
#pragma unroll
    for (int kb = 0; kb < 7; ++kb) {
      short8 av = *(const short8*)&Vls[rc][kb * 32 + qd * 8];
      short8 bv = *(const short8*)(Bp2 + (size_t)((kb * 4 + qd) * 208 + nt * 16 + rc) * 8);
      acc = __builtin_amdgcn_mfma_f32_16x16x32_bf16(av, bv, acc, 0, 0, 0);
    }
    int col = nt * 16 + rc;
    float w0 = We2[col], w1 = We2[208 + col], w2 = We2[416 + col], w3 = We2[624 + col];
    float bb2 = bm2[col] + be2[col];
    bool c192 = col < 192;
    float s1 = c192 ? aff1[col] : 0.f;
    float t1 = c192 ? aff1[192 + col] : 0.f;
    float ps = 0.f, pq = 0.f;
#pragma unroll
    for (int r = 0; r < 4; ++r) {
      int ml = qd * 4 + r;
      int m = blockIdx.x * 16 + ml;
      bool mv = m < N;
      float x1 = 0.f;
      if (mv) {
        x1 = c192 ? (bf2f(h1bf[(size_t)m * 192 + col]) * s1 + t1)
                  : x[(size_t)m * 16 + (col - 192)];
      }
      float val = acc[r] + eals[ml][0] * w0 + eals[ml][1] * w1 + eals[ml][2] * w2 +
                  eals[ml][3] * w3 + degls[ml] * bb2 + x1;
      if (mv) {
        h2bf[(size_t)m * 208 + col] = f2bf(val);
        ps += val;
        pq += val * val;
      }
    }
    ps += __shfl_xor(ps, 16); ps += __shfl_xor(ps, 32);
    pq += __shfl_xor(pq, 16); pq += __shfl_xor(pq, 32);
    if (qd == 0) {
      atomAddF(&bns2p[slice + col], ps);
      atomAddF(&bns2p[slice + 416 + col], pq);
    }
  }
}

// ---- bn finalize: unified affine table ---- grid 2x256
__global__ void bnfin2_k(const float* __restrict__ bns2p, const float* __restrict__ aff1,
                         const float* __restrict__ g2, const float* __restrict__ bta2,
                         float Ninv, float* __restrict__ aff) {
  int f = blockIdx.x * 256 + threadIdx.x;
  if (f >= 416) return;
  float sc, sh;
  if (f < 208) {
    float sm = 0.f, sq = 0.f;
    for (int k = 0; k < 64; ++k) {
      sm += bns2p[k * 832 + f];
      sq += bns2p[k * 832 + 416 + f];
    }
    float m2 = sm * Ninv;
    float var = sq * Ninv - m2 * m2;
    sc = g2[f] * rsqrtf(var + 1e-5f);
    sh = bta2[f] - m2 * sc;
  } else if (f < 400) {
    sc = aff1[f - 208];
    sh = aff1[192 + (f - 208)];
  } else {
    sc = 1.f;
    sh = 0.f;
  }
  aff[f] = sc;
  aff[416 + f] = sh;
}

// ---- pooling: feature-pair threads, partial stores ---- grid=(64,16), block=256
__global__ void pool_k(const u16* __restrict__ h2bf, const u16* __restrict__ h1bf,
                       const float* __restrict__ x, const float* __restrict__ aff,
                       const int* __restrict__ gstart, const int* __restrict__ gend,
                       float* __restrict__ psp, float* __restrict__ pmp) {
  int b = blockIdx.x, sub = blockIdx.y;
  int t = threadIdx.x;
  if (t >= 208) return;
  int s0 = gstart[b], e0 = gend[b];
  int cnt = (s0 <= e0) ? e0 - s0 + 1 : 0;
  int per = (cnt + 15) >> 4;
  int n0 = s0 + sub * per;
  int n1 = min(n0 + per, s0 + cnt);
  int f = 2 * t;
  float sc0 = aff[f], sc1 = aff[f + 1];
  float sh0 = aff[416 + f], sh1 = aff[417 + f];
  float s0f = 0.f, s1f = 0.f, m0f = -3.4e38f, m1f = -3.4e38f;
  if (f < 208) {
    for (int n = n0; n < n1; ++n) {
      u32 p = *(const u32*)(h2bf + (size_t)n * 208 + f);
      float v0 = bf2f((u16)p) * sc0 + sh0;
      float v1 = bf2f((u16)(p >> 16)) * sc1 + sh1;
      s0f += v0; s1f += v1;
      m0f = fmaxf(m0f, v0); m1f = fmaxf(m1f, v1);
    }
  } else if (f < 400) {
    int jc = f - 208;
    for (int n = n0; n < n1; ++n) {
      u32 p = *(const u32*)(h1bf + (size_t)n * 192 + jc);
      float v0 = bf2f((u16)p) * sc0 + sh0;
      float v1 = bf2f((u16)(p >> 16)) * sc1 + sh1;
      s0f += v0; s1f += v1;
      m0f = fmaxf(m0f, v0); m1f = fmaxf(m1f, v1);
    }
  } else {
    int jc = f - 400;
    for (int n = n0; n < n1; ++n) {
      float2 p = *(const float2*)(x + (size_t)n * 16 + jc);
      s0f += p.x; s1f += p.y;
      m0f = fmaxf(m0f, p.x); m1f = fmaxf(m1f, p.y);
    }
  }
  size_t idx = ((size_t)(b * 16 + sub)) * 416 + f;
  *(float2*)(psp + idx) = make_float2(s0f, s1f);
  *(float2*)(pmp + idx) = make_float2(m0f, m1f);
}

// ---- pooled partial reduce -> bf16 A matrix [64 x 1248] ---- grid=64, block=256
__global__ void pooledprep_k(const float* __restrict__ psp, const float* __restrict__ pmp,
                             const int* __restrict__ gstart, const int* __restrict__ gend,
                             u16* __restrict__ Apool) {
  int b = blockIdx.x, t = threadIdx.x;
  int cnt = gend[b] - gstart[b] + 1;
  float inv = 1.f / (float)max(cnt, 1);
  for (int f = t; f < 416; f += 256) {
    float s = 0.f, m = -3.4e38f;
    for (int k = 0; k < 16; ++k) {
      size_t idx = ((size_t)(b * 16 + k)) * 416 + f;
      s += psp[idx];
      m = fmaxf(m, pmp[idx]);
    }
    u16* row = Apool + (size_t)b * 1248;
    row[f] = f2bf(s);
    row[416 + f] = f2bf((cnt > 0) ? m : 0.f);
    row[832 + f] = f2bf(s * inv);
  }
}

// ---- MLP layer 1 via MFMA ---- grid=(4,39), block=64
__global__ void mlpgemm_k(const u16* __restrict__ A, const u16* __restrict__ Bp,
                          const float* __restrict__ b1, const float* __restrict__ al,
                          float* __restrict__ hid) {
  int lane = threadIdx.x;
  int mt = blockIdx.x, nt = blockIdx.y;
  int rc = lane & 15, qd = lane >> 4;
  f32x4 acc = {0.f, 0.f, 0.f, 0.f};
  const u16* Ap = A + (size_t)(mt * 16 + rc) * 1248 + qd * 8;
  const u16* Bq = Bp + (size_t)(qd * 624 + nt * 16 + rc) * 8;
  for (int kb = 0; kb < 39; ++kb) {
    short8 av = *(const short8*)(Ap + kb * 32);
    short8 bv = *(const short8*)(Bq + (size_t)kb * 4 * 624 * 8);
    acc = __builtin_amdgcn_mfma_f32_16x16x32_bf16(av, bv, acc, 0, 0, 0);
  }
  int col = nt * 16 + rc;
  float bb = b1[col], alpha = al[0];
  int m0 = mt * 16 + qd * 4;
#pragma unroll
  for (int r = 0; r < 4; ++r) {
    float v = acc[r] + bb;
    hid[(size_t)(m0 + r) * 624 + col] = (v >= 0.f) ? v : alpha * v;
  }
}

// ---- logits + log_softmax ---- grid=64, block=64
__global__ void head_k(const float* __restrict__ hid, const float* __restrict__ W2,
                       const float* __restrict__ b2, float* __restrict__ out) {
  int b = blockIdx.x, t = threadIdx.x;
  float p0 = 0.f, p1 = 0.f;
  for (int k = t; k < 624; k += 64) {
    float h = hid[(size_t)b * 624 + k];
    p0 += h * W2[k * 2];
    p1 += h * W2[k * 2 + 1];
  }
#pragma unroll
  for (int off = 32; off > 0; off >>= 1) {
    p0 += __shfl_down(p0, off);
    p1 += __shfl_down(p1, off);
  }
  if (t == 0) {
    float l0 = p0 + b2[0], l1 = p1 + b2[1];
    float m = fmaxf(l0, l1);
    float lse = m + logf(expf(l0 - m) + expf(l1 - m));
    out[b * 2] = l0 - lse;
    out[b * 2 + 1] = l1 - lse;
  }
}

extern "C" void kernel_launch(void* const* d_in, const int* in_sizes, int n_in,
                              void* d_out, int out_size, void* d_ws, size_t ws_size,
                              hipStream_t stream) {
  const float* x = (const float*)d_in[0];
  const int* ei = (const int*)d_in[1];
  const float* ea = (const float*)d_in[2];
  const int* batch = (const int*)d_in[3];
  const float* Wm1 = (const float*)d_in[4];
  const float* bm1 = (const float*)d_in[5];
  const float* We1 = (const float*)d_in[6];
  const float* be1 = (const float*)d_in[7];
  const float* Ws1 = (const float*)d_in[8];
  const float* bs1 = (const float*)d_in[9];
  const float* g1 = (const float*)d_in[10];
  const float* bta1 = (const float*)d_in[11];
  const float* Wm2 = (const float*)d_in[12];
  const float* bm2 = (const float*)d_in[13];
  const float* We2 = (const float*)d_in[14];
  const float* be2 = (const float*)d_in[15];
  const float* g2 = (const float*)d_in[16];
  const float* bta2 = (const float*)d_in[17];
  const float* Wl1 = (const float*)d_in[18];
  const float* bl1 = (const float*)d_in[19];
  const float* alpha = (const float*)d_in[20];
  const float* Wl2 = (const float*)d_in[21];
  const float* bl2 = (const float*)d_in[22];
  float* out = (float*)d_out;

  const int N = in_sizes[3];      // 50000
  const int E = in_sizes[2] / 4;  // 800000
  const int nb = (N + 255) / 256; // 196 (<=256)
  const float Ninv = 1.f / (float)N;

  float* ws = (float*)d_ws;
  size_t o = 0;
  u16* acc1c = (u16*)(ws + o); o += (size_t)N * 16;  // N*32 u16
  u16* h2bf = (u16*)(ws + o);  o += (size_t)N * 104; // N*208 u16
  u16* h1bf = (u16*)(ws + o);  o += (size_t)N * 96;  // N*192 u16
  u16* eabf = (u16*)(ws + o);  o += (size_t)E * 2;   // E*4 u16
  u16* Wp1 = (u16*)(ws + o);   o += 6144;
  u16* Wp2 = (u16*)(ws + o);   o += 23296;
  u16* Wp3 = (u16*)(ws + o);   o += 389376;
  u16* Apool = (u16*)(ws + o); o += 39936;
  float* hid = ws + o;    o += 64 * 624;
  float* bns1p = ws + o;  o += 64 * 384;
  float* bns2p = ws + o;  o += 64 * 832;
  float* aff1 = ws + o;   o += 384;
  float* aff = ws + o;    o += 832;
  float* psp = ws + o;    o += (size_t)64 * 16 * 416;
  float* pmp = ws + o;    o += (size_t)64 * 16 * 416;
  int* gstart = (int*)(ws + o); o += 64;
  int* gend = (int*)(ws + o);   o += 64;
  int* deg = (int*)(ws + o);    o += N;
  int* rowptr = (int*)(ws + o); o += N + 1;
  int* cur = (int*)(ws + o);    o += N + 1;
  int* bsum = (int*)(ws + o);   o += 256;
  int2* se = (int2*)(ws + o);   o += (size_t)2 * E;

  const int gconv = (N + 15) / 16;  // 3125
  prep_k<<<(E + 255) / 256, 256, 0, stream>>>(Wm1, We1, Ws1, Wm2, Wl1, ea, batch, Wp1, Wp2,
                                              Wp3, eabf, gstart, gend, deg, bns1p, bns2p,
                                              N, E);
  count_k<<<(E + 255) / 256, 256, 0, stream>>>(ei, deg, E);
  scanA_k<<<nb, 256, 0, stream>>>(deg, bsum, N);
  scanC_k<<<nb, 256, 0, stream>>>(deg, bsum, rowptr, cur, N, nb);
  scatter_k<<<(E + 255) / 256, 256, 0, stream>>>(ei, cur, se, E);
  conv1_k<<<gconv, 128, 0, stream>>>(se, rowptr, x, eabf, Wp1, bm1, be1, bs1, acc1c, h1bf,
                                     bns1p, N);
  bnfin1_k<<<1, 256, 0, stream>>>(bns1p, g1, bta1, Ninv, aff1);
  conv2_k<<<gconv, 128, 0, stream>>>(se, rowptr, acc1c, h1bf, x, Wp1, Wp2, bm1, be1, bs1,
                                     aff1, We2, bm2, be2, bns2p, h2bf, N);
  bnfin2_k<<<2, 256, 0, stream>>>(bns2p, aff1, g2, bta2, Ninv, aff);
  pool_k<<<dim3(64, 16), 256, 0, stream>>>(h2bf, h1bf, x, aff, gstart, gend, psp, pmp);
  pooledprep_k<<<64, 256, 0, stream>>>(psp, pmp, gstart, gend, Apool);
  mlpgemm_k<<<dim3(4, 39), 64, 0, stream>>>(Apool, Wp3, bl1, alpha, hid);
  head_k<<<64, 64, 0, stream>>>(hid, Wl2, bl2, out);
}

// Round 13
// 353.650 us; speedup vs baseline: 1.6185x; 1.0407x over previous
//
#include <hip/hip_runtime.h>

typedef __attribute__((ext_vector_type(8))) short short8;
typedef __attribute__((ext_vector_type(4))) float f32x4;
typedef unsigned short u16;
typedef unsigned int u32;

__device__ __forceinline__ u16 f2bf(float f) {
  u32 u = __float_as_uint(f);
  u = (u + 0x7fffu + ((u >> 16) & 1u)) >> 16;
  return (u16)u;
}
__device__ __forceinline__ float bf2f(u16 v) { return __uint_as_float((u32)v << 16); }
__device__ __forceinline__ void atomAddF(float* p, float v) { unsafeAtomicAdd(p, v); }
__device__ __forceinline__ void addp(float* v, u32 p) {
  v[0] += bf2f((u16)p);
  v[1] += bf2f((u16)(p >> 16));
}

// ---- prep: pack bf16 weights + ea/x->bf16 + graph bounds + zero scratch ---- grid E/256
__global__ void prep_k(const float* __restrict__ Wm1, const float* __restrict__ We1,
                       const float* __restrict__ Ws1, const float* __restrict__ Wm2,
                       const float* __restrict__ Wl1, const float* __restrict__ ea,
                       const float* __restrict__ x, const int* __restrict__ batch,
                       u16* __restrict__ Wp1, u16* __restrict__ Wp2, u16* __restrict__ Wp3,
                       u16* __restrict__ eabf, u16* __restrict__ xbf,
                       int* __restrict__ gstart, int* __restrict__ gend,
                       int* __restrict__ deg, float* __restrict__ bns1p,
                       float* __restrict__ bns2p, int N, int E) {
  int tid = blockIdx.x * 256 + threadIdx.x;
  if (tid < 64 * 192) {  // Wcat1 = [Wm1(16); We1(4); Ws1(16)], pad K to 64
    int k = tid / 192, n = tid % 192;
    float v = 0.f;
    if (k < 16) v = Wm1[k * 192 + n];
    else if (k < 20) v = We1[(k - 16) * 192 + n];
    else if (k < 36) v = Ws1[(k - 20) * 192 + n];
    Wp1[((k >> 3) * 192 + n) * 8 + (k & 7)] = f2bf(v);
  }
  if (tid < 224 * 208) {  // W_msg2, pad K 208->224
    int k = tid / 208, n = tid % 208;
    float v = (k < 208) ? Wm2[k * 208 + n] : 0.f;
    Wp2[((k >> 3) * 208 + n) * 8 + (k & 7)] = f2bf(v);
  }
  if (tid < E) {
    float4 w = *(const float4*)(ea + (size_t)tid * 4);
    uint2 p;
    p.x = (u32)f2bf(w.x) | ((u32)f2bf(w.y) << 16);
    p.y = (u32)f2bf(w.z) | ((u32)f2bf(w.w) << 16);
    *(uint2*)(eabf + (size_t)tid * 4) = p;
  }
  if (tid < N * 8) {  // x -> bf16, 2 elems/thread
    float2 p = *(const float2*)(x + (size_t)tid * 2);
    *(u32*)(xbf + (size_t)tid * 2) = (u32)f2bf(p.x) | ((u32)f2bf(p.y) << 16);
  }
  if (tid < N) {
    int b = batch[tid];
    if (tid == 0 || batch[tid - 1] != b) gstart[b] = tid;
    if (tid == N - 1 || batch[tid + 1] != b) gend[b] = tid;
    deg[tid] = 0;
  }
  if (tid < 64 * 384) bns1p[tid] = 0.f;
  if (tid < 64 * 832) bns2p[tid] = 0.f;
  if (tid < 1248 * 624) {
    int k = tid / 624, n = tid % 624;
    Wp3[((size_t)(k >> 3) * 624 + n) * 8 + (k & 7)] = f2bf(Wl1[(size_t)k * 624 + n]);
  }
}

// ---- CSR build ----
__global__ void count_k(const int* __restrict__ ei, int* __restrict__ deg, int E) {
  int e = blockIdx.x * 256 + threadIdx.x;
  if (e >= E) return;
  atomicAdd(&deg[ei[E + e]], 1);
}

__global__ void scanA_k(const int* __restrict__ deg, int* __restrict__ bsum, int N) {
  __shared__ int sh[256];
  int t = threadIdx.x;
  int i = blockIdx.x * 256 + t;
  sh[t] = (i < N) ? deg[i] : 0;
  __syncthreads();
  for (int off = 128; off > 0; off >>= 1) {
    if (t < off) sh[t] += sh[t + off];
    __syncthreads();
  }
  if (t == 0) bsum[blockIdx.x] = sh[0];
}

__global__ void scanC_k(const int* __restrict__ deg, const int* __restrict__ bsum,
                        int* __restrict__ rowptr, int* __restrict__ cur, int N, int nb) {
  __shared__ int sb2[256];
  __shared__ int sh[256];
  int t = threadIdx.x;
  int bv = (t < nb) ? bsum[t] : 0;
  sb2[t] = bv;
  __syncthreads();
  for (int off = 1; off < 256; off <<= 1) {
    int u = (t >= off) ? sb2[t - off] : 0;
    __syncthreads();
    sb2[t] += u;
    __syncthreads();
  }
  int bpref = (blockIdx.x == 0) ? 0 : sb2[blockIdx.x - 1];
  int i = blockIdx.x * 256 + t;
  int d = (i < N) ? deg[i] : 0;
  sh[t] = d;
  __syncthreads();
  for (int off = 1; off < 256; off <<= 1) {
    int u = (t >= off) ? sh[t - off] : 0;
    __syncthreads();
    sh[t] += u;
    __syncthreads();
  }
  int excl = sh[t] - d + bpref;
  if (i < N) {
    rowptr[i] = excl;
    cur[i] = excl;
    if (i == N - 1) rowptr[N] = excl + d;
  }
}

__global__ void scatter_k(const int* __restrict__ ei, int* __restrict__ cur,
                          int2* __restrict__ se, int E) {
  int e = blockIdx.x * 256 + threadIdx.x;
  if (e >= E) return;
  int s = ei[e], d = ei[E + e];
  int slot = atomicAdd(&cur[d], 1);
  se[slot] = make_int2(s, e);
}

// ---- CONV1: gather1 (16 lanes/node) + U1(LDS) + gemm1 MFMA + h1bf + bn1 stats ----
// grid ceil(N/16), block 256 (4 waves)
__global__ void __launch_bounds__(256) conv1_k(
    const int2* __restrict__ se, const int* __restrict__ rowptr,
    const u16* __restrict__ xbf, const u16* __restrict__ eabf,
    const u16* __restrict__ Bp, const float* __restrict__ bm1,
    const float* __restrict__ be1, const float* __restrict__ bs1,
    u16* __restrict__ acc1c, u16* __restrict__ h1bf, float* __restrict__ bns1p, int N) {
  __shared__ __align__(16) u16 Uls[16][72];
  __shared__ float degls[16];
  int tid = threadIdx.x;
  int nl = tid >> 4, q = tid & 15;
  int n = blockIdx.x * 16 + nl;
  bool nval = n < N;
  int j0 = nval ? rowptr[n] : 0;
  int j1 = nval ? rowptr[n + 1] : 0;
  float v[20];
#pragma unroll
  for (int i = 0; i < 20; ++i) v[i] = 0.f;
  for (int j = j0 + q; j < j1; j += 16) {
    int2 p = se[j];
    const uint4* xs = (const uint4*)(xbf + (size_t)p.x * 16);
    uint4 x0 = xs[0], x1 = xs[1];
    uint2 w = *(const uint2*)(eabf + (size_t)p.y * 4);
    addp(v + 0, x0.x); addp(v + 2, x0.y); addp(v + 4, x0.z); addp(v + 6, x0.w);
    addp(v + 8, x1.x); addp(v + 10, x1.y); addp(v + 12, x1.z); addp(v + 14, x1.w);
    addp(v + 16, w.x); addp(v + 18, w.y);
  }
#pragma unroll
  for (int i = 0; i < 20; ++i) {
    v[i] += __shfl_xor(v[i], 1);
    v[i] += __shfl_xor(v[i], 2);
    v[i] += __shfl_xor(v[i], 4);
    v[i] += __shfl_xor(v[i], 8);
  }
  float degf = (float)(j1 - j0);
  const u16* xr = xbf + (size_t)n * 16;
  {  // U1 row -> LDS: [sums20, x(n)16, 0..]; lane q writes elems q*4..q*4+3
    u32 w2[2];
#pragma unroll
    for (int jj = 0; jj < 2; ++jj) {
      int t0 = q * 4 + 2 * jj, t1 = t0 + 1;
      u16 b0 = (t0 < 20) ? f2bf(v[t0]) : ((t0 < 36 && nval) ? xr[t0 - 20] : (u16)0);
      u16 b1 = (t1 < 20) ? f2bf(v[t1]) : ((t1 < 36 && nval) ? xr[t1 - 20] : (u16)0);
      w2[jj] = (u32)b0 | ((u32)b1 << 16);
    }
    *(uint2*)&Uls[nl][q * 4] = make_uint2(w2[0], w2[1]);
  }
  if (nval) {  // acc1c row: [sx16, sea4, deg, 0..]; lane q -> elems 2q,2q+1
    int t0 = q * 2, t1 = t0 + 1;
    float f0 = (t0 < 20) ? v[t0] : ((t0 == 20) ? degf : 0.f);
    float f1 = (t1 < 20) ? v[t1] : ((t1 == 20) ? degf : 0.f);
    *(u32*)(acc1c + (size_t)n * 32 + q * 2) = (u32)f2bf(f0) | ((u32)f2bf(f1) << 16);
  }
  if (q == 0) degls[nl] = degf;
  __syncthreads();
  // Phase B: 12 n-tile jobs over 4 waves
  int w = tid >> 6, lane = tid & 63, rc = lane & 15, qd = lane >> 4;
  int slice = (blockIdx.x & 63) * 384;
  for (int nt = w; nt < 12; nt += 4) {
    f32x4 acc = {0.f, 0.f, 0.f, 0.f};
#pragma unroll
    for (int kb = 0; kb < 2; ++kb) {
      short8 av = *(const short8*)&Uls[rc][kb * 32 + qd * 8];
      short8 bv = *(const short8*)(Bp + (size_t)((kb * 4 + qd) * 192 + nt * 16 + rc) * 8);
      acc = __builtin_amdgcn_mfma_f32_16x16x32_bf16(av, bv, acc, 0, 0, 0);
    }
    int col = nt * 16 + rc;
    float bb = bm1[col] + be1[col], bsv = bs1[col];
    float ps = 0.f, pq = 0.f;
#pragma unroll
    for (int r = 0; r < 4; ++r) {
      int ml = qd * 4 + r;
      int m = blockIdx.x * 16 + ml;
      float val = acc[r] + degls[ml] * bb + bsv;
      if (m < N) {
        h1bf[(size_t)m * 192 + col] = f2bf(val);
        ps += val;
        pq += val * val;
      }
    }
    ps += __shfl_xor(ps, 16); ps += __shfl_xor(ps, 32);
    pq += __shfl_xor(pq, 16); pq += __shfl_xor(pq, 32);
    if (qd == 0) {
      atomAddF(&bns1p[slice + col], ps);
      atomAddF(&bns1p[slice + 192 + col], pq);
    }
  }
}

// ---- bn1 finalize ---- 1 block, 256 threads
__global__ void bnfin1_k(const float* __restrict__ bns1p, const float* __restrict__ g1,
                         const float* __restrict__ bta1, float Ninv,
                         float* __restrict__ aff1) {
  int c = threadIdx.x;
  if (c >= 192) return;
  float sm = 0.f, sq = 0.f;
  for (int k = 0; k < 64; ++k) {
    sm += bns1p[k * 384 + c];
    sq += bns1p[k * 384 + 192 + c];
  }
  float m1 = sm * Ninv;
  float var = sq * Ninv - m1 * m1;
  float s1 = g1[c] * rsqrtf(var + 1e-5f);
  aff1[c] = s1;
  aff1[192 + c] = bta1[c] - m1 * s1;
}

// ---- CONV2: gather2 (16 lanes/node) + U2(LDS) + gemmq2 (V in LDS) + gemm2 + bn2 ----
// grid ceil(N/16), block 256 (4 waves)
__global__ void __launch_bounds__(256) conv2_k(
    const int2* __restrict__ se, const int* __restrict__ rowptr,
    const u16* __restrict__ acc1c, const u16* __restrict__ h1bf,
    const u16* __restrict__ xbf, const u16* __restrict__ Bp1, const u16* __restrict__ Bp2,
    const float* __restrict__ bm1, const float* __restrict__ be1,
    const float* __restrict__ bs1, const float* __restrict__ aff1,
    const float* __restrict__ We2, const float* __restrict__ bm2,
    const float* __restrict__ be2, float* __restrict__ bns2p,
    u16* __restrict__ h2bf, int N) {
  __shared__ __align__(16) u16 Uls[16][72];
  __shared__ __align__(16) u16 Vls[16][232];
  __shared__ float degls[16], sdegls[16], eals[16][4];
  int tid = threadIdx.x;
  int nl = tid >> 4, q = tid & 15;
  int n = blockIdx.x * 16 + nl;
  bool nval = n < N;
  int j0 = nval ? rowptr[n] : 0;
  int j1 = nval ? rowptr[n + 1] : 0;
  float v[21];
#pragma unroll
  for (int i = 0; i < 21; ++i) v[i] = 0.f;
  for (int j = j0 + q; j < j1; j += 16) {
    int s = se[j].x;
    const uint4* cr = (const uint4*)(acc1c + (size_t)s * 32);
    uint4 c0 = cr[0], c1 = cr[1], c2 = cr[2];
    addp(v + 0, c0.x); addp(v + 2, c0.y); addp(v + 4, c0.z); addp(v + 6, c0.w);
    addp(v + 8, c1.x); addp(v + 10, c1.y); addp(v + 12, c1.z); addp(v + 14, c1.w);
    addp(v + 16, c2.x); addp(v + 18, c2.y);
    v[20] += bf2f((u16)c2.z);
  }
#pragma unroll
  for (int i = 0; i < 21; ++i) {
    v[i] += __shfl_xor(v[i], 1);
    v[i] += __shfl_xor(v[i], 2);
    v[i] += __shfl_xor(v[i], 4);
    v[i] += __shfl_xor(v[i], 8);
  }
  const u16* selfr = acc1c + (size_t)n * 32;
  {  // U2 row -> LDS: [sums20, self sx16, 0..]; lane q writes elems q*4..q*4+3
    u32 w2[2];
#pragma unroll
    for (int jj = 0; jj < 2; ++jj) {
      int t0 = q * 4 + 2 * jj, t1 = t0 + 1;
      u16 b0 = (t0 < 20) ? f2bf(v[t0]) : ((t0 < 36 && nval) ? selfr[t0 - 20] : (u16)0);
      u16 b1 = (t1 < 20) ? f2bf(v[t1]) : ((t1 < 36 && nval) ? selfr[t1 - 20] : (u16)0);
      w2[jj] = (u32)b0 | ((u32)b1 << 16);
    }
    *(uint2*)&Uls[nl][q * 4] = make_uint2(w2[0], w2[1]);
  }
  {  // V tail cols [192..224): self sx16 then zeros; lane q -> elems 192+2q, +1
    int t0 = q * 2, t1 = t0 + 1;
    u16 b0 = (t0 < 16 && nval) ? selfr[t0] : (u16)0;
    u16 b1 = (t1 < 16 && nval) ? selfr[t1] : (u16)0;
    *(u32*)&Vls[nl][192 + q * 2] = (u32)b0 | ((u32)b1 << 16);
  }
  if (q == 0) sdegls[nl] = v[20];
  if (q == 1) degls[nl] = nval ? bf2f(selfr[20]) : 0.f;
  if (q == 2) {
#pragma unroll
    for (int k = 0; k < 4; ++k) eals[nl][k] = nval ? bf2f(selfr[16 + k]) : 0.f;
  }
  __syncthreads();
  // Phase B: gemmq2 -> Vls[:,0..192), 12 jobs / 4 waves
  int w = tid >> 6, lane = tid & 63, rc = lane & 15, qd = lane >> 4;
  for (int nt = w; nt < 12; nt += 4) {
    f32x4 acc = {0.f, 0.f, 0.f, 0.f};
#pragma unroll
    for (int kb = 0; kb < 2; ++kb) {
      short8 av = *(const short8*)&Uls[rc][kb * 32 + qd * 8];
      short8 bv = *(const short8*)(Bp1 + (size_t)((kb * 4 + qd) * 192 + nt * 16 + rc) * 8);
      acc = __builtin_amdgcn_mfma_f32_16x16x32_bf16(av, bv, acc, 0, 0, 0);
    }
    int col = nt * 16 + rc;
    float s1 = aff1[col], t1 = aff1[192 + col];
    float bb = bm1[col] + be1[col], bsv = bs1[col];
#pragma unroll
    for (int r = 0; r < 4; ++r) {
      int ml = qd * 4 + r;
      float qv = acc[r] + sdegls[ml] * bb + degls[ml] * bsv;
      Vls[ml][col] = f2bf(qv * s1 + degls[ml] * t1);
    }
  }
  __syncthreads();
  // Phase C: gemm2, A = Vls, 13 jobs / 4 waves
  int slice = (blockIdx.x & 63) * 832;
  for (int nt = w; nt < 13; nt += 4) {
    f32x4 acc = {0.f, 0.f, 0.f, 0.f};
#pragma unroll
    for (int kb = 0; kb < 7; ++kb) {
      short8 av = *(const short8*)&Vls[rc][kb * 32 + qd * 8];
      short8 bv = *(const short8*)(Bp2 + (size_t)((kb * 4 + qd) * 208 + nt * 16 + rc) * 8);
      acc = __builtin_amdgcn_mfma_f32_16x16x32_bf16(av, bv, acc, 0, 0, 0);
    }
    int col = nt * 16 + rc;
    float w0 = We2[col], w1 = We2[208 + col], w2 = We2[416 + col], w3 = We2[624 + col];
    float bb2 = bm2[col] + be2[col];
    bool c192 = col < 192;
    float s1 = c192 ? aff1[col] : 0.f;
    float t1 = c192 ? aff1[192 + col] : 0.f;
    float ps = 0.f, pq = 0.f;
#pragma unroll
    for (int r = 0; r < 4; ++r) {
      int ml = qd * 4 + r;
      int m = blockIdx.x * 16 + ml;
      bool mv = m < N;
      float x1 = 0.f;
      if (mv) {
        x1 = c192 ? (bf2f(h1bf[(size_t)m * 192 + col]) * s1 + t1)
                  : bf2f(xbf[(size_t)m * 16 + (col - 192)]);
      }
      float val = acc[r] + eals[ml][0] * w0 + eals[ml][1] * w1 + eals[ml][2] * w2 +
                  eals[ml][3] * w3 + degls[ml] * bb2 + x1;
      if (mv) {
        h2bf[(size_t)m * 208 + col] = f2bf(val);
        ps += val;
        pq += val * val;
      }
    }
    ps += __shfl_xor(ps, 16); ps += __shfl_xor(ps, 32);
    pq += __shfl_xor(pq, 16); pq += __shfl_xor(pq, 32);
    if (qd == 0) {
      atomAddF(&bns2p[slice + col], ps);
      atomAddF(&bns2p[slice + 416 + col], pq);
    }
  }
}

// ---- bn finalize: unified affine table ---- grid 2x256
__global__ void bnfin2_k(const float* __restrict__ bns2p, const float* __restrict__ aff1,
                         const float* __restrict__ g2, const float* __restrict__ bta2,
                         float Ninv, float* __restrict__ aff) {
  int f = blockIdx.x * 256 + threadIdx.x;
  if (f >= 416) return;
  float sc, sh;
  if (f < 208) {
    float sm = 0.f, sq = 0.f;
    for (int k = 0; k < 64; ++k) {
      sm += bns2p[k * 832 + f];
      sq += bns2p[k * 832 + 416 + f];
    }
    float m2 = sm * Ninv;
    float var = sq * Ninv - m2 * m2;
    sc = g2[f] * rsqrtf(var + 1e-5f);
    sh = bta2[f] - m2 * sc;
  } else if (f < 400) {
    sc = aff1[f - 208];
    sh = aff1[192 + (f - 208)];
  } else {
    sc = 1.f;
    sh = 0.f;
  }
  aff[f] = sc;
  aff[416 + f] = sh;
}

// ---- pooling: feature-pair threads, partial stores ---- grid=(64,16), block=256
__global__ void pool_k(const u16* __restrict__ h2bf, const u16* __restrict__ h1bf,
                       const u16* __restrict__ xbf, const float* __restrict__ aff,
                       const int* __restrict__ gstart, const int* __restrict__ gend,
                       float* __restrict__ psp, float* __restrict__ pmp) {
  int b = blockIdx.x, sub = blockIdx.y;
  int t = threadIdx.x;
  if (t >= 208) return;
  int s0 = gstart[b], e0 = gend[b];
  int cnt = (s0 <= e0) ? e0 - s0 + 1 : 0;
  int per = (cnt + 15) >> 4;
  int n0 = s0 + sub * per;
  int n1 = min(n0 + per, s0 + cnt);
  int f = 2 * t;
  const u16* src;
  int stride;
  if (f < 208) { src = h2bf + f; stride = 208; }
  else if (f < 400) { src = h1bf + (f - 208); stride = 192; }
  else { src = xbf + (f - 400); stride = 16; }
  float sc0 = aff[f], sc1 = aff[f + 1];
  float sh0 = aff[416 + f], sh1 = aff[417 + f];
  float s0f = 0.f, s1f = 0.f, m0f = -3.4e38f, m1f = -3.4e38f;
  for (int n = n0; n < n1; ++n) {
    u32 p = *(const u32*)(src + (size_t)n * stride);
    float v0 = bf2f((u16)p) * sc0 + sh0;
    float v1 = bf2f((u16)(p >> 16)) * sc1 + sh1;
    s0f += v0; s1f += v1;
    m0f = fmaxf(m0f, v0); m1f = fmaxf(m1f, v1);
  }
  size_t idx = ((size_t)(b * 16 + sub)) * 416 + f;
  *(float2*)(psp + idx) = make_float2(s0f, s1f);
  *(float2*)(pmp + idx) = make_float2(m0f, m1f);
}

// ---- pooled partial reduce -> bf16 A matrix [64 x 1248] ---- grid=64, block=256
__global__ void pooledprep_k(const float* __restrict__ psp, const float* __restrict__ pmp,
                             const int* __restrict__ gstart, const int* __restrict__ gend,
                             u16* __restrict__ Apool) {
  int b = blockIdx.x, t = threadIdx.x;
  int cnt = gend[b] - gstart[b] + 1;
  float inv = 1.f / (float)max(cnt, 1);
  for (int f = t; f < 416; f += 256) {
    float s = 0.f, m = -3.4e38f;
    for (int k = 0; k < 16; ++k) {
      size_t idx = ((size_t)(b * 16 + k)) * 416 + f;
      s += psp[idx];
      m = fmaxf(m, pmp[idx]);
    }
    u16* row = Apool + (size_t)b * 1248;
    row[f] = f2bf(s);
    row[416 + f] = f2bf((cnt > 0) ? m : 0.f);
    row[832 + f] = f2bf(s * inv);
  }
}

// ---- MLP layer 1 via MFMA ---- grid=(4,39), block=64
__global__ void mlpgemm_k(const u16* __restrict__ A, const u16* __restrict__ Bp,
                          const float* __restrict__ b1, const float* __restrict__ al,
                          float* __restrict__ hid) {
  int lane = threadIdx.x;
  int mt = blockIdx.x, nt = blockIdx.y;
  int rc = lane & 15, qd = lane >> 4;
  f32x4 acc = {0.f, 0.f, 0.f, 0.f};
  const u16* Ap = A + (size_t)(mt * 16 + rc) * 1248 + qd * 8;
  const u16* Bq = Bp + (size_t)(qd * 624 + nt * 16 + rc) * 8;
  for (int kb = 0; kb < 39; ++kb) {
    short8 av = *(const short8*)(Ap + kb * 32);
    short8 bv = *(const short8*)(Bq + (size_t)kb * 4 * 624 * 8);
    acc = __builtin_amdgcn_mfma_f32_16x16x32_bf16(av, bv, acc, 0, 0, 0);
  }
  int col = nt * 16 + rc;
  float bb = b1[col], alpha = al[0];
  int m0 = mt * 16 + qd * 4;
#pragma unroll
  for (int r = 0; r < 4; ++r) {
    float v = acc[r] + bb;
    hid[(size_t)(m0 + r) * 624 + col] = (v >= 0.f) ? v : alpha * v;
  }
}

// ---- logits + log_softmax ---- grid=64, block=64
__global__ void head_k(const float* __restrict__ hid, const float* __restrict__ W2,
                       const float* __restrict__ b2, float* __restrict__ out) {
  int b = blockIdx.x, t = threadIdx.x;
  float p0 = 0.f, p1 = 0.f;
  for (int k = t; k < 624; k += 64) {
    float h = hid[(size_t)b * 624 + k];
    p0 += h * W2[k * 2];
    p1 += h * W2[k * 2 + 1];
  }
#pragma unroll
  for (int off = 32; off > 0; off >>= 1) {
    p0 += __shfl_down(p0, off);
    p1 += __shfl_down(p1, off);
  }
  if (t == 0) {
    float l0 = p0 + b2[0], l1 = p1 + b2[1];
    float m = fmaxf(l0, l1);
    float lse = m + logf(expf(l0 - m) + expf(l1 - m));
    out[b * 2] = l0 - lse;
    out[b * 2 + 1] = l1 - lse;
  }
}

extern "C" void kernel_launch(void* const* d_in, const int* in_sizes, int n_in,
                              void* d_out, int out_size, void* d_ws, size_t ws_size,
                              hipStream_t stream) {
  const float* x = (const float*)d_in[0];
  const int* ei = (const int*)d_in[1];
  const float* ea = (const float*)d_in[2];
  const int* batch = (const int*)d_in[3];
  const float* Wm1 = (const float*)d_in[4];
  const float* bm1 = (const float*)d_in[5];
  const float* We1 = (const float*)d_in[6];
  const float* be1 = (const float*)d_in[7];
  const float* Ws1 = (const float*)d_in[8];
  const float* bs1 = (const float*)d_in[9];
  const float* g1 = (const float*)d_in[10];
  const float* bta1 = (const float*)d_in[11];
  const float* Wm2 = (const float*)d_in[12];
  const float* bm2 = (const float*)d_in[13];
  const float* We2 = (const float*)d_in[14];
  const float* be2 = (const float*)d_in[15];
  const float* g2 = (const float*)d_in[16];
  const float* bta2 = (const float*)d_in[17];
  const float* Wl1 = (const float*)d_in[18];
  const float* bl1 = (const float*)d_in[19];
  const float* alpha = (const float*)d_in[20];
  const float* Wl2 = (const float*)d_in[21];
  const float* bl2 = (const float*)d_in[22];
  float* out = (float*)d_out;

  const int N = in_sizes[3];      // 50000
  const int E = in_sizes[2] / 4;  // 800000
  const int nb = (N + 255) / 256; // 196 (<=256)
  const float Ninv = 1.f / (float)N;

  float* ws = (float*)d_ws;
  size_t o = 0;
  u16* acc1c = (u16*)(ws + o); o += (size_t)N * 16;  // N*32 u16
  u16* h2bf = (u16*)(ws + o);  o += (size_t)N * 104; // N*208 u16
  u16* h1bf = (u16*)(ws + o);  o += (size_t)N * 96;  // N*192 u16
  u16* eabf = (u16*)(ws + o);  o += (size_t)E * 2;   // E*4 u16
  u16* xbf = (u16*)(ws + o);   o += (size_t)N * 8;   // N*16 u16
  u16* Wp1 = (u16*)(ws + o);   o += 6144;
  u16* Wp2 = (u16*)(ws + o);   o += 23296;
  u16* Wp3 = (u16*)(ws + o);   o += 389376;
  u16* Apool = (u16*)(ws + o); o += 39936;
  float* hid = ws + o;    o += 64 * 624;
  float* bns1p = ws + o;  o += 64 * 384;
  float* bns2p = ws + o;  o += 64 * 832;
  float* aff1 = ws + o;   o += 384;
  float* aff = ws + o;    o += 832;
  float* psp = ws + o;    o += (size_t)64 * 16 * 416;
  float* pmp = ws + o;    o += (size_t)64 * 16 * 416;
  int* gstart = (int*)(ws + o); o += 64;
  int* gend = (int*)(ws + o);   o += 64;
  int* deg = (int*)(ws + o);    o += N;
  int* rowptr = (int*)(ws + o); o += N + 1;
  int* cur = (int*)(ws + o);    o += N + 1;
  int* bsum = (int*)(ws + o);   o += 256;
  int2* se = (int2*)(ws + o);   o += (size_t)2 * E;

  const int gconv = (N + 15) / 16;  // 3125
  prep_k<<<(E + 255) / 256, 256, 0, stream>>>(Wm1, We1, Ws1, Wm2, Wl1, ea, x, batch, Wp1,
                                              Wp2, Wp3, eabf, xbf, gstart, gend, deg, bns1p,
                                              bns2p, N, E);
  count_k<<<(E + 255) / 256, 256, 0, stream>>>(ei, deg, E);
  scanA_k<<<nb, 256, 0, stream>>>(deg, bsum, N);
  scanC_k<<<nb, 256, 0, stream>>>(deg, bsum, rowptr, cur, N, nb);
  scatter_k<<<(E + 255) / 256, 256, 0, stream>>>(ei, cur, se, E);
  conv1_k<<<gconv, 256, 0, stream>>>(se, rowptr, xbf, eabf, Wp1, bm1, be1, bs1, acc1c, h1bf,
                                     bns1p, N);
  bnfin1_k<<<1, 256, 0, stream>>>(bns1p, g1, bta1, Ninv, aff1);
  conv2_k<<<gconv, 256, 0, stream>>>(se, rowptr, acc1c, h1bf, xbf, Wp1, Wp2, bm1, be1, bs1,
                                     aff1, We2, bm2, be2, bns2p, h2bf, N);
  bnfin2_k<<<2, 256, 0, stream>>>(bns2p, aff1, g2, bta2, Ninv, aff);
  pool_k<<<dim3(64, 16), 256, 0, stream>>>(h2bf, h1bf, xbf, aff, gstart, gend, psp, pmp);
  pooledprep_k<<<64, 256, 0, stream>>>(psp, pmp, gstart, gend, Apool);
  mlpgemm_k<<<dim3(4, 39), 64, 0, stream>>>(Apool, Wp3, bl1, alpha, hid);
  head_k<<<64, 64, 0, stream>>>(hid, Wl2, bl2, out);
}

// Round 14
// 304.911 us; speedup vs baseline: 1.8772x; 1.1598x over previous
//
#include <hip/hip_runtime.h>

typedef __attribute__((ext_vector_type(8))) short short8;
typedef __attribute__((ext_vector_type(4))) float f32x4;
typedef unsigned short u16;
typedef unsigned int u32;

__device__ __forceinline__ u16 f2bf(float f) {
  u32 u = __float_as_uint(f);
  u = (u + 0x7fffu + ((u >> 16) & 1u)) >> 16;
  return (u16)u;
}
__device__ __forceinline__ float bf2f(u16 v) { return __uint_as_float((u32)v << 16); }
__device__ __forceinline__ void atomAddF(float* p, float v) { unsafeAtomicAdd(p, v); }
__device__ __forceinline__ void addp(float* v, u32 p) {
  v[0] += bf2f((u16)p);
  v[1] += bf2f((u16)(p >> 16));
}

// ---- prep: pack bf16 weights + x->bf16 + graph bounds + zero scratch ---- grid E/256
__global__ void prep_k(const float* __restrict__ Wm1, const float* __restrict__ We1,
                       const float* __restrict__ Ws1, const float* __restrict__ Wm2,
                       const float* __restrict__ Wl1, const float* __restrict__ x,
                       const int* __restrict__ batch, u16* __restrict__ Wp1,
                       u16* __restrict__ Wp2, u16* __restrict__ Wp3,
                       u16* __restrict__ xbf, int* __restrict__ gstart,
                       int* __restrict__ gend, int* __restrict__ deg,
                       float* __restrict__ bns1p, float* __restrict__ bns2p, int N, int E) {
  int tid = blockIdx.x * 256 + threadIdx.x;
  if (tid < 64 * 192) {  // Wcat1 = [Wm1(16); We1(4); Ws1(16)], pad K to 64
    int k = tid / 192, n = tid % 192;
    float v = 0.f;
    if (k < 16) v = Wm1[k * 192 + n];
    else if (k < 20) v = We1[(k - 16) * 192 + n];
    else if (k < 36) v = Ws1[(k - 20) * 192 + n];
    Wp1[((k >> 3) * 192 + n) * 8 + (k & 7)] = f2bf(v);
  }
  if (tid < 224 * 208) {  // W_msg2, pad K 208->224
    int k = tid / 208, n = tid % 208;
    float v = (k < 208) ? Wm2[k * 208 + n] : 0.f;
    Wp2[((k >> 3) * 208 + n) * 8 + (k & 7)] = f2bf(v);
  }
  if (tid < N * 8) {  // x -> bf16, 2 elems/thread
    float2 p = *(const float2*)(x + (size_t)tid * 2);
    *(u32*)(xbf + (size_t)tid * 2) = (u32)f2bf(p.x) | ((u32)f2bf(p.y) << 16);
  }
  if (tid < N) {
    int b = batch[tid];
    if (tid == 0 || batch[tid - 1] != b) gstart[b] = tid;
    if (tid == N - 1 || batch[tid + 1] != b) gend[b] = tid;
    deg[tid] = 0;
  }
  if (tid < 64 * 384) bns1p[tid] = 0.f;
  if (tid < 64 * 832) bns2p[tid] = 0.f;
  if (tid < 1248 * 624) {
    int k = tid / 624, n = tid % 624;
    Wp3[((size_t)(k >> 3) * 624 + n) * 8 + (k & 7)] = f2bf(Wl1[(size_t)k * 624 + n]);
  }
}

// ---- count + within-row ordinal ----
__global__ void count_k(const int* __restrict__ ei, int* __restrict__ deg,
                        int* __restrict__ ord, int E) {
  int e = blockIdx.x * 256 + threadIdx.x;
  if (e >= E) return;
  ord[e] = atomicAdd(&deg[ei[E + e]], 1);
}

__global__ void scanA_k(const int* __restrict__ deg, int* __restrict__ bsum, int N) {
  __shared__ int sh[256];
  int t = threadIdx.x;
  int i = blockIdx.x * 256 + t;
  sh[t] = (i < N) ? deg[i] : 0;
  __syncthreads();
  for (int off = 128; off > 0; off >>= 1) {
    if (t < off) sh[t] += sh[t + off];
    __syncthreads();
  }
  if (t == 0) bsum[blockIdx.x] = sh[0];
}

__global__ void scanC_k(const int* __restrict__ deg, const int* __restrict__ bsum,
                        int* __restrict__ rowptr, int N, int nb) {
  __shared__ int sb2[256];
  __shared__ int sh[256];
  int t = threadIdx.x;
  int bv = (t < nb) ? bsum[t] : 0;
  sb2[t] = bv;
  __syncthreads();
  for (int off = 1; off < 256; off <<= 1) {
    int u = (t >= off) ? sb2[t - off] : 0;
    __syncthreads();
    sb2[t] += u;
    __syncthreads();
  }
  int bpref = (blockIdx.x == 0) ? 0 : sb2[blockIdx.x - 1];
  int i = blockIdx.x * 256 + t;
  int d = (i < N) ? deg[i] : 0;
  sh[t] = d;
  __syncthreads();
  for (int off = 1; off < 256; off <<= 1) {
    int u = (t >= off) ? sh[t - off] : 0;
    __syncthreads();
    sh[t] += u;
    __syncthreads();
  }
  int excl = sh[t] - d + bpref;
  if (i < N) {
    rowptr[i] = excl;
    if (i == N - 1) rowptr[N] = excl + d;
  }
}

// ---- scatter (no atomics): se16[rowptr[d]+ord[e]] = {src, ea01, ea23, 0} ----
__global__ void scatter_k(const int* __restrict__ ei, const float* __restrict__ ea,
                          const int* __restrict__ ord, const int* __restrict__ rowptr,
                          int4* __restrict__ se16, int E) {
  int e = blockIdx.x * 256 + threadIdx.x;
  if (e >= E) return;
  int s = ei[e], d = ei[E + e];
  float4 w = *(const float4*)(ea + (size_t)e * 4);
  int slot = rowptr[d] + ord[e];
  int4 ent;
  ent.x = s;
  ent.y = (int)((u32)f2bf(w.x) | ((u32)f2bf(w.y) << 16));
  ent.z = (int)((u32)f2bf(w.z) | ((u32)f2bf(w.w) << 16));
  ent.w = 0;
  se16[slot] = ent;
}

// ---- CONV1: gather1 (16 lanes/node) + U1(LDS) + gemm1 MFMA + h1bf + bn1 stats ----
// grid ceil(N/16), block 256 (4 waves)
__global__ void __launch_bounds__(256) conv1_k(
    const int4* __restrict__ se16, const int* __restrict__ rowptr,
    const u16* __restrict__ xbf, const u16* __restrict__ Bp,
    const float* __restrict__ bm1, const float* __restrict__ be1,
    const float* __restrict__ bs1, u16* __restrict__ acc1c, u16* __restrict__ h1bf,
    float* __restrict__ bns1p, int N) {
  __shared__ __align__(16) u16 Uls[16][72];
  __shared__ float degls[16];
  int tid = threadIdx.x;
  int nl = tid >> 4, q = tid & 15;
  int n = blockIdx.x * 16 + nl;
  bool nval = n < N;
  int j0 = nval ? rowptr[n] : 0;
  int j1 = nval ? rowptr[n + 1] : 0;
  float v[20];
#pragma unroll
  for (int i = 0; i < 20; ++i) v[i] = 0.f;
  for (int j = j0 + q; j < j1; j += 16) {
    int4 p = se16[j];
    const uint4* xs = (const uint4*)(xbf + (size_t)p.x * 16);
    uint4 x0 = xs[0], x1 = xs[1];
    addp(v + 0, x0.x); addp(v + 2, x0.y); addp(v + 4, x0.z); addp(v + 6, x0.w);
    addp(v + 8, x1.x); addp(v + 10, x1.y); addp(v + 12, x1.z); addp(v + 14, x1.w);
    addp(v + 16, (u32)p.y); addp(v + 18, (u32)p.z);
  }
#pragma unroll
  for (int i = 0; i < 20; ++i) {
    v[i] += __shfl_xor(v[i], 1);
    v[i] += __shfl_xor(v[i], 2);
    v[i] += __shfl_xor(v[i], 4);
    v[i] += __shfl_xor(v[i], 8);
  }
  float degf = (float)(j1 - j0);
  const u16* xr = xbf + (size_t)n * 16;
  {  // U1 row -> LDS: [sums20, x(n)16, 0..]; lane q writes elems q*4..q*4+3
    u32 w2[2];
#pragma unroll
    for (int jj = 0; jj < 2; ++jj) {
      int t0 = q * 4 + 2 * jj, t1 = t0 + 1;
      u16 b0 = (t0 < 20) ? f2bf(v[t0]) : ((t0 < 36 && nval) ? xr[t0 - 20] : (u16)0);
      u16 b1 = (t1 < 20) ? f2bf(v[t1]) : ((t1 < 36 && nval) ? xr[t1 - 20] : (u16)0);
      w2[jj] = (u32)b0 | ((u32)b1 << 16);
    }
    *(uint2*)&Uls[nl][q * 4] = make_uint2(w2[0], w2[1]);
  }
  if (nval) {  // acc1c row: [sx16, sea4, deg, 0..]; lane q -> elems 2q,2q+1
    int t0 = q * 2, t1 = t0 + 1;
    float f0 = (t0 < 20) ? v[t0] : ((t0 == 20) ? degf : 0.f);
    float f1 = (t1 < 20) ? v[t1] : ((t1 == 20) ? degf : 0.f);
    *(u32*)(acc1c + (size_t)n * 32 + q * 2) = (u32)f2bf(f0) | ((u32)f2bf(f1) << 16);
  }
  if (q == 0) degls[nl] = degf;
  __syncthreads();
  // Phase B: 12 n-tile jobs over 4 waves
  int w = tid >> 6, lane = tid & 63, rc = lane & 15, qd = lane >> 4;
  int slice = (blockIdx.x & 63) * 384;
  for (int nt = w; nt < 12; nt += 4) {
    f32x4 acc = {0.f, 0.f, 0.f, 0.f};
#pragma unroll
    for (int kb = 0; kb < 2; ++kb) {
      short8 av = *(const short8*)&Uls[rc][kb * 32 + qd * 8];
      short8 bv = *(const short8*)(Bp + (size_t)((kb * 4 + qd) * 192 + nt * 16 + rc) * 8);
      acc = __builtin_amdgcn_mfma_f32_16x16x32_bf16(av, bv, acc, 0, 0, 0);
    }
    int col = nt * 16 + rc;
    float bb = bm1[col] + be1[col], bsv = bs1[col];
    float ps = 0.f, pq = 0.f;
#pragma unroll
    for (int r = 0; r < 4; ++r) {
      int ml = qd * 4 + r;
      int m = blockIdx.x * 16 + ml;
      float val = acc[r] + degls[ml] * bb + bsv;
      if (m < N) {
        h1bf[(size_t)m * 192 + col] = f2bf(val);
        ps += val;
        pq += val * val;
      }
    }
    ps += __shfl_xor(ps, 16); ps += __shfl_xor(ps, 32);
    pq += __shfl_xor(pq, 16); pq += __shfl_xor(pq, 32);
    if (qd == 0) {
      atomAddF(&bns1p[slice + col], ps);
      atomAddF(&bns1p[slice + 192 + col], pq);
    }
  }
}

// ---- bn1 finalize ---- 1 block, 256 threads
__global__ void bnfin1_k(const float* __restrict__ bns1p, const float* __restrict__ g1,
                         const float* __restrict__ bta1, float Ninv,
                         float* __restrict__ aff1) {
  int c = threadIdx.x;
  if (c >= 192) return;
  float sm = 0.f, sq = 0.f;
  for (int k = 0; k < 64; ++k) {
    sm += bns1p[k * 384 + c];
    sq += bns1p[k * 384 + 192 + c];
  }
  float m1 = sm * Ninv;
  float var = sq * Ninv - m1 * m1;
  float s1 = g1[c] * rsqrtf(var + 1e-5f);
  aff1[c] = s1;
  aff1[192 + c] = bta1[c] - m1 * s1;
}

// ---- CONV2: gather2 (16 lanes/node) + U2(LDS) + gemmq2 (V in LDS) + gemm2 + bn2 ----
// grid ceil(N/16), block 256 (4 waves)
__global__ void __launch_bounds__(256) conv2_k(
    const int4* __restrict__ se16, const int* __restrict__ rowptr,
    const u16* __restrict__ acc1c, const u16* __restrict__ h1bf,
    const u16* __restrict__ xbf, const u16* __restrict__ Bp1, const u16* __restrict__ Bp2,
    const float* __restrict__ bm1, const float* __restrict__ be1,
    const float* __restrict__ bs1, const float* __restrict__ aff1,
    const float* __restrict__ We2, const float* __restrict__ bm2,
    const float* __restrict__ be2, float* __restrict__ bns2p,
    u16* __restrict__ h2bf, int N) {
  __shared__ __align__(16) u16 Uls[16][72];
  __shared__ __align__(16) u16 Vls[16][232];
  __shared__ float degls[16], sdegls[16], eals[16][4];
  int tid = threadIdx.x;
  int nl = tid >> 4, q = tid & 15;
  int n = blockIdx.x * 16 + nl;
  bool nval = n < N;
  int j0 = nval ? rowptr[n] : 0;
  int j1 = nval ? rowptr[n + 1] : 0;
  float v[21];
#pragma unroll
  for (int i = 0; i < 21; ++i) v[i] = 0.f;
  for (int j = j0 + q; j < j1; j += 16) {
    int s = se16[j].x;
    const uint4* cr = (const uint4*)(acc1c + (size_t)s * 32);
    uint4 c0 = cr[0], c1 = cr[1], c2 = cr[2];
    addp(v + 0, c0.x); addp(v + 2, c0.y); addp(v + 4, c0.z); addp(v + 6, c0.w);
    addp(v + 8, c1.x); addp(v + 10, c1.y); addp(v + 12, c1.z); addp(v + 14, c1.w);
    addp(v + 16, c2.x); addp(v + 18, c2.y);
    v[20] += bf2f((u16)c2.z);
  }
#pragma unroll
  for (int i = 0; i < 21; ++i) {
    v[i] += __shfl_xor(v[i], 1);
    v[i] += __shfl_xor(v[i], 2);
    v[i] += __shfl_xor(v[i], 4);
    v[i] += __shfl_xor(v[i], 8);
  }
  const u16* selfr = acc1c + (size_t)n * 32;
  {  // U2 row -> LDS: [sums20, self sx16, 0..]; lane q writes elems q*4..q*4+3
    u32 w2[2];
#pragma unroll
    for (int jj = 0; jj < 2; ++jj) {
      int t0 = q * 4 + 2 * jj, t1 = t0 + 1;
      u16 b0 = (t0 < 20) ? f2bf(v[t0]) : ((t0 < 36 && nval) ? selfr[t0 - 20] : (u16)0);
      u16 b1 = (t1 < 20) ? f2bf(v[t1]) : ((t1 < 36 && nval) ? selfr[t1 - 20] : (u16)0);
      w2[jj] = (u32)b0 | ((u32)b1 << 16);
    }
    *(uint2*)&Uls[nl][q * 4] = make_uint2(w2[0], w2[1]);
  }
  {  // V tail cols [192..224): self sx16 then zeros; lane q -> elems 192+2q, +1
    int t0 = q * 2, t1 = t0 + 1;
    u16 b0 = (t0 < 16 && nval) ? selfr[t0] : (u16)0;
    u16 b1 = (t1 < 16 && nval) ? selfr[t1] : (u16)0;
    *(u32*)&Vls[nl][192 + q * 2] = (u32)b0 | ((u32)b1 << 16);
  }
  if (q == 0) sdegls[nl] = v[20];
  if (q == 1) degls[nl] = nval ? bf2f(selfr[20]) : 0.f;
  if (q == 2) {
#pragma unroll
    for (int k = 0; k < 4; ++k) eals[nl][k] = nval ? bf2f(selfr[16 + k]) : 0.f;
  }
  __syncthreads();
  // Phase B: gemmq2 -> Vls[:,0..192), 12 jobs / 4 waves
  int w = tid >> 6, lane = tid & 63, rc = lane & 15, qd = lane >> 4;
  for (int nt = w; nt < 12; nt += 4) {
    f32x4 acc = {0.f, 0.f, 0.f, 0.f};
#pragma unroll
    for (int kb = 0; kb < 2; ++kb) {
      short8 av = *(const short8*)&Uls[rc][kb * 32 + qd * 8];
      short8 bv = *(const short8*)(Bp1 + (size_t)((kb * 4 + qd) * 192 + nt * 16 + rc) * 8);
      acc = __builtin_amdgcn_mfma_f32_16x16x32_bf16(av, bv, acc, 0, 0, 0);
    }
    int col = nt * 16 + rc;
    float s1 = aff1[col], t1 = aff1[192 + col];
    float bb = bm1[col] + be1[col], bsv = bs1[col];
#pragma unroll
    for (int r = 0; r < 4; ++r) {
      int ml = qd * 4 + r;
      float qv = acc[r] + sdegls[ml] * bb + degls[ml] * bsv;
      Vls[ml][col] = f2bf(qv * s1 + degls[ml] * t1);
    }
  }
  __syncthreads();
  // Phase C: gemm2, A = Vls, 13 jobs / 4 waves
  int slice = (blockIdx.x & 63) * 832;
  for (int nt = w; nt < 13; nt += 4) {
    f32x4 acc = {0.f, 0.f, 0.f, 0.f};
#pragma unroll
    for (int kb = 0; kb < 7; ++kb) {
      short8 av = *(const short8*)&Vls[rc][kb * 32 + qd * 8];
      short8 bv = *(const short8*)(Bp2 + (size_t)((kb * 4 + qd) * 208 + nt * 16 + rc) * 8);
      acc = __builtin_amdgcn_mfma_f32_16x16x32_bf16(av, bv, acc, 0, 0, 0);
    }
    int col = nt * 16 + rc;
    float w0 = We2[col], w1 = We2[208 + col], w2 = We2[416 + col], w3 = We2[624 + col];
    float bb2 = bm2[col] + be2[col];
    bool c192 = col < 192;
    float s1 = c192 ? aff1[col] : 0.f;
    float t1 = c192 ? aff1[192 + col] : 0.f;
    float ps = 0.f, pq = 0.f;
#pragma unroll
    for (int r = 0; r < 4; ++r) {
      int ml = qd * 4 + r;
      int m = blockIdx.x * 16 + ml;
      bool mv = m < N;
      float x1 = 0.f;
      if (mv) {
        x1 = c192 ? (bf2f(h1bf[(size_t)m * 192 + col]) * s1 + t1)
                  : bf2f(xbf[(size_t)m * 16 + (col - 192)]);
      }
      float val = acc[r] + eals[ml][0] * w0 + eals[ml][1] * w1 + eals[ml][2] * w2 +
                  eals[ml][3] * w3 + degls[ml] * bb2 + x1;
      if (mv) {
        h2bf[(size_t)m * 208 + col] = f2bf(val);
        ps += val;
        pq += val * val;
      }
    }
    ps += __shfl_xor(ps, 16); ps += __shfl_xor(ps, 32);
    pq += __shfl_xor(pq, 16); pq += __shfl_xor(pq, 32);
    if (qd == 0) {
      atomAddF(&bns2p[slice + col], ps);
      atomAddF(&bns2p[slice + 416 + col], pq);
    }
  }
}

// ---- bn finalize: unified affine table ---- grid 2x256
__global__ void bnfin2_k(const float* __restrict__ bns2p, const float* __restrict__ aff1,
                         const float* __restrict__ g2, const float* __restrict__ bta2,
                         float Ninv, float* __restrict__ aff) {
  int f = blockIdx.x * 256 + threadIdx.x;
  if (f >= 416) return;
  float sc, sh;
  if (f < 208) {
    float sm = 0.f, sq = 0.f;
    for (int k = 0; k < 64; ++k) {
      sm += bns2p[k * 832 + f];
      sq += bns2p[k * 832 + 416 + f];
    }
    float m2 = sm * Ninv;
    float var = sq * Ninv - m2 * m2;
    sc = g2[f] * rsqrtf(var + 1e-5f);
    sh = bta2[f] - m2 * sc;
  } else if (f < 400) {
    sc = aff1[f - 208];
    sh = aff1[192 + (f - 208)];
  } else {
    sc = 1.f;
    sh = 0.f;
  }
  aff[f] = sc;
  aff[416 + f] = sh;
}

// ---- pooling: feature-pair threads, partial stores ---- grid=(64,16), block=256
__global__ void pool_k(const u16* __restrict__ h2bf, const u16* __restrict__ h1bf,
                       const u16* __restrict__ xbf, const float* __restrict__ aff,
                       const int* __restrict__ gstart, const int* __restrict__ gend,
                       float* __restrict__ psp, float* __restrict__ pmp) {
  int b = blockIdx.x, sub = blockIdx.y;
  int t = threadIdx.x;
  if (t >= 208) return;
  int s0 = gstart[b], e0 = gend[b];
  int cnt = (s0 <= e0) ? e0 - s0 + 1 : 0;
  int per = (cnt + 15) >> 4;
  int n0 = s0 + sub * per;
  int n1 = min(n0 + per, s0 + cnt);
  int f = 2 * t;
  const u16* src;
  int stride;
  if (f < 208) { src = h2bf + f; stride = 208; }
  else if (f < 400) { src = h1bf + (f - 208); stride = 192; }
  else { src = xbf + (f - 400); stride = 16; }
  float sc0 = aff[f], sc1 = aff[f + 1];
  float sh0 = aff[416 + f], sh1 = aff[417 + f];
  float s0f = 0.f, s1f = 0.f, m0f = -3.4e38f, m1f = -3.4e38f;
  for (int n = n0; n < n1; ++n) {
    u32 p = *(const u32*)(src + (size_t)n * stride);
    float v0 = bf2f((u16)p) * sc0 + sh0;
    float v1 = bf2f((u16)(p >> 16)) * sc1 + sh1;
    s0f += v0; s1f += v1;
    m0f = fmaxf(m0f, v0); m1f = fmaxf(m1f, v1);
  }
  size_t idx = ((size_t)(b * 16 + sub)) * 416 + f;
  *(float2*)(psp + idx) = make_float2(s0f, s1f);
  *(float2*)(pmp + idx) = make_float2(m0f, m1f);
}

// ---- pooled partial reduce -> bf16 A matrix [64 x 1248] ---- grid=64, block=256
__global__ void pooledprep_k(const float* __restrict__ psp, const float* __restrict__ pmp,
                             const int* __restrict__ gstart, const int* __restrict__ gend,
                             u16* __restrict__ Apool) {
  int b = blockIdx.x, t = threadIdx.x;
  int cnt = gend[b] - gstart[b] + 1;
  float inv = 1.f / (float)max(cnt, 1);
  for (int f = t; f < 416; f += 256) {
    float s = 0.f, m = -3.4e38f;
    for (int k = 0; k < 16; ++k) {
      size_t idx = ((size_t)(b * 16 + k)) * 416 + f;
      s += psp[idx];
      m = fmaxf(m, pmp[idx]);
    }
    u16* row = Apool + (size_t)b * 1248;
    row[f] = f2bf(s);
    row[416 + f] = f2bf((cnt > 0) ? m : 0.f);
    row[832 + f] = f2bf(s * inv);
  }
}

// ---- MLP layer 1 via MFMA ---- grid=(4,39), block=64
__global__ void mlpgemm_k(const u16* __restrict__ A, const u16* __restrict__ Bp,
                          const float* __restrict__ b1, const float* __restrict__ al,
                          float* __restrict__ hid) {
  int lane = threadIdx.x;
  int mt = blockIdx.x, nt = blockIdx.y;
  int rc = lane & 15, qd = lane >> 4;
  f32x4 acc = {0.f, 0.f, 0.f, 0.f};
  const u16* Ap = A + (size_t)(mt * 16 + rc) * 1248 + qd * 8;
  const u16* Bq = Bp + (size_t)(qd * 624 + nt * 16 + rc) * 8;
  for (int kb = 0; kb < 39; ++kb) {
    short8 av = *(const short8*)(Ap + kb * 32);
    short8 bv = *(const short8*)(Bq + (size_t)kb * 4 * 624 * 8);
    acc = __builtin_amdgcn_mfma_f32_16x16x32_bf16(av, bv, acc, 0, 0, 0);
  }
  int col = nt * 16 + rc;
  float bb = b1[col], alpha = al[0];
  int m0 = mt * 16 + qd * 4;
#pragma unroll
  for (int r = 0; r < 4; ++r) {
    float v = acc[r] + bb;
    hid[(size_t)(m0 + r) * 624 + col] = (v >= 0.f) ? v : alpha * v;
  }
}

// ---- logits + log_softmax ---- grid=64, block=64
__global__ void head_k(const float* __restrict__ hid, const float* __restrict__ W2,
                       const float* __restrict__ b2, float* __restrict__ out) {
  int b = blockIdx.x, t = threadIdx.x;
  float p0 = 0.f, p1 = 0.f;
  for (int k = t; k < 624; k += 64) {
    float h = hid[(size_t)b * 624 + k];
    p0 += h * W2[k * 2];
    p1 += h * W2[k * 2 + 1];
  }
#pragma unroll
  for (int off = 32; off > 0; off >>= 1) {
    p0 += __shfl_down(p0, off);
    p1 += __shfl_down(p1, off);
  }
  if (t == 0) {
    float l0 = p0 + b2[0], l1 = p1 + b2[1];
    float m = fmaxf(l0, l1);
    float lse = m + logf(expf(l0 - m) + expf(l1 - m));
    out[b * 2] = l0 - lse;
    out[b * 2 + 1] = l1 - lse;
  }
}

extern "C" void kernel_launch(void* const* d_in, const int* in_sizes, int n_in,
                              void* d_out, int out_size, void* d_ws, size_t ws_size,
                              hipStream_t stream) {
  const float* x = (const float*)d_in[0];
  const int* ei = (const int*)d_in[1];
  const float* ea = (const float*)d_in[2];
  const int* batch = (const int*)d_in[3];
  const float* Wm1 = (const float*)d_in[4];
  const float* bm1 = (const float*)d_in[5];
  const float* We1 = (const float*)d_in[6];
  const float* be1 = (const float*)d_in[7];
  const float* Ws1 = (const float*)d_in[8];
  const float* bs1 = (const float*)d_in[9];
  const float* g1 = (const float*)d_in[10];
  const float* bta1 = (const float*)d_in[11];
  const float* Wm2 = (const float*)d_in[12];
  const float* bm2 = (const float*)d_in[13];
  const float* We2 = (const float*)d_in[14];
  const float* be2 = (const float*)d_in[15];
  const float* g2 = (const float*)d_in[16];
  const float* bta2 = (const float*)d_in[17];
  const float* Wl1 = (const float*)d_in[18];
  const float* bl1 = (const float*)d_in[19];
  const float* alpha = (const float*)d_in[20];
  const float* Wl2 = (const float*)d_in[21];
  const float* bl2 = (const float*)d_in[22];
  float* out = (float*)d_out;

  const int N = in_sizes[3];      // 50000
  const int E = in_sizes[2] / 4;  // 800000
  const int nb = (N + 255) / 256; // 196 (<=256)
  const float Ninv = 1.f / (float)N;

  float* ws = (float*)d_ws;
  size_t o = 0;
  u16* acc1c = (u16*)(ws + o); o += (size_t)N * 16;  // N*32 u16
  u16* h2bf = (u16*)(ws + o);  o += (size_t)N * 104; // N*208 u16
  u16* h1bf = (u16*)(ws + o);  o += (size_t)N * 96;  // N*192 u16
  u16* xbf = (u16*)(ws + o);   o += (size_t)N * 8;   // N*16 u16
  u16* Wp1 = (u16*)(ws + o);   o += 6144;
  u16* Wp2 = (u16*)(ws + o);   o += 23296;
  u16* Wp3 = (u16*)(ws + o);   o += 389376;
  u16* Apool = (u16*)(ws + o); o += 39936;
  float* hid = ws + o;    o += 64 * 624;
  float* bns1p = ws + o;  o += 64 * 384;
  float* bns2p = ws + o;  o += 64 * 832;
  float* aff1 = ws + o;   o += 384;
  float* aff = ws + o;    o += 832;
  float* psp = ws + o;    o += (size_t)64 * 16 * 416;
  float* pmp = ws + o;    o += (size_t)64 * 16 * 416;
  int* gstart = (int*)(ws + o); o += 64;
  int* gend = (int*)(ws + o);   o += 64;
  int* deg = (int*)(ws + o);    o += N;
  int* rowptr = (int*)(ws + o); o += N + 1;
  int* ord = (int*)(ws + o);    o += E;
  int* bsum = (int*)(ws + o);   o += 256;
  o = (o + 3) & ~(size_t)3;  // 16B align for int4
  int4* se16 = (int4*)(ws + o); o += (size_t)4 * E;

  const int gconv = (N + 15) / 16;  // 3125
  prep_k<<<(E + 255) / 256, 256, 0, stream>>>(Wm1, We1, Ws1, Wm2, Wl1, x, batch, Wp1, Wp2,
                                              Wp3, xbf, gstart, gend, deg, bns1p, bns2p,
                                              N, E);
  count_k<<<(E + 255) / 256, 256, 0, stream>>>(ei, deg, ord, E);
  scanA_k<<<nb, 256, 0, stream>>>(deg, bsum, N);
  scanC_k<<<nb, 256, 0, stream>>>(deg, bsum, rowptr, N, nb);
  scatter_k<<<(E + 255) / 256, 256, 0, stream>>>(ei, ea, ord, rowptr, se16, E);
  conv1_k<<<gconv, 256, 0, stream>>>(se16, rowptr, xbf, Wp1, bm1, be1, bs1, acc1c, h1bf,
                                     bns1p, N);
  bnfin1_k<<<1, 256, 0, stream>>>(bns1p, g1, bta1, Ninv, aff1);
  conv2_k<<<gconv, 256, 0, stream>>>(se16, rowptr, acc1c, h1bf, xbf, Wp1, Wp2, bm1, be1,
                                     bs1, aff1, We2, bm2, be2, bns2p, h2bf, N);
  bnfin2_k<<<2, 256, 0, stream>>>(bns2p, aff1, g2, bta2, Ninv, aff);
  pool_k<<<dim3(64, 16), 256, 0, stream>>>(h2bf, h1bf, xbf, aff, gstart, gend, psp, pmp);
  pooledprep_k<<<64, 256, 0, stream>>>(psp, pmp, gstart, gend, Apool);
  mlpgemm_k<<<dim3(4, 39), 64, 0, stream>>>(Apool, Wp3, bl1, alpha, hid);
  head_k<<<64, 64, 0, stream>>>(hid, Wl2, bl2, out);
}